// Round 8
// baseline (776.355 us; speedup 1.0000x reference)
//
#include <hip/hip_runtime.h>
#include <hip/hip_bf16.h>
#include <stdint.h>

// Problem constants (fixed by reference setup)
#define N_NODES 50000
#define M_PAD   50048          // 391 * 128
#define N_EDGES 1600000
#define R_REL   5
#define NSEG    (N_NODES * R_REL)    // 250000
#define CPAD    16                   // one counter per 64B line
#define SCAN_BLOCKS 245              // ceil(NSEG / 1024)
#define HIST_BLOCKS 196              // ceil(N_NODES / 256)

typedef __bf16 bf16;
typedef __bf16 bf16x2 __attribute__((ext_vector_type(2)));
typedef __bf16 bf16x4 __attribute__((ext_vector_type(4)));
typedef __bf16 bf16x8 __attribute__((ext_vector_type(8)));
typedef float  f32x4  __attribute__((ext_vector_type(4)));

#define GLOAD_LDS16(g, l)                                                          \
    __builtin_amdgcn_global_load_lds(                                              \
        (const __attribute__((address_space(1))) void*)(g),                        \
        (__attribute__((address_space(3))) void*)(l), 16, 0, 0)

// ---------------------------------------------------------------------------
// h0[n,:] = xlist[node_type[n]][local_idx[n], :]  (f32 -> bf16), 4 rows/block
__global__ __launch_bounds__(256) void group_input_k(
    const float* __restrict__ x0, const float* __restrict__ x1,
    const float* __restrict__ emb2, const int* __restrict__ ntype,
    const int* __restrict__ lidx, bf16* __restrict__ h)
{
    int row = blockIdx.x * 4 + (threadIdx.x >> 6);
    int lane = threadIdx.x & 63;
    if (row >= N_NODES) return;
    int t = ntype[row];
    int li = lidx[row];
    const float* src = (t == 0) ? x0 : (t == 1) ? x1 : emb2;
    float4 v = *reinterpret_cast<const float4*>(&src[(size_t)li * 256 + lane * 4]);
    bf16x4 o;
    o[0] = (bf16)v.x; o[1] = (bf16)v.y; o[2] = (bf16)v.z; o[3] = (bf16)v.w;
    *reinterpret_cast<bf16x4*>(&h[(size_t)row * 256 + lane * 4]) = o;
}

// ---------------------------------------------------------------------------
// CSR build: histogram over seg = dst*R + edge_type; rank = position in seg.
// Counters padded to one per 64B line to avoid same-line atomic contention.
__global__ __launch_bounds__(256) void hist_k(
    const int* __restrict__ ei, const int* __restrict__ et,
    int* __restrict__ cnt, int* __restrict__ rank)
{
    int e = blockIdx.x * 256 + threadIdx.x;
    if (e >= N_EDGES) return;
    int dst = ei[N_EDGES + e];
    rank[e] = atomicAdd(&cnt[(dst * R_REL + et[e]) * CPAD], 1);
}

// Two-level exclusive scan (1024 elems per block); reads padded counters.
__global__ __launch_bounds__(256) void scan1_k(
    const int* __restrict__ cnt, int* __restrict__ excl, int* __restrict__ blksum)
{
    __shared__ int lds[256];
    int base = blockIdx.x * 1024;
    int t = threadIdx.x;
    int vals[4]; int s = 0;
#pragma unroll
    for (int i = 0; i < 4; ++i) {
        int idx = base + t * 4 + i;
        vals[i] = (idx < NSEG) ? cnt[idx * CPAD] : 0;
        s += vals[i];
    }
    lds[t] = s;
    __syncthreads();
    for (int off = 1; off < 256; off <<= 1) {
        int v = (t >= off) ? lds[t - off] : 0;
        __syncthreads();
        lds[t] += v;
        __syncthreads();
    }
    int incl = lds[t];
    int ex = incl - s;
    if (t == 255) blksum[blockIdx.x] = incl;
    int run = ex;
#pragma unroll
    for (int i = 0; i < 4; ++i) {
        int idx = base + t * 4 + i;
        if (idx < NSEG) excl[idx] = run;
        run += vals[i];
    }
}

__global__ __launch_bounds__(256) void scan2_k(int* __restrict__ blksum, int nblk)
{
    __shared__ int lds[256];
    int t = threadIdx.x;
    int v = (t < nblk) ? blksum[t] : 0;
    lds[t] = v;
    __syncthreads();
    for (int off = 1; off < 256; off <<= 1) {
        int u = (t >= off) ? lds[t - off] : 0;
        __syncthreads();
        lds[t] += u;
        __syncthreads();
    }
    if (t < nblk) blksum[t] = lds[t] - v;  // exclusive over block sums
}

// Fold block offsets into excl -> absolute segment starts; add sentinel.
__global__ __launch_bounds__(256) void finalize_k(
    int* __restrict__ excl, const int* __restrict__ blks)
{
    int base = blockIdx.x * 1024 + threadIdx.x * 4;
    int b = blks[blockIdx.x];
#pragma unroll
    for (int i = 0; i < 4; ++i) {
        int idx = base + i;
        if (idx < NSEG) excl[idx] += b;
    }
    if (blockIdx.x == 0 && threadIdx.x == 0) excl[NSEG] = N_EDGES;
}

// Scatter (atomic-free, single 4B store per edge):
// pk[pos] = (src*R + r) | cnt(seg) << 18   (idx < 2^18, cnt < 2^14)
__global__ __launch_bounds__(256) void scatter_k(
    const int* __restrict__ ei, const int* __restrict__ et,
    const int* __restrict__ excl, const int* __restrict__ cnt,
    const int* __restrict__ rank, uint32_t* __restrict__ pk)
{
    int e = blockIdx.x * 256 + threadIdx.x;
    if (e >= N_EDGES) return;
    int r = et[e];
    int seg = ei[N_EDGES + e] * R_REL + r;
    int pos = excl[seg] + rank[e];
    pk[pos] = (uint32_t)(ei[e] * R_REL + r) | ((uint32_t)cnt[seg * CPAD] << 18);
}

// ---------------------------------------------------------------------------
// Type partition: perm lists node ids sorted by type (stable by block).
__global__ __launch_bounds__(256) void typed_hist_k(
    const int* __restrict__ ntype, int* __restrict__ tcnt)
{
    __shared__ int c[3];
    if (threadIdx.x < 3) c[threadIdx.x] = 0;
    __syncthreads();
    int n = blockIdx.x * 256 + threadIdx.x;
    if (n < N_NODES) atomicAdd(&c[ntype[n]], 1);
    __syncthreads();
    if (threadIdx.x < 3) tcnt[threadIdx.x * HIST_BLOCKS + blockIdx.x] = c[threadIdx.x];
}

// scan over 3*196=588 values ordered (type, block); emit toff + meta
// meta[0..3]=typestart, meta[4..7]=block-chunk offsets, meta[8..10]=type counts
__global__ __launch_bounds__(1024) void typed_scan_k(
    const int* __restrict__ tcnt, int* __restrict__ toff, int* __restrict__ meta)
{
    __shared__ int lds[1024];
    int t = threadIdx.x;
    int v = (t < 3 * HIST_BLOCKS) ? tcnt[t] : 0;
    lds[t] = v;
    __syncthreads();
    for (int off = 1; off < 1024; off <<= 1) {
        int u = (t >= off) ? lds[t - off] : 0;
        __syncthreads();
        lds[t] += u;
        __syncthreads();
    }
    if (t < 3 * HIST_BLOCKS) toff[t] = lds[t] - v;
    if (t == 0) {
        int ts1 = lds[1 * HIST_BLOCKS - 1];
        int ts2 = lds[2 * HIST_BLOCKS - 1];
        int ts3 = lds[3 * HIST_BLOCKS - 1];
        meta[0] = 0; meta[1] = ts1; meta[2] = ts2; meta[3] = ts3;
        int c0 = ts1, c1 = ts2 - ts1, c2 = ts3 - ts2;
        meta[8] = c0; meta[9] = c1; meta[10] = c2;
        int b0 = (c0 + 127) >> 7, b1 = (c1 + 127) >> 7, b2 = (c2 + 127) >> 7;
        meta[4] = 0; meta[5] = b0; meta[6] = b0 + b1; meta[7] = b0 + b1 + b2;
    }
}

__global__ __launch_bounds__(256) void typed_scatter_k(
    const int* __restrict__ ntype, const int* __restrict__ toff,
    int* __restrict__ perm)
{
    __shared__ int cur[3];
    if (threadIdx.x < 3) cur[threadIdx.x] = 0;
    __syncthreads();
    int n = blockIdx.x * 256 + threadIdx.x;
    if (n < N_NODES) {
        int t = ntype[n];
        int rank = atomicAdd(&cur[t], 1);
        perm[toff[t * HIST_BLOCKS + blockIdx.x] + rank] = n;
    }
}

// ---------------------------------------------------------------------------
// Weight prep: Wt arranged [half][r][128][256]: row w = h*640 + r*128 + oo
// maps to relW[r][h*128+oo][:]. Rt = straight cast of rootW.
__global__ __launch_bounds__(256) void cast_w_k(
    const float* __restrict__ relW, const float* __restrict__ rootW,
    bf16* __restrict__ Wt, bf16* __restrict__ Rt, int Dout)
{
    int i = blockIdx.x * 256 + threadIdx.x;
    int relN = R_REL * Dout * 256;
    if (i < relN) {
        int d = i & 255;
        int w = i >> 8;
        int h = w / 640;
        int rem = w - h * 640;
        int r = rem >> 7;
        int o = h * 128 + (rem & 127);
        Wt[i] = (bf16)relW[((size_t)r * Dout + o) * 256 + d];
    }
    int rootN = 3 * Dout * 256;
    if (i < rootN) Rt[i] = (bf16)rootW[i];
}

// ---------------------------------------------------------------------------
// Y GEMM: Y[m, j] = sum_d h[m, d] * W[j, d]   (bf16 out, K=256, no row guard)
__global__ __launch_bounds__(256) void gemm_y_k(
    const bf16* __restrict__ A, const bf16* __restrict__ B,
    bf16* __restrict__ Y, int ldc)
{
    __shared__ bf16 As[128][64];
    __shared__ bf16 Bs[128][64];
    int tid = threadIdx.x;
    int lane = tid & 63, wave = tid >> 6;
    int wm = wave >> 1, wn = wave & 1;
    int m0 = blockIdx.x * 128, n0 = blockIdx.y * 128;

    f32x4 acc[4][4] = {};

    for (int kt = 0; kt < 4; ++kt) {
#pragma unroll
        for (int cc = 0; cc < 4; ++cc) {
            int linear = cc * 256 + tid;
            int row = linear >> 3, sl = linear & 7;
            const bf16* gA = &A[(size_t)(m0 + row) * 256 + kt * 64 + sl * 8];
            const bf16* gB = &B[(size_t)(n0 + row) * 256 + kt * 64 + sl * 8];
            char* sA = (char*)&As[0][0] + (size_t)(cc * 256 + wave * 64) * 16;
            char* sB = (char*)&Bs[0][0] + (size_t)(cc * 256 + wave * 64) * 16;
            GLOAD_LDS16(gA, sA);
            GLOAD_LDS16(gB, sB);
        }
        __syncthreads();
#pragma unroll
        for (int kk = 0; kk < 2; ++kk) {
            bf16x8 af[4], bfr[4];
            int k0 = kk * 32 + (lane >> 4) * 8;
#pragma unroll
            for (int i = 0; i < 4; ++i) {
                af[i]  = *reinterpret_cast<const bf16x8*>(&As[wm * 64 + i * 16 + (lane & 15)][k0]);
                bfr[i] = *reinterpret_cast<const bf16x8*>(&Bs[wn * 64 + i * 16 + (lane & 15)][k0]);
            }
#pragma unroll
            for (int i = 0; i < 4; ++i)
#pragma unroll
                for (int j = 0; j < 4; ++j)
                    acc[i][j] = __builtin_amdgcn_mfma_f32_16x16x32_bf16(af[i], bfr[j], acc[i][j], 0, 0, 0);
        }
        __syncthreads();
    }

#pragma unroll
    for (int i = 0; i < 4; ++i)
#pragma unroll
        for (int j = 0; j < 4; ++j)
#pragma unroll
            for (int r = 0; r < 4; ++r) {
                int row = m0 + wm * 64 + i * 16 + (lane >> 4) * 4 + r;
                int col = n0 + wn * 64 + j * 16 + (lane & 15);
                Y[(size_t)row * ldc + col] = (bf16)acc[i][j][r];
            }
}

// ---------------------------------------------------------------------------
// Gather-accumulate over one 128-wide column slab:
// Cb[n, lane*2..+1] = sum_e (1/cnt_e) * Y[idx_e, lane*2..+1]
// pk packs idx (18b) | cnt (14b); weight via v_rcp_f32 (1 ulp).
__global__ __launch_bounds__(256) void gather_k(
    const bf16* __restrict__ Y, const uint32_t* __restrict__ pk,
    const int* __restrict__ excl, bf16* __restrict__ Cb, int ldcb)
{
    int wave = threadIdx.x >> 6, lane = threadIdx.x & 63;
    int n = blockIdx.x * 4 + wave;
    if (n >= N_NODES) return;
    int off0 = excl[n * R_REL];
    int off1 = excl[n * R_REL + R_REL];
    int c = off1 - off0;

    float s0 = 0.f, s1 = 0.f;
    int e = 0;
    for (; e + 8 <= c; e += 8) {
        uint32_t w[8]; bf16x2 v[8];
#pragma unroll
        for (int j = 0; j < 8; ++j) w[j] = pk[off0 + e + j];
#pragma unroll
        for (int j = 0; j < 8; ++j)
            v[j] = *reinterpret_cast<const bf16x2*>(&Y[(size_t)(w[j] & 0x3FFFF) * 128 + lane * 2]);
#pragma unroll
        for (int j = 0; j < 8; ++j) {
            float ww = __builtin_amdgcn_rcpf((float)(w[j] >> 18));
            s0 += ww * (float)v[j][0];
            s1 += ww * (float)v[j][1];
        }
    }
    if (e + 4 <= c) {
        uint32_t w[4]; bf16x2 v[4];
#pragma unroll
        for (int j = 0; j < 4; ++j) w[j] = pk[off0 + e + j];
#pragma unroll
        for (int j = 0; j < 4; ++j)
            v[j] = *reinterpret_cast<const bf16x2*>(&Y[(size_t)(w[j] & 0x3FFFF) * 128 + lane * 2]);
#pragma unroll
        for (int j = 0; j < 4; ++j) {
            float ww = __builtin_amdgcn_rcpf((float)(w[j] >> 18));
            s0 += ww * (float)v[j][0];
            s1 += ww * (float)v[j][1];
        }
        e += 4;
    }
    for (; e < c; ++e) {
        uint32_t w = pk[off0 + e];
        bf16x2 v = *reinterpret_cast<const bf16x2*>(&Y[(size_t)(w & 0x3FFFF) * 128 + lane * 2]);
        float ww = __builtin_amdgcn_rcpf((float)(w >> 18));
        s0 += ww * (float)v[0];
        s1 += ww * (float)v[1];
    }

    bf16x2 o; o[0] = (bf16)s0; o[1] = (bf16)s1;
    *reinterpret_cast<bf16x2*>(&Cb[(size_t)n * ldcb + lane * 2]) = o;
}

// ---------------------------------------------------------------------------
// Root GEMM over type-sorted 128-row chunks: out = Cb[ri] + h[ri]@Rt[t]^T + b[t]
// relu_mode: ReLU + bf16 emit to hout; else fp32 emit to C (last layer).
__global__ __launch_bounds__(256) void gemm_root_k(
    const bf16* __restrict__ h, const bf16* __restrict__ Rt,
    const float* __restrict__ rootB, const int* __restrict__ perm,
    const int* __restrict__ meta, const bf16* __restrict__ Cb,
    float* __restrict__ C, bf16* __restrict__ hout, int Dout, int relu_mode)
{
    __shared__ bf16 As[128][64];
    __shared__ bf16 Bs[128][64];
    __shared__ int ridx[128];
    int tid = threadIdx.x;
    int bx = blockIdx.x;
    int b1 = meta[5], b2 = meta[6], b3 = meta[7];
    if (bx >= b3) return;
    int t = (bx >= b2) ? 2 : (bx >= b1 ? 1 : 0);
    int chunk = bx - (t == 2 ? b2 : (t == 1 ? b1 : 0));
    int tstart = meta[t];
    int tc = meta[8 + t];
    int rbase = chunk * 128;
    if (tid < 128) {
        int lr = rbase + tid;
        ridx[tid] = (lr < tc) ? perm[tstart + lr] : 0;
    }
    __syncthreads();

    int lane = tid & 63, wave = tid >> 6;
    int wm = wave >> 1, wn = wave & 1;
    int n0 = blockIdx.y * 128;
    const bf16* B = Rt + (size_t)t * Dout * 256;

    f32x4 acc[4][4] = {};

    for (int kt = 0; kt < 4; ++kt) {   // K = 256
#pragma unroll
        for (int cc = 0; cc < 4; ++cc) {
            int linear = cc * 256 + tid;
            int row = linear >> 3, sl = linear & 7;
            const bf16* gA = &h[(size_t)ridx[row] * 256 + kt * 64 + sl * 8];
            const bf16* gB = &B[(size_t)(n0 + row) * 256 + kt * 64 + sl * 8];
            char* sA = (char*)&As[0][0] + (size_t)(cc * 256 + wave * 64) * 16;
            char* sB = (char*)&Bs[0][0] + (size_t)(cc * 256 + wave * 64) * 16;
            GLOAD_LDS16(gA, sA);
            GLOAD_LDS16(gB, sB);
        }
        __syncthreads();
#pragma unroll
        for (int kk = 0; kk < 2; ++kk) {
            bf16x8 af[4], bfr[4];
            int k0 = kk * 32 + (lane >> 4) * 8;
#pragma unroll
            for (int i = 0; i < 4; ++i) {
                af[i]  = *reinterpret_cast<const bf16x8*>(&As[wm * 64 + i * 16 + (lane & 15)][k0]);
                bfr[i] = *reinterpret_cast<const bf16x8*>(&Bs[wn * 64 + i * 16 + (lane & 15)][k0]);
            }
#pragma unroll
            for (int i = 0; i < 4; ++i)
#pragma unroll
                for (int j = 0; j < 4; ++j)
                    acc[i][j] = __builtin_amdgcn_mfma_f32_16x16x32_bf16(af[i], bfr[j], acc[i][j], 0, 0, 0);
        }
        __syncthreads();
    }

#pragma unroll
    for (int i = 0; i < 4; ++i)
#pragma unroll
        for (int j = 0; j < 4; ++j)
#pragma unroll
            for (int r = 0; r < 4; ++r) {
                int rl = wm * 64 + i * 16 + (lane >> 4) * 4 + r;
                int col = n0 + wn * 64 + j * 16 + (lane & 15);
                if (rbase + rl < tc) {
                    int ri = ridx[rl];
                    float v = (float)Cb[(size_t)ri * Dout + col] + acc[i][j][r]
                              + rootB[t * Dout + col];
                    if (relu_mode)
                        hout[(size_t)ri * Dout + col] = (bf16)fmaxf(v, 0.f);
                    else
                        C[(size_t)ri * Dout + col] = v;
                }
            }
}

// ---------------------------------------------------------------------------
// Row-wise log_softmax over 128 logits; one wave per row.
__global__ __launch_bounds__(256) void logsoftmax_k(
    const float* __restrict__ C, float* __restrict__ out, int M)
{
    int row = blockIdx.x * 4 + (threadIdx.x >> 6);
    int lane = threadIdx.x & 63;
    if (row >= M) return;
    float v0 = C[(size_t)row * 128 + lane];
    float v1 = C[(size_t)row * 128 + 64 + lane];
    float m = fmaxf(v0, v1);
    for (int off = 32; off; off >>= 1) m = fmaxf(m, __shfl_xor(m, off));
    float s = expf(v0 - m) + expf(v1 - m);
    for (int off = 32; off; off >>= 1) s += __shfl_xor(s, off);
    float lse = m + logf(s);
    out[(size_t)row * 128 + lane] = v0 - lse;
    out[(size_t)row * 128 + 64 + lane] = v1 - lse;
}

// ---------------------------------------------------------------------------
extern "C" void kernel_launch(void* const* d_in, const int* in_sizes, int n_in,
                              void* d_out, int out_size, void* d_ws, size_t ws_size,
                              hipStream_t stream)
{
    const float* x0   = (const float*)d_in[0];
    const float* x1   = (const float*)d_in[1];
    const float* emb2 = (const float*)d_in[2];
    const int*   ei   = (const int*)d_in[3];
    const int*   et   = (const int*)d_in[4];
    const int*   ntyp = (const int*)d_in[5];
    const int*   lidx = (const int*)d_in[6];
    const float* relW[3]  = {(const float*)d_in[7],  (const float*)d_in[10], (const float*)d_in[13]};
    const float* rootW[3] = {(const float*)d_in[8],  (const float*)d_in[11], (const float*)d_in[14]};
    const float* rootB[3] = {(const float*)d_in[9],  (const float*)d_in[12], (const float*)d_in[15]};
    float* out = (float*)d_out;

    char* p = (char*)d_ws;
    auto carve = [&](size_t bytes) {
        char* q = p;
        p += (bytes + 255) & ~(size_t)255;
        return (void*)q;
    };
    bf16* h_a   = (bf16*)carve((size_t)M_PAD * 256 * 2);
    bf16* h_b   = (bf16*)carve((size_t)M_PAD * 256 * 2);
    bf16* Y     = (bf16*)carve((size_t)2 * M_PAD * 640 * 2);  // two 64 MB slabs
    bf16* Cb    = (bf16*)carve((size_t)M_PAD * 256 * 2);
    bf16* WtA   = (bf16*)carve((size_t)(2 * R_REL * 256 * 256 + R_REL * 128 * 256) * 2);
    bf16* RtA   = (bf16*)carve((size_t)(2 * 3 * 256 * 256 + 3 * 128 * 256) * 2);
    int* cnt    = (int*)carve((size_t)NSEG * CPAD * 4);       // 16 MB, line-padded
    int* excl   = (int*)carve((size_t)(NSEG + 1) * 4);
    int* blks   = (int*)carve((size_t)256 * 4);
    int* rank   = (int*)carve((size_t)N_EDGES * 4);
    uint32_t* pk = (uint32_t*)carve((size_t)N_EDGES * 4);
    int* tcnt   = (int*)carve((size_t)3 * HIST_BLOCKS * 4);
    int* toff   = (int*)carve((size_t)3 * HIST_BLOCKS * 4);
    int* meta   = (int*)carve((size_t)16 * 4);
    int* perm   = (int*)carve((size_t)N_NODES * 4);
    // fp32 logits buffer aliased into Y slab 1 (dead at layer 3, which uses
    // only slab 0 = 64.06 MB; C sits at +96 MB, needs 25.6 MB < 128.1 MB).
    float* C = (float*)((char*)Y + (size_t)96 * 1024 * 1024);

    bf16* Wt[3] = {WtA, WtA + (size_t)R_REL * 256 * 256, WtA + (size_t)2 * R_REL * 256 * 256};
    bf16* Rt[3] = {RtA, RtA + (size_t)3 * 256 * 256, RtA + (size_t)2 * 3 * 256 * 256};

    hipMemsetAsync(cnt, 0, (size_t)NSEG * CPAD * 4, stream);

    group_input_k<<<(N_NODES + 3) / 4, 256, 0, stream>>>(x0, x1, emb2, ntyp, lidx, h_a);
    hist_k<<<(N_EDGES + 255) / 256, 256, 0, stream>>>(ei, et, cnt, rank);
    scan1_k<<<SCAN_BLOCKS, 256, 0, stream>>>(cnt, excl, blks);
    scan2_k<<<1, 256, 0, stream>>>(blks, SCAN_BLOCKS);
    finalize_k<<<SCAN_BLOCKS, 256, 0, stream>>>(excl, blks);
    scatter_k<<<(N_EDGES + 255) / 256, 256, 0, stream>>>(ei, et, excl, cnt, rank, pk);
    typed_hist_k<<<HIST_BLOCKS, 256, 0, stream>>>(ntyp, tcnt);
    typed_scan_k<<<1, 1024, 0, stream>>>(tcnt, toff, meta);
    typed_scatter_k<<<HIST_BLOCKS, 256, 0, stream>>>(ntyp, toff, perm);
    // weight prep for all layers up-front (independent of activations)
    const int douts[3] = {256, 256, 128};
    for (int l = 0; l < 3; ++l)
        cast_w_k<<<(R_REL * douts[l] * 256 + 255) / 256, 256, 0, stream>>>(
            relW[l], rootW[l], Wt[l], Rt[l], douts[l]);

    bf16* cur = h_a;
    bf16* nxt = h_b;
    for (int l = 0; l < 3; ++l) {
        int Dout = douts[l];
        int NH = Dout / 128;
        for (int h = 0; h < NH; ++h) {
            bf16* Yh = Y + (size_t)h * M_PAD * 640;
            gemm_y_k<<<dim3(M_PAD / 128, 5), 256, 0, stream>>>(
                cur, Wt[l] + (size_t)h * 640 * 256, Yh, 640);
            gather_k<<<(N_NODES + 3) / 4, 256, 0, stream>>>(
                Yh, pk, excl, Cb + h * 128, Dout);
        }
        gemm_root_k<<<dim3(393, Dout / 128), 256, 0, stream>>>(
            cur, Rt[l], rootB[l], perm, meta, Cb, C, nxt, Dout, (l < 2) ? 1 : 0);
        bf16* tmp = cur; cur = nxt; nxt = tmp;
    }
    logsoftmax_k<<<(N_NODES + 3) / 4, 256, 0, stream>>>(C, out, N_NODES);
}

// Round 9
// 701.790 us; speedup vs baseline: 1.1062x; 1.1062x over previous
//
#include <hip/hip_runtime.h>
#include <hip/hip_bf16.h>
#include <stdint.h>

// Problem constants (fixed by reference setup)
#define N_NODES 50000
#define M_PAD   50048          // 391 * 128
#define N_EDGES 1600000
#define R_REL   5
#define NBUCK   391            // buckets of 128 dst nodes
#define NB1     256            // blocks in bucket hist/scatter
#define EPB     6250           // N_EDGES / NB1 (exact)
#define BH_N    (NBUCK * NB1)  // 100096
#define GS_BLOCKS 98           // ceil(BH_N / 1024)
#define STAGE_CAP 6144         // LDS staging cap per bucket (mean 4092)
#define HIST_BLOCKS 196        // ceil(N_NODES / 256)

typedef __bf16 bf16;
typedef __bf16 bf16x2 __attribute__((ext_vector_type(2)));
typedef __bf16 bf16x4 __attribute__((ext_vector_type(4)));
typedef __bf16 bf16x8 __attribute__((ext_vector_type(8)));
typedef float  f32x4  __attribute__((ext_vector_type(4)));

#define GLOAD_LDS16(g, l)                                                          \
    __builtin_amdgcn_global_load_lds(                                              \
        (const __attribute__((address_space(1))) void*)(g),                        \
        (__attribute__((address_space(3))) void*)(l), 16, 0, 0)

// ---------------------------------------------------------------------------
// h0[n,:] = xlist[node_type[n]][local_idx[n], :]  (f32 -> bf16), 4 rows/block
__global__ __launch_bounds__(256) void group_input_k(
    const float* __restrict__ x0, const float* __restrict__ x1,
    const float* __restrict__ emb2, const int* __restrict__ ntype,
    const int* __restrict__ lidx, bf16* __restrict__ h)
{
    int row = blockIdx.x * 4 + (threadIdx.x >> 6);
    int lane = threadIdx.x & 63;
    if (row >= N_NODES) return;
    int t = ntype[row];
    int li = lidx[row];
    const float* src = (t == 0) ? x0 : (t == 1) ? x1 : emb2;
    float4 v = *reinterpret_cast<const float4*>(&src[(size_t)li * 256 + lane * 4]);
    bf16x4 o;
    o[0] = (bf16)v.x; o[1] = (bf16)v.y; o[2] = (bf16)v.z; o[3] = (bf16)v.w;
    *reinterpret_cast<bf16x4*>(&h[(size_t)row * 256 + lane * 4]) = o;
}

// ---------------------------------------------------------------------------
// CSR build phase 1: per-block LDS histogram over 391 dst-buckets.
__global__ __launch_bounds__(256) void bucket_hist_k(
    const int* __restrict__ ei, int* __restrict__ bh)
{
    __shared__ int lds[NBUCK];
    int t = threadIdx.x;
    for (int i = t; i < NBUCK; i += 256) lds[i] = 0;
    __syncthreads();
    int base = blockIdx.x * EPB;
    for (int i = t; i < EPB; i += 256) {
        int dst = ei[N_EDGES + base + i];
        atomicAdd(&lds[dst >> 7], 1);
    }
    __syncthreads();
    for (int i = t; i < NBUCK; i += 256) bh[i * NB1 + blockIdx.x] = lds[i];
}

// Generic two-level exclusive scan over n ints (1024/block).
__global__ __launch_bounds__(256) void gscan1_k(
    const int* __restrict__ in, int* __restrict__ outv,
    int* __restrict__ blksum, int n)
{
    __shared__ int lds[256];
    int base = blockIdx.x * 1024;
    int t = threadIdx.x;
    int vals[4]; int s = 0;
#pragma unroll
    for (int i = 0; i < 4; ++i) {
        int idx = base + t * 4 + i;
        vals[i] = (idx < n) ? in[idx] : 0;
        s += vals[i];
    }
    lds[t] = s;
    __syncthreads();
    for (int off = 1; off < 256; off <<= 1) {
        int v = (t >= off) ? lds[t - off] : 0;
        __syncthreads();
        lds[t] += v;
        __syncthreads();
    }
    int incl = lds[t];
    int ex = incl - s;
    if (t == 255) blksum[blockIdx.x] = incl;
    int run = ex;
#pragma unroll
    for (int i = 0; i < 4; ++i) {
        int idx = base + t * 4 + i;
        if (idx < n) outv[idx] = run;
        run += vals[i];
    }
}

__global__ __launch_bounds__(256) void gscan2_k(int* __restrict__ blksum, int nblk)
{
    __shared__ int lds[256];
    int t = threadIdx.x;
    int v = (t < nblk) ? blksum[t] : 0;
    lds[t] = v;
    __syncthreads();
    for (int off = 1; off < 256; off <<= 1) {
        int u = (t >= off) ? lds[t - off] : 0;
        __syncthreads();
        lds[t] += u;
        __syncthreads();
    }
    if (t < nblk) blksum[t] = lds[t] - v;
}

__global__ __launch_bounds__(256) void gfold_k(
    int* __restrict__ outv, const int* __restrict__ blksum, int n)
{
    int base = blockIdx.x * 1024 + threadIdx.x * 4;
    int b = blksum[blockIdx.x];
#pragma unroll
    for (int i = 0; i < 4; ++i) {
        int idx = base + i;
        if (idx < n) outv[idx] += b;
    }
}

// CSR build phase 2: scatter edges to bucket-contiguous ebuf via LDS cursors.
// ebuf[pos] = (src*R + r) in bits [0,18) | dst&127 in bits [25,32)
__global__ __launch_bounds__(256) void bucket_scatter_k(
    const int* __restrict__ ei, const int* __restrict__ et,
    const int* __restrict__ bhs, uint32_t* __restrict__ ebuf)
{
    __shared__ int cur[NBUCK];
    int t = threadIdx.x;
    for (int i = t; i < NBUCK; i += 256) cur[i] = bhs[i * NB1 + blockIdx.x];
    __syncthreads();
    int base = blockIdx.x * EPB;
    for (int i = t; i < EPB; i += 256) {
        int e = base + i;
        int src = ei[e];
        int dst = ei[N_EDGES + e];
        int r = et[e];
        int pos = atomicAdd(&cur[dst >> 7], 1);
        ebuf[pos] = (uint32_t)(src * R_REL + r) | ((uint32_t)(dst & 127) << 25);
    }
}

// CSR build phase 3: one block per bucket. LDS hist over 640 local segs,
// LDS scan, LDS-atomic ranks -> final pk (sr | cnt<<18) + per-node offsets.
__global__ __launch_bounds__(256) void bucket_rank_k(
    const uint32_t* __restrict__ ebuf, const int* __restrict__ bhs,
    uint32_t* __restrict__ pk, int* __restrict__ noff)
{
    __shared__ uint32_t se[STAGE_CAP];
    __shared__ int hist[640];
    __shared__ int cursor[640];
    __shared__ int sb[256];
    int t = threadIdx.x;
    int b = blockIdx.x;
    int start = bhs[b * NB1];
    int end = (b < NBUCK - 1) ? bhs[(b + 1) * NB1] : N_EDGES;
    int size = end - start;
    for (int i = t; i < 640; i += 256) hist[i] = 0;
    __syncthreads();
    for (int i = t; i < size; i += 256) {
        uint32_t v = ebuf[start + i];
        if (i < STAGE_CAP) se[i] = v;
        uint32_t sr = v & 0x3FFFFu;
        int r = (int)(sr % 5u);
        int seg = (int)(v >> 25) * R_REL + r;
        atomicAdd(&hist[seg], 1);
    }
    __syncthreads();
    // exclusive scan of hist[640] -> cursor = start + excl (3 bins/thread)
    int b0 = t * 3;
    int loc[3]; int s0 = 0;
#pragma unroll
    for (int j = 0; j < 3; ++j) {
        int idx = b0 + j;
        int v = (idx < 640) ? hist[idx] : 0;
        loc[j] = s0; s0 += v;
    }
    sb[t] = s0;
    __syncthreads();
    for (int off = 1; off < 256; off <<= 1) {
        int u = (t >= off) ? sb[t - off] : 0;
        __syncthreads();
        sb[t] += u;
        __syncthreads();
    }
    int pre = sb[t] - s0;
#pragma unroll
    for (int j = 0; j < 3; ++j) {
        int idx = b0 + j;
        if (idx < 640) cursor[idx] = start + pre + loc[j];
    }
    __syncthreads();
    if (t < 128) noff[b * 128 + t] = cursor[t * 5];
    if (b == NBUCK - 1 && t == 128) noff[M_PAD] = N_EDGES;
    __syncthreads();
    for (int i = t; i < size; i += 256) {
        uint32_t v = (i < STAGE_CAP) ? se[i] : ebuf[start + i];
        uint32_t sr = v & 0x3FFFFu;
        int r = (int)(sr % 5u);
        int seg = (int)(v >> 25) * R_REL + r;
        int pos = atomicAdd(&cursor[seg], 1);
        pk[pos] = sr | ((uint32_t)hist[seg] << 18);
    }
}

// ---------------------------------------------------------------------------
// Type partition: perm lists node ids sorted by type (stable by block).
__global__ __launch_bounds__(256) void typed_hist_k(
    const int* __restrict__ ntype, int* __restrict__ tcnt)
{
    __shared__ int c[3];
    if (threadIdx.x < 3) c[threadIdx.x] = 0;
    __syncthreads();
    int n = blockIdx.x * 256 + threadIdx.x;
    if (n < N_NODES) atomicAdd(&c[ntype[n]], 1);
    __syncthreads();
    if (threadIdx.x < 3) tcnt[threadIdx.x * HIST_BLOCKS + blockIdx.x] = c[threadIdx.x];
}

// scan over 3*196=588 values ordered (type, block); emit toff + meta
// meta[0..3]=typestart, meta[4..7]=block-chunk offsets, meta[8..10]=type counts
__global__ __launch_bounds__(1024) void typed_scan_k(
    const int* __restrict__ tcnt, int* __restrict__ toff, int* __restrict__ meta)
{
    __shared__ int lds[1024];
    int t = threadIdx.x;
    int v = (t < 3 * HIST_BLOCKS) ? tcnt[t] : 0;
    lds[t] = v;
    __syncthreads();
    for (int off = 1; off < 1024; off <<= 1) {
        int u = (t >= off) ? lds[t - off] : 0;
        __syncthreads();
        lds[t] += u;
        __syncthreads();
    }
    if (t < 3 * HIST_BLOCKS) toff[t] = lds[t] - v;
    if (t == 0) {
        int ts1 = lds[1 * HIST_BLOCKS - 1];
        int ts2 = lds[2 * HIST_BLOCKS - 1];
        int ts3 = lds[3 * HIST_BLOCKS - 1];
        meta[0] = 0; meta[1] = ts1; meta[2] = ts2; meta[3] = ts3;
        int c0 = ts1, c1 = ts2 - ts1, c2 = ts3 - ts2;
        meta[8] = c0; meta[9] = c1; meta[10] = c2;
        int b0 = (c0 + 127) >> 7, b1 = (c1 + 127) >> 7, b2 = (c2 + 127) >> 7;
        meta[4] = 0; meta[5] = b0; meta[6] = b0 + b1; meta[7] = b0 + b1 + b2;
    }
}

__global__ __launch_bounds__(256) void typed_scatter_k(
    const int* __restrict__ ntype, const int* __restrict__ toff,
    int* __restrict__ perm)
{
    __shared__ int cur[3];
    if (threadIdx.x < 3) cur[threadIdx.x] = 0;
    __syncthreads();
    int n = blockIdx.x * 256 + threadIdx.x;
    if (n < N_NODES) {
        int t = ntype[n];
        int rank = atomicAdd(&cur[t], 1);
        perm[toff[t * HIST_BLOCKS + blockIdx.x] + rank] = n;
    }
}

// ---------------------------------------------------------------------------
// Weight prep: Wt arranged [half][r][128][256]: row w = h*640 + r*128 + oo
// maps to relW[r][h*128+oo][:]. Rt = straight cast of rootW.
__global__ __launch_bounds__(256) void cast_w_k(
    const float* __restrict__ relW, const float* __restrict__ rootW,
    bf16* __restrict__ Wt, bf16* __restrict__ Rt, int Dout)
{
    int i = blockIdx.x * 256 + threadIdx.x;
    int relN = R_REL * Dout * 256;
    if (i < relN) {
        int d = i & 255;
        int w = i >> 8;
        int h = w / 640;
        int rem = w - h * 640;
        int r = rem >> 7;
        int o = h * 128 + (rem & 127);
        Wt[i] = (bf16)relW[((size_t)r * Dout + o) * 256 + d];
    }
    int rootN = 3 * Dout * 256;
    if (i < rootN) Rt[i] = (bf16)rootW[i];
}

// ---------------------------------------------------------------------------
// Y GEMM: Y[m, j] = sum_d h[m, d] * W[j, d]   (bf16 out, K=256, no row guard)
__global__ __launch_bounds__(256) void gemm_y_k(
    const bf16* __restrict__ A, const bf16* __restrict__ B,
    bf16* __restrict__ Y, int ldc)
{
    __shared__ bf16 As[128][64];
    __shared__ bf16 Bs[128][64];
    int tid = threadIdx.x;
    int lane = tid & 63, wave = tid >> 6;
    int wm = wave >> 1, wn = wave & 1;
    int m0 = blockIdx.x * 128, n0 = blockIdx.y * 128;

    f32x4 acc[4][4] = {};

    for (int kt = 0; kt < 4; ++kt) {
#pragma unroll
        for (int cc = 0; cc < 4; ++cc) {
            int linear = cc * 256 + tid;
            int row = linear >> 3, sl = linear & 7;
            const bf16* gA = &A[(size_t)(m0 + row) * 256 + kt * 64 + sl * 8];
            const bf16* gB = &B[(size_t)(n0 + row) * 256 + kt * 64 + sl * 8];
            char* sA = (char*)&As[0][0] + (size_t)(cc * 256 + wave * 64) * 16;
            char* sB = (char*)&Bs[0][0] + (size_t)(cc * 256 + wave * 64) * 16;
            GLOAD_LDS16(gA, sA);
            GLOAD_LDS16(gB, sB);
        }
        __syncthreads();
#pragma unroll
        for (int kk = 0; kk < 2; ++kk) {
            bf16x8 af[4], bfr[4];
            int k0 = kk * 32 + (lane >> 4) * 8;
#pragma unroll
            for (int i = 0; i < 4; ++i) {
                af[i]  = *reinterpret_cast<const bf16x8*>(&As[wm * 64 + i * 16 + (lane & 15)][k0]);
                bfr[i] = *reinterpret_cast<const bf16x8*>(&Bs[wn * 64 + i * 16 + (lane & 15)][k0]);
            }
#pragma unroll
            for (int i = 0; i < 4; ++i)
#pragma unroll
                for (int j = 0; j < 4; ++j)
                    acc[i][j] = __builtin_amdgcn_mfma_f32_16x16x32_bf16(af[i], bfr[j], acc[i][j], 0, 0, 0);
        }
        __syncthreads();
    }

#pragma unroll
    for (int i = 0; i < 4; ++i)
#pragma unroll
        for (int j = 0; j < 4; ++j)
#pragma unroll
            for (int r = 0; r < 4; ++r) {
                int row = m0 + wm * 64 + i * 16 + (lane >> 4) * 4 + r;
                int col = n0 + wn * 64 + j * 16 + (lane & 15);
                Y[(size_t)row * ldc + col] = (bf16)acc[i][j][r];
            }
}

// ---------------------------------------------------------------------------
// Gather-accumulate over one 128-wide column slab:
// Cb[n, lane*2..+1] = sum_e (1/cnt_e) * Y[idx_e, lane*2..+1]
// pk packs idx (18b) | cnt (14b); weight via v_rcp_f32 (1 ulp).
__global__ __launch_bounds__(256) void gather_k(
    const bf16* __restrict__ Y, const uint32_t* __restrict__ pk,
    const int* __restrict__ noff, bf16* __restrict__ Cb, int ldcb)
{
    int wave = threadIdx.x >> 6, lane = threadIdx.x & 63;
    int n = blockIdx.x * 4 + wave;
    if (n >= N_NODES) return;
    int off0 = noff[n];
    int off1 = noff[n + 1];
    int c = off1 - off0;

    float s0 = 0.f, s1 = 0.f;
    int e = 0;
    for (; e + 8 <= c; e += 8) {
        uint32_t w[8]; bf16x2 v[8];
#pragma unroll
        for (int j = 0; j < 8; ++j) w[j] = pk[off0 + e + j];
#pragma unroll
        for (int j = 0; j < 8; ++j)
            v[j] = *reinterpret_cast<const bf16x2*>(&Y[(size_t)(w[j] & 0x3FFFF) * 128 + lane * 2]);
#pragma unroll
        for (int j = 0; j < 8; ++j) {
            float ww = __builtin_amdgcn_rcpf((float)(w[j] >> 18));
            s0 += ww * (float)v[j][0];
            s1 += ww * (float)v[j][1];
        }
    }
    if (e + 4 <= c) {
        uint32_t w[4]; bf16x2 v[4];
#pragma unroll
        for (int j = 0; j < 4; ++j) w[j] = pk[off0 + e + j];
#pragma unroll
        for (int j = 0; j < 4; ++j)
            v[j] = *reinterpret_cast<const bf16x2*>(&Y[(size_t)(w[j] & 0x3FFFF) * 128 + lane * 2]);
#pragma unroll
        for (int j = 0; j < 4; ++j) {
            float ww = __builtin_amdgcn_rcpf((float)(w[j] >> 18));
            s0 += ww * (float)v[j][0];
            s1 += ww * (float)v[j][1];
        }
        e += 4;
    }
    for (; e < c; ++e) {
        uint32_t w = pk[off0 + e];
        bf16x2 v = *reinterpret_cast<const bf16x2*>(&Y[(size_t)(w & 0x3FFFF) * 128 + lane * 2]);
        float ww = __builtin_amdgcn_rcpf((float)(w >> 18));
        s0 += ww * (float)v[0];
        s1 += ww * (float)v[1];
    }

    bf16x2 o; o[0] = (bf16)s0; o[1] = (bf16)s1;
    *reinterpret_cast<bf16x2*>(&Cb[(size_t)n * ldcb + lane * 2]) = o;
}

// ---------------------------------------------------------------------------
// Root GEMM over type-sorted 128-row chunks: out = Cb[ri] + h[ri]@Rt[t]^T + b[t]
// relu_mode: ReLU + bf16 emit to hout; else fp32 emit to C (last layer).
__global__ __launch_bounds__(256) void gemm_root_k(
    const bf16* __restrict__ h, const bf16* __restrict__ Rt,
    const float* __restrict__ rootB, const int* __restrict__ perm,
    const int* __restrict__ meta, const bf16* __restrict__ Cb,
    float* __restrict__ C, bf16* __restrict__ hout, int Dout, int relu_mode)
{
    __shared__ bf16 As[128][64];
    __shared__ bf16 Bs[128][64];
    __shared__ int ridx[128];
    int tid = threadIdx.x;
    int bx = blockIdx.x;
    int b1 = meta[5], b2 = meta[6], b3 = meta[7];
    if (bx >= b3) return;
    int t = (bx >= b2) ? 2 : (bx >= b1 ? 1 : 0);
    int chunk = bx - (t == 2 ? b2 : (t == 1 ? b1 : 0));
    int tstart = meta[t];
    int tc = meta[8 + t];
    int rbase = chunk * 128;
    if (tid < 128) {
        int lr = rbase + tid;
        ridx[tid] = (lr < tc) ? perm[tstart + lr] : 0;
    }
    __syncthreads();

    int lane = tid & 63, wave = tid >> 6;
    int wm = wave >> 1, wn = wave & 1;
    int n0 = blockIdx.y * 128;
    const bf16* B = Rt + (size_t)t * Dout * 256;

    f32x4 acc[4][4] = {};

    for (int kt = 0; kt < 4; ++kt) {   // K = 256
#pragma unroll
        for (int cc = 0; cc < 4; ++cc) {
            int linear = cc * 256 + tid;
            int row = linear >> 3, sl = linear & 7;
            const bf16* gA = &h[(size_t)ridx[row] * 256 + kt * 64 + sl * 8];
            const bf16* gB = &B[(size_t)(n0 + row) * 256 + kt * 64 + sl * 8];
            char* sA = (char*)&As[0][0] + (size_t)(cc * 256 + wave * 64) * 16;
            char* sB = (char*)&Bs[0][0] + (size_t)(cc * 256 + wave * 64) * 16;
            GLOAD_LDS16(gA, sA);
            GLOAD_LDS16(gB, sB);
        }
        __syncthreads();
#pragma unroll
        for (int kk = 0; kk < 2; ++kk) {
            bf16x8 af[4], bfr[4];
            int k0 = kk * 32 + (lane >> 4) * 8;
#pragma unroll
            for (int i = 0; i < 4; ++i) {
                af[i]  = *reinterpret_cast<const bf16x8*>(&As[wm * 64 + i * 16 + (lane & 15)][k0]);
                bfr[i] = *reinterpret_cast<const bf16x8*>(&Bs[wn * 64 + i * 16 + (lane & 15)][k0]);
            }
#pragma unroll
            for (int i = 0; i < 4; ++i)
#pragma unroll
                for (int j = 0; j < 4; ++j)
                    acc[i][j] = __builtin_amdgcn_mfma_f32_16x16x32_bf16(af[i], bfr[j], acc[i][j], 0, 0, 0);
        }
        __syncthreads();
    }

#pragma unroll
    for (int i = 0; i < 4; ++i)
#pragma unroll
        for (int j = 0; j < 4; ++j)
#pragma unroll
            for (int r = 0; r < 4; ++r) {
                int rl = wm * 64 + i * 16 + (lane >> 4) * 4 + r;
                int col = n0 + wn * 64 + j * 16 + (lane & 15);
                if (rbase + rl < tc) {
                    int ri = ridx[rl];
                    float v = (float)Cb[(size_t)ri * Dout + col] + acc[i][j][r]
                              + rootB[t * Dout + col];
                    if (relu_mode)
                        hout[(size_t)ri * Dout + col] = (bf16)fmaxf(v, 0.f);
                    else
                        C[(size_t)ri * Dout + col] = v;
                }
            }
}

// ---------------------------------------------------------------------------
// Row-wise log_softmax over 128 logits; one wave per row.
__global__ __launch_bounds__(256) void logsoftmax_k(
    const float* __restrict__ C, float* __restrict__ out, int M)
{
    int row = blockIdx.x * 4 + (threadIdx.x >> 6);
    int lane = threadIdx.x & 63;
    if (row >= M) return;
    float v0 = C[(size_t)row * 128 + lane];
    float v1 = C[(size_t)row * 128 + 64 + lane];
    float m = fmaxf(v0, v1);
    for (int off = 32; off; off >>= 1) m = fmaxf(m, __shfl_xor(m, off));
    float s = expf(v0 - m) + expf(v1 - m);
    for (int off = 32; off; off >>= 1) s += __shfl_xor(s, off);
    float lse = m + logf(s);
    out[(size_t)row * 128 + lane] = v0 - lse;
    out[(size_t)row * 128 + 64 + lane] = v1 - lse;
}

// ---------------------------------------------------------------------------
extern "C" void kernel_launch(void* const* d_in, const int* in_sizes, int n_in,
                              void* d_out, int out_size, void* d_ws, size_t ws_size,
                              hipStream_t stream)
{
    const float* x0   = (const float*)d_in[0];
    const float* x1   = (const float*)d_in[1];
    const float* emb2 = (const float*)d_in[2];
    const int*   ei   = (const int*)d_in[3];
    const int*   et   = (const int*)d_in[4];
    const int*   ntyp = (const int*)d_in[5];
    const int*   lidx = (const int*)d_in[6];
    const float* relW[3]  = {(const float*)d_in[7],  (const float*)d_in[10], (const float*)d_in[13]};
    const float* rootW[3] = {(const float*)d_in[8],  (const float*)d_in[11], (const float*)d_in[14]};
    const float* rootB[3] = {(const float*)d_in[9],  (const float*)d_in[12], (const float*)d_in[15]};
    float* out = (float*)d_out;

    char* p = (char*)d_ws;
    auto carve = [&](size_t bytes) {
        char* q = p;
        p += (bytes + 255) & ~(size_t)255;
        return (void*)q;
    };
    bf16* h_a   = (bf16*)carve((size_t)M_PAD * 256 * 2);
    bf16* h_b   = (bf16*)carve((size_t)M_PAD * 256 * 2);
    bf16* Y     = (bf16*)carve((size_t)2 * M_PAD * 640 * 2);  // two 64 MB slabs
    bf16* Cb    = (bf16*)carve((size_t)M_PAD * 256 * 2);
    bf16* WtA   = (bf16*)carve((size_t)(2 * R_REL * 256 * 256 + R_REL * 128 * 256) * 2);
    bf16* RtA   = (bf16*)carve((size_t)(2 * 3 * 256 * 256 + 3 * 128 * 256) * 2);
    int* bh     = (int*)carve((size_t)BH_N * 4);
    int* bhs    = (int*)carve((size_t)BH_N * 4);
    int* gblk   = (int*)carve((size_t)256 * 4);
    uint32_t* ebuf = (uint32_t*)carve((size_t)N_EDGES * 4);
    uint32_t* pk   = (uint32_t*)carve((size_t)N_EDGES * 4);
    int* noff   = (int*)carve((size_t)(M_PAD + 1) * 4);
    int* tcnt   = (int*)carve((size_t)3 * HIST_BLOCKS * 4);
    int* toff   = (int*)carve((size_t)3 * HIST_BLOCKS * 4);
    int* meta   = (int*)carve((size_t)16 * 4);
    int* perm   = (int*)carve((size_t)N_NODES * 4);
    // fp32 logits buffer aliased into Y slab 1 (dead at layer 3, which uses
    // only slab 0 = 64.06 MB; C sits at +96 MB, needs 25.6 MB < 128.1 MB).
    float* C = (float*)((char*)Y + (size_t)96 * 1024 * 1024);

    bf16* Wt[3] = {WtA, WtA + (size_t)R_REL * 256 * 256, WtA + (size_t)2 * R_REL * 256 * 256};
    bf16* Rt[3] = {RtA, RtA + (size_t)3 * 256 * 256, RtA + (size_t)2 * 3 * 256 * 256};

    group_input_k<<<(N_NODES + 3) / 4, 256, 0, stream>>>(x0, x1, emb2, ntyp, lidx, h_a);
    // CSR build: bucket hist -> scan -> bucket scatter -> in-bucket rank
    bucket_hist_k<<<NB1, 256, 0, stream>>>(ei, bh);
    gscan1_k<<<GS_BLOCKS, 256, 0, stream>>>(bh, bhs, gblk, BH_N);
    gscan2_k<<<1, 256, 0, stream>>>(gblk, GS_BLOCKS);
    gfold_k<<<GS_BLOCKS, 256, 0, stream>>>(bhs, gblk, BH_N);
    bucket_scatter_k<<<NB1, 256, 0, stream>>>(ei, et, bhs, ebuf);
    bucket_rank_k<<<NBUCK, 256, 0, stream>>>(ebuf, bhs, pk, noff);
    typed_hist_k<<<HIST_BLOCKS, 256, 0, stream>>>(ntyp, tcnt);
    typed_scan_k<<<1, 1024, 0, stream>>>(tcnt, toff, meta);
    typed_scatter_k<<<HIST_BLOCKS, 256, 0, stream>>>(ntyp, toff, perm);
    // weight prep for all layers up-front (independent of activations)
    const int douts[3] = {256, 256, 128};
    for (int l = 0; l < 3; ++l)
        cast_w_k<<<(R_REL * douts[l] * 256 + 255) / 256, 256, 0, stream>>>(
            relW[l], rootW[l], Wt[l], Rt[l], douts[l]);

    bf16* cur = h_a;
    bf16* nxt = h_b;
    for (int l = 0; l < 3; ++l) {
        int Dout = douts[l];
        int NH = Dout / 128;
        for (int h = 0; h < NH; ++h) {
            bf16* Yh = Y + (size_t)h * M_PAD * 640;
            gemm_y_k<<<dim3(M_PAD / 128, 5), 256, 0, stream>>>(
                cur, Wt[l] + (size_t)h * 640 * 256, Yh, 640);
            gather_k<<<(N_NODES + 3) / 4, 256, 0, stream>>>(
                Yh, pk, noff, Cb + h * 128, Dout);
        }
        gemm_root_k<<<dim3(393, Dout / 128), 256, 0, stream>>>(
            cur, Rt[l], rootB[l], perm, meta, Cb, C, nxt, Dout, (l < 2) ? 1 : 0);
        bf16* tmp = cur; cur = nxt; nxt = tmp;
    }
    logsoftmax_k<<<(N_NODES + 3) / 4, 256, 0, stream>>>(C, out, N_NODES);
}

// Round 10
// 664.029 us; speedup vs baseline: 1.1692x; 1.0569x over previous
//
#include <hip/hip_runtime.h>
#include <hip/hip_bf16.h>
#include <stdint.h>

// Problem constants (fixed by reference setup)
#define N_NODES 50000
#define M_PAD   50048          // 391 * 128
#define N_EDGES 1600000
#define R_REL   5
#define NBUCK   391            // buckets of 128 dst nodes
#define NB1     256            // blocks in bucket hist/scatter
#define EPB     6250           // N_EDGES / NB1 (exact)
#define BH_N    (NBUCK * NB1)  // 100096
#define GS_BLOCKS 98           // ceil(BH_N / 1024)
#define STAGE_CAP 6144         // LDS staging cap per bucket (mean 4092)
#define HIST_BLOCKS 196        // ceil(N_NODES / 256)

typedef __bf16 bf16;
typedef __bf16 bf16x2 __attribute__((ext_vector_type(2)));
typedef __bf16 bf16x4 __attribute__((ext_vector_type(4)));
typedef __bf16 bf16x8 __attribute__((ext_vector_type(8)));
typedef float  f32x4  __attribute__((ext_vector_type(4)));

#define GLOAD_LDS16(g, l)                                                          \
    __builtin_amdgcn_global_load_lds(                                              \
        (const __attribute__((address_space(1))) void*)(g),                        \
        (__attribute__((address_space(3))) void*)(l), 16, 0, 0)

// ---------------------------------------------------------------------------
// h0[n,:] = xlist[node_type[n]][local_idx[n], :]  (f32 -> bf16), 4 rows/block
__global__ __launch_bounds__(256) void group_input_k(
    const float* __restrict__ x0, const float* __restrict__ x1,
    const float* __restrict__ emb2, const int* __restrict__ ntype,
    const int* __restrict__ lidx, bf16* __restrict__ h)
{
    int row = blockIdx.x * 4 + (threadIdx.x >> 6);
    int lane = threadIdx.x & 63;
    if (row >= N_NODES) return;
    int t = ntype[row];
    int li = lidx[row];
    const float* src = (t == 0) ? x0 : (t == 1) ? x1 : emb2;
    float4 v = *reinterpret_cast<const float4*>(&src[(size_t)li * 256 + lane * 4]);
    bf16x4 o;
    o[0] = (bf16)v.x; o[1] = (bf16)v.y; o[2] = (bf16)v.z; o[3] = (bf16)v.w;
    *reinterpret_cast<bf16x4*>(&h[(size_t)row * 256 + lane * 4]) = o;
}

// ---------------------------------------------------------------------------
// CSR build phase 1: per-block LDS histogram over 391 dst-buckets.
__global__ __launch_bounds__(256) void bucket_hist_k(
    const int* __restrict__ ei, int* __restrict__ bh)
{
    __shared__ int lds[NBUCK];
    int t = threadIdx.x;
    for (int i = t; i < NBUCK; i += 256) lds[i] = 0;
    __syncthreads();
    int base = blockIdx.x * EPB;
    for (int i = t; i < EPB; i += 256) {
        int dst = ei[N_EDGES + base + i];
        atomicAdd(&lds[dst >> 7], 1);
    }
    __syncthreads();
    for (int i = t; i < NBUCK; i += 256) bh[i * NB1 + blockIdx.x] = lds[i];
}

// Generic two-level exclusive scan over n ints (1024/block).
__global__ __launch_bounds__(256) void gscan1_k(
    const int* __restrict__ in, int* __restrict__ outv,
    int* __restrict__ blksum, int n)
{
    __shared__ int lds[256];
    int base = blockIdx.x * 1024;
    int t = threadIdx.x;
    int vals[4]; int s = 0;
#pragma unroll
    for (int i = 0; i < 4; ++i) {
        int idx = base + t * 4 + i;
        vals[i] = (idx < n) ? in[idx] : 0;
        s += vals[i];
    }
    lds[t] = s;
    __syncthreads();
    for (int off = 1; off < 256; off <<= 1) {
        int v = (t >= off) ? lds[t - off] : 0;
        __syncthreads();
        lds[t] += v;
        __syncthreads();
    }
    int incl = lds[t];
    int ex = incl - s;
    if (t == 255) blksum[blockIdx.x] = incl;
    int run = ex;
#pragma unroll
    for (int i = 0; i < 4; ++i) {
        int idx = base + t * 4 + i;
        if (idx < n) outv[idx] = run;
        run += vals[i];
    }
}

__global__ __launch_bounds__(256) void gscan2_k(int* __restrict__ blksum, int nblk)
{
    __shared__ int lds[256];
    int t = threadIdx.x;
    int v = (t < nblk) ? blksum[t] : 0;
    lds[t] = v;
    __syncthreads();
    for (int off = 1; off < 256; off <<= 1) {
        int u = (t >= off) ? lds[t - off] : 0;
        __syncthreads();
        lds[t] += u;
        __syncthreads();
    }
    if (t < nblk) blksum[t] = lds[t] - v;
}

__global__ __launch_bounds__(256) void gfold_k(
    int* __restrict__ outv, const int* __restrict__ blksum, int n)
{
    int base = blockIdx.x * 1024 + threadIdx.x * 4;
    int b = blksum[blockIdx.x];
#pragma unroll
    for (int i = 0; i < 4; ++i) {
        int idx = base + i;
        if (idx < n) outv[idx] += b;
    }
}

// CSR build phase 2: scatter edges to bucket-contiguous ebuf via LDS cursors.
// ebuf[pos] = (src*R + r) in bits [0,18) | dst&127 in bits [25,32)
__global__ __launch_bounds__(256) void bucket_scatter_k(
    const int* __restrict__ ei, const int* __restrict__ et,
    const int* __restrict__ bhs, uint32_t* __restrict__ ebuf)
{
    __shared__ int cur[NBUCK];
    int t = threadIdx.x;
    for (int i = t; i < NBUCK; i += 256) cur[i] = bhs[i * NB1 + blockIdx.x];
    __syncthreads();
    int base = blockIdx.x * EPB;
    for (int i = t; i < EPB; i += 256) {
        int e = base + i;
        int src = ei[e];
        int dst = ei[N_EDGES + e];
        int r = et[e];
        int pos = atomicAdd(&cur[dst >> 7], 1);
        ebuf[pos] = (uint32_t)(src * R_REL + r) | ((uint32_t)(dst & 127) << 25);
    }
}

// CSR build phase 3: one block per bucket. LDS hist over 640 local segs,
// LDS scan, LDS-atomic ranks -> final pk (sr | cnt<<18) + per-node offsets.
__global__ __launch_bounds__(256) void bucket_rank_k(
    const uint32_t* __restrict__ ebuf, const int* __restrict__ bhs,
    uint32_t* __restrict__ pk, int* __restrict__ noff)
{
    __shared__ uint32_t se[STAGE_CAP];
    __shared__ int hist[640];
    __shared__ int cursor[640];
    __shared__ int sb[256];
    int t = threadIdx.x;
    int b = blockIdx.x;
    int start = bhs[b * NB1];
    int end = (b < NBUCK - 1) ? bhs[(b + 1) * NB1] : N_EDGES;
    int size = end - start;
    for (int i = t; i < 640; i += 256) hist[i] = 0;
    __syncthreads();
    for (int i = t; i < size; i += 256) {
        uint32_t v = ebuf[start + i];
        if (i < STAGE_CAP) se[i] = v;
        uint32_t sr = v & 0x3FFFFu;
        int r = (int)(sr % 5u);
        int seg = (int)(v >> 25) * R_REL + r;
        atomicAdd(&hist[seg], 1);
    }
    __syncthreads();
    // exclusive scan of hist[640] -> cursor = start + excl (3 bins/thread)
    int b0 = t * 3;
    int loc[3]; int s0 = 0;
#pragma unroll
    for (int j = 0; j < 3; ++j) {
        int idx = b0 + j;
        int v = (idx < 640) ? hist[idx] : 0;
        loc[j] = s0; s0 += v;
    }
    sb[t] = s0;
    __syncthreads();
    for (int off = 1; off < 256; off <<= 1) {
        int u = (t >= off) ? sb[t - off] : 0;
        __syncthreads();
        sb[t] += u;
        __syncthreads();
    }
    int pre = sb[t] - s0;
#pragma unroll
    for (int j = 0; j < 3; ++j) {
        int idx = b0 + j;
        if (idx < 640) cursor[idx] = start + pre + loc[j];
    }
    __syncthreads();
    if (t < 128) noff[b * 128 + t] = cursor[t * 5];
    if (b == NBUCK - 1 && t == 128) noff[M_PAD] = N_EDGES;
    __syncthreads();
    for (int i = t; i < size; i += 256) {
        uint32_t v = (i < STAGE_CAP) ? se[i] : ebuf[start + i];
        uint32_t sr = v & 0x3FFFFu;
        int r = (int)(sr % 5u);
        int seg = (int)(v >> 25) * R_REL + r;
        int pos = atomicAdd(&cursor[seg], 1);
        pk[pos] = sr | ((uint32_t)hist[seg] << 18);
    }
}

// ---------------------------------------------------------------------------
// Type partition: perm lists node ids sorted by type (stable by block).
__global__ __launch_bounds__(256) void typed_hist_k(
    const int* __restrict__ ntype, int* __restrict__ tcnt)
{
    __shared__ int c[3];
    if (threadIdx.x < 3) c[threadIdx.x] = 0;
    __syncthreads();
    int n = blockIdx.x * 256 + threadIdx.x;
    if (n < N_NODES) atomicAdd(&c[ntype[n]], 1);
    __syncthreads();
    if (threadIdx.x < 3) tcnt[threadIdx.x * HIST_BLOCKS + blockIdx.x] = c[threadIdx.x];
}

// scan over 3*196=588 values ordered (type, block); emit toff + meta
// meta[0..3]=typestart, meta[4..7]=block-chunk offsets, meta[8..10]=type counts
__global__ __launch_bounds__(1024) void typed_scan_k(
    const int* __restrict__ tcnt, int* __restrict__ toff, int* __restrict__ meta)
{
    __shared__ int lds[1024];
    int t = threadIdx.x;
    int v = (t < 3 * HIST_BLOCKS) ? tcnt[t] : 0;
    lds[t] = v;
    __syncthreads();
    for (int off = 1; off < 1024; off <<= 1) {
        int u = (t >= off) ? lds[t - off] : 0;
        __syncthreads();
        lds[t] += u;
        __syncthreads();
    }
    if (t < 3 * HIST_BLOCKS) toff[t] = lds[t] - v;
    if (t == 0) {
        int ts1 = lds[1 * HIST_BLOCKS - 1];
        int ts2 = lds[2 * HIST_BLOCKS - 1];
        int ts3 = lds[3 * HIST_BLOCKS - 1];
        meta[0] = 0; meta[1] = ts1; meta[2] = ts2; meta[3] = ts3;
        int c0 = ts1, c1 = ts2 - ts1, c2 = ts3 - ts2;
        meta[8] = c0; meta[9] = c1; meta[10] = c2;
        int b0 = (c0 + 127) >> 7, b1 = (c1 + 127) >> 7, b2 = (c2 + 127) >> 7;
        meta[4] = 0; meta[5] = b0; meta[6] = b0 + b1; meta[7] = b0 + b1 + b2;
    }
}

__global__ __launch_bounds__(256) void typed_scatter_k(
    const int* __restrict__ ntype, const int* __restrict__ toff,
    int* __restrict__ perm)
{
    __shared__ int cur[3];
    if (threadIdx.x < 3) cur[threadIdx.x] = 0;
    __syncthreads();
    int n = blockIdx.x * 256 + threadIdx.x;
    if (n < N_NODES) {
        int t = ntype[n];
        int rank = atomicAdd(&cur[t], 1);
        perm[toff[t * HIST_BLOCKS + blockIdx.x] + rank] = n;
    }
}

// ---------------------------------------------------------------------------
// Weight prep: Wt arranged [half][r][128][256]: row w = h*640 + r*128 + oo
// maps to relW[r][h*128+oo][:]. Rt = straight cast of rootW.
__global__ __launch_bounds__(256) void cast_w_k(
    const float* __restrict__ relW, const float* __restrict__ rootW,
    bf16* __restrict__ Wt, bf16* __restrict__ Rt, int Dout)
{
    int i = blockIdx.x * 256 + threadIdx.x;
    int relN = R_REL * Dout * 256;
    if (i < relN) {
        int d = i & 255;
        int w = i >> 8;
        int h = w / 640;
        int rem = w - h * 640;
        int r = rem >> 7;
        int o = h * 128 + (rem & 127);
        Wt[i] = (bf16)relW[((size_t)r * Dout + o) * 256 + d];
    }
    int rootN = 3 * Dout * 256;
    if (i < rootN) Rt[i] = (bf16)rootW[i];
}

// ---------------------------------------------------------------------------
// Y GEMM: Y[m, j] = sum_d h[m, d] * W[j, d]   (bf16 out, K=256, no row guard)
// XCD-aware 1-D grid: bid = (m_local*5 + nt)*8 + xcd, m = xcd*49 + m_local.
// Each XCD owns a contiguous 49-m-tile range -> its A slice (3.2 MB) is
// L2-resident and the 5 same-A blocks run back-to-back on that XCD.
__global__ __launch_bounds__(256) void gemm_y_k(
    const bf16* __restrict__ A, const bf16* __restrict__ B,
    bf16* __restrict__ Y, int ldc)
{
    __shared__ bf16 As[128][64];
    __shared__ bf16 Bs[128][64];
    int bid = blockIdx.x;
    int xcd = bid & 7;
    int r2 = bid >> 3;
    int ml = r2 / 5, nt = r2 - ml * 5;
    int m = xcd * 49 + ml;
    if (m >= M_PAD / 128) return;
    int m0 = m * 128, n0 = nt * 128;
    int tid = threadIdx.x;
    int lane = tid & 63, wave = tid >> 6;
    int wm = wave >> 1, wn = wave & 1;

    f32x4 acc[4][4] = {};

    for (int kt = 0; kt < 4; ++kt) {
#pragma unroll
        for (int cc = 0; cc < 4; ++cc) {
            int linear = cc * 256 + tid;
            int row = linear >> 3, sl = linear & 7;
            const bf16* gA = &A[(size_t)(m0 + row) * 256 + kt * 64 + sl * 8];
            const bf16* gB = &B[(size_t)(n0 + row) * 256 + kt * 64 + sl * 8];
            char* sA = (char*)&As[0][0] + (size_t)(cc * 256 + wave * 64) * 16;
            char* sB = (char*)&Bs[0][0] + (size_t)(cc * 256 + wave * 64) * 16;
            GLOAD_LDS16(gA, sA);
            GLOAD_LDS16(gB, sB);
        }
        __syncthreads();
#pragma unroll
        for (int kk = 0; kk < 2; ++kk) {
            bf16x8 af[4], bfr[4];
            int k0 = kk * 32 + (lane >> 4) * 8;
#pragma unroll
            for (int i = 0; i < 4; ++i) {
                af[i]  = *reinterpret_cast<const bf16x8*>(&As[wm * 64 + i * 16 + (lane & 15)][k0]);
                bfr[i] = *reinterpret_cast<const bf16x8*>(&Bs[wn * 64 + i * 16 + (lane & 15)][k0]);
            }
#pragma unroll
            for (int i = 0; i < 4; ++i)
#pragma unroll
                for (int j = 0; j < 4; ++j)
                    acc[i][j] = __builtin_amdgcn_mfma_f32_16x16x32_bf16(af[i], bfr[j], acc[i][j], 0, 0, 0);
        }
        __syncthreads();
    }

#pragma unroll
    for (int i = 0; i < 4; ++i)
#pragma unroll
        for (int j = 0; j < 4; ++j)
#pragma unroll
            for (int r = 0; r < 4; ++r) {
                int row = m0 + wm * 64 + i * 16 + (lane >> 4) * 4 + r;
                int col = n0 + wn * 64 + j * 16 + (lane & 15);
                Y[(size_t)row * ldc + col] = (bf16)acc[i][j][r];
            }
}

// ---------------------------------------------------------------------------
// Gather-accumulate over one 128-wide column slab:
// Cb[n, lane*2..+1] = sum_e (1/cnt_e) * Y[idx_e, lane*2..+1]
// pk packs idx (18b) | cnt (14b); weight via v_rcp_f32 (1 ulp).
// 16 independent gathers in flight per wave.
__global__ __launch_bounds__(256) void gather_k(
    const bf16* __restrict__ Y, const uint32_t* __restrict__ pk,
    const int* __restrict__ noff, bf16* __restrict__ Cb, int ldcb)
{
    int wave = threadIdx.x >> 6, lane = threadIdx.x & 63;
    int n = blockIdx.x * 4 + wave;
    if (n >= N_NODES) return;
    int off0 = noff[n];
    int c = noff[n + 1] - off0;

    float s0 = 0.f, s1 = 0.f;
    int e = 0;
    for (; e + 16 <= c; e += 16) {
        uint32_t w[16]; bf16x2 v[16];
#pragma unroll
        for (int j = 0; j < 16; ++j) w[j] = pk[off0 + e + j];
#pragma unroll
        for (int j = 0; j < 16; ++j)
            v[j] = *reinterpret_cast<const bf16x2*>(&Y[(size_t)(w[j] & 0x3FFFF) * 128 + lane * 2]);
#pragma unroll
        for (int j = 0; j < 16; ++j) {
            float ww = __builtin_amdgcn_rcpf((float)(w[j] >> 18));
            s0 += ww * (float)v[j][0];
            s1 += ww * (float)v[j][1];
        }
    }
    if (e + 8 <= c) {
        uint32_t w[8]; bf16x2 v[8];
#pragma unroll
        for (int j = 0; j < 8; ++j) w[j] = pk[off0 + e + j];
#pragma unroll
        for (int j = 0; j < 8; ++j)
            v[j] = *reinterpret_cast<const bf16x2*>(&Y[(size_t)(w[j] & 0x3FFFF) * 128 + lane * 2]);
#pragma unroll
        for (int j = 0; j < 8; ++j) {
            float ww = __builtin_amdgcn_rcpf((float)(w[j] >> 18));
            s0 += ww * (float)v[j][0];
            s1 += ww * (float)v[j][1];
        }
        e += 8;
    }
    if (e + 4 <= c) {
        uint32_t w[4]; bf16x2 v[4];
#pragma unroll
        for (int j = 0; j < 4; ++j) w[j] = pk[off0 + e + j];
#pragma unroll
        for (int j = 0; j < 4; ++j)
            v[j] = *reinterpret_cast<const bf16x2*>(&Y[(size_t)(w[j] & 0x3FFFF) * 128 + lane * 2]);
#pragma unroll
        for (int j = 0; j < 4; ++j) {
            float ww = __builtin_amdgcn_rcpf((float)(w[j] >> 18));
            s0 += ww * (float)v[j][0];
            s1 += ww * (float)v[j][1];
        }
        e += 4;
    }
    for (; e < c; ++e) {
        uint32_t w = pk[off0 + e];
        bf16x2 v = *reinterpret_cast<const bf16x2*>(&Y[(size_t)(w & 0x3FFFF) * 128 + lane * 2]);
        float ww = __builtin_amdgcn_rcpf((float)(w >> 18));
        s0 += ww * (float)v[0];
        s1 += ww * (float)v[1];
    }

    bf16x2 o; o[0] = (bf16)s0; o[1] = (bf16)s1;
    *reinterpret_cast<bf16x2*>(&Cb[(size_t)n * ldcb + lane * 2]) = o;
}

// ---------------------------------------------------------------------------
// Root GEMM over type-sorted 128-row chunks: out = Cb[ri] + h[ri]@Rt[t]^T + b[t]
// relu_mode: ReLU + bf16 emit to hout; else fp32 emit to C (last layer).
__global__ __launch_bounds__(256) void gemm_root_k(
    const bf16* __restrict__ h, const bf16* __restrict__ Rt,
    const float* __restrict__ rootB, const int* __restrict__ perm,
    const int* __restrict__ meta, const bf16* __restrict__ Cb,
    float* __restrict__ C, bf16* __restrict__ hout, int Dout, int relu_mode)
{
    __shared__ bf16 As[128][64];
    __shared__ bf16 Bs[128][64];
    __shared__ int ridx[128];
    int tid = threadIdx.x;
    int bx = blockIdx.x;
    int b1 = meta[5], b2 = meta[6], b3 = meta[7];
    if (bx >= b3) return;
    int t = (bx >= b2) ? 2 : (bx >= b1 ? 1 : 0);
    int chunk = bx - (t == 2 ? b2 : (t == 1 ? b1 : 0));
    int tstart = meta[t];
    int tc = meta[8 + t];
    int rbase = chunk * 128;
    if (tid < 128) {
        int lr = rbase + tid;
        ridx[tid] = (lr < tc) ? perm[tstart + lr] : 0;
    }
    __syncthreads();

    int lane = tid & 63, wave = tid >> 6;
    int wm = wave >> 1, wn = wave & 1;
    int n0 = blockIdx.y * 128;
    const bf16* B = Rt + (size_t)t * Dout * 256;

    f32x4 acc[4][4] = {};

    for (int kt = 0; kt < 4; ++kt) {   // K = 256
#pragma unroll
        for (int cc = 0; cc < 4; ++cc) {
            int linear = cc * 256 + tid;
            int row = linear >> 3, sl = linear & 7;
            const bf16* gA = &h[(size_t)ridx[row] * 256 + kt * 64 + sl * 8];
            const bf16* gB = &B[(size_t)(n0 + row) * 256 + kt * 64 + sl * 8];
            char* sA = (char*)&As[0][0] + (size_t)(cc * 256 + wave * 64) * 16;
            char* sB = (char*)&Bs[0][0] + (size_t)(cc * 256 + wave * 64) * 16;
            GLOAD_LDS16(gA, sA);
            GLOAD_LDS16(gB, sB);
        }
        __syncthreads();
#pragma unroll
        for (int kk = 0; kk < 2; ++kk) {
            bf16x8 af[4], bfr[4];
            int k0 = kk * 32 + (lane >> 4) * 8;
#pragma unroll
            for (int i = 0; i < 4; ++i) {
                af[i]  = *reinterpret_cast<const bf16x8*>(&As[wm * 64 + i * 16 + (lane & 15)][k0]);
                bfr[i] = *reinterpret_cast<const bf16x8*>(&Bs[wn * 64 + i * 16 + (lane & 15)][k0]);
            }
#pragma unroll
            for (int i = 0; i < 4; ++i)
#pragma unroll
                for (int j = 0; j < 4; ++j)
                    acc[i][j] = __builtin_amdgcn_mfma_f32_16x16x32_bf16(af[i], bfr[j], acc[i][j], 0, 0, 0);
        }
        __syncthreads();
    }

#pragma unroll
    for (int i = 0; i < 4; ++i)
#pragma unroll
        for (int j = 0; j < 4; ++j)
#pragma unroll
            for (int r = 0; r < 4; ++r) {
                int rl = wm * 64 + i * 16 + (lane >> 4) * 4 + r;
                int col = n0 + wn * 64 + j * 16 + (lane & 15);
                if (rbase + rl < tc) {
                    int ri = ridx[rl];
                    float v = (float)Cb[(size_t)ri * Dout + col] + acc[i][j][r]
                              + rootB[t * Dout + col];
                    if (relu_mode)
                        hout[(size_t)ri * Dout + col] = (bf16)fmaxf(v, 0.f);
                    else
                        C[(size_t)ri * Dout + col] = v;
                }
            }
}

// ---------------------------------------------------------------------------
// Row-wise log_softmax over 128 logits; one wave per row.
__global__ __launch_bounds__(256) void logsoftmax_k(
    const float* __restrict__ C, float* __restrict__ out, int M)
{
    int row = blockIdx.x * 4 + (threadIdx.x >> 6);
    int lane = threadIdx.x & 63;
    if (row >= M) return;
    float v0 = C[(size_t)row * 128 + lane];
    float v1 = C[(size_t)row * 128 + 64 + lane];
    float m = fmaxf(v0, v1);
    for (int off = 32; off; off >>= 1) m = fmaxf(m, __shfl_xor(m, off));
    float s = expf(v0 - m) + expf(v1 - m);
    for (int off = 32; off; off >>= 1) s += __shfl_xor(s, off);
    float lse = m + logf(s);
    out[(size_t)row * 128 + lane] = v0 - lse;
    out[(size_t)row * 128 + 64 + lane] = v1 - lse;
}

// ---------------------------------------------------------------------------
extern "C" void kernel_launch(void* const* d_in, const int* in_sizes, int n_in,
                              void* d_out, int out_size, void* d_ws, size_t ws_size,
                              hipStream_t stream)
{
    const float* x0   = (const float*)d_in[0];
    const float* x1   = (const float*)d_in[1];
    const float* emb2 = (const float*)d_in[2];
    const int*   ei   = (const int*)d_in[3];
    const int*   et   = (const int*)d_in[4];
    const int*   ntyp = (const int*)d_in[5];
    const int*   lidx = (const int*)d_in[6];
    const float* relW[3]  = {(const float*)d_in[7],  (const float*)d_in[10], (const float*)d_in[13]};
    const float* rootW[3] = {(const float*)d_in[8],  (const float*)d_in[11], (const float*)d_in[14]};
    const float* rootB[3] = {(const float*)d_in[9],  (const float*)d_in[12], (const float*)d_in[15]};
    float* out = (float*)d_out;

    char* p = (char*)d_ws;
    auto carve = [&](size_t bytes) {
        char* q = p;
        p += (bytes + 255) & ~(size_t)255;
        return (void*)q;
    };
    bf16* h_a   = (bf16*)carve((size_t)M_PAD * 256 * 2);
    bf16* h_b   = (bf16*)carve((size_t)M_PAD * 256 * 2);
    bf16* Y     = (bf16*)carve((size_t)2 * M_PAD * 640 * 2);  // two 64 MB slabs
    bf16* Cb    = (bf16*)carve((size_t)M_PAD * 256 * 2);
    bf16* WtA   = (bf16*)carve((size_t)(2 * R_REL * 256 * 256 + R_REL * 128 * 256) * 2);
    bf16* RtA   = (bf16*)carve((size_t)(2 * 3 * 256 * 256 + 3 * 128 * 256) * 2);
    int* bh     = (int*)carve((size_t)BH_N * 4);
    int* bhs    = (int*)carve((size_t)BH_N * 4);
    int* gblk   = (int*)carve((size_t)256 * 4);
    uint32_t* ebuf = (uint32_t*)carve((size_t)N_EDGES * 4);
    uint32_t* pk   = (uint32_t*)carve((size_t)N_EDGES * 4);
    int* noff   = (int*)carve((size_t)(M_PAD + 1) * 4);
    int* tcnt   = (int*)carve((size_t)3 * HIST_BLOCKS * 4);
    int* toff   = (int*)carve((size_t)3 * HIST_BLOCKS * 4);
    int* meta   = (int*)carve((size_t)16 * 4);
    int* perm   = (int*)carve((size_t)N_NODES * 4);
    // fp32 logits buffer aliased into Y slab 1 (dead at layer 3, which uses
    // only slab 0 = 64.06 MB; C sits at +96 MB, needs 25.6 MB < 128.1 MB).
    float* C = (float*)((char*)Y + (size_t)96 * 1024 * 1024);

    bf16* Wt[3] = {WtA, WtA + (size_t)R_REL * 256 * 256, WtA + (size_t)2 * R_REL * 256 * 256};
    bf16* Rt[3] = {RtA, RtA + (size_t)3 * 256 * 256, RtA + (size_t)2 * 3 * 256 * 256};

    group_input_k<<<(N_NODES + 3) / 4, 256, 0, stream>>>(x0, x1, emb2, ntyp, lidx, h_a);
    // CSR build: bucket hist -> scan -> bucket scatter -> in-bucket rank
    bucket_hist_k<<<NB1, 256, 0, stream>>>(ei, bh);
    gscan1_k<<<GS_BLOCKS, 256, 0, stream>>>(bh, bhs, gblk, BH_N);
    gscan2_k<<<1, 256, 0, stream>>>(gblk, GS_BLOCKS);
    gfold_k<<<GS_BLOCKS, 256, 0, stream>>>(bhs, gblk, BH_N);
    bucket_scatter_k<<<NB1, 256, 0, stream>>>(ei, et, bhs, ebuf);
    bucket_rank_k<<<NBUCK, 256, 0, stream>>>(ebuf, bhs, pk, noff);
    typed_hist_k<<<HIST_BLOCKS, 256, 0, stream>>>(ntyp, tcnt);
    typed_scan_k<<<1, 1024, 0, stream>>>(tcnt, toff, meta);
    typed_scatter_k<<<HIST_BLOCKS, 256, 0, stream>>>(ntyp, toff, perm);
    // weight prep for all layers up-front (independent of activations)
    const int douts[3] = {256, 256, 128};
    for (int l = 0; l < 3; ++l)
        cast_w_k<<<(R_REL * douts[l] * 256 + 255) / 256, 256, 0, stream>>>(
            relW[l], rootW[l], Wt[l], Rt[l], douts[l]);

    bf16* cur = h_a;
    bf16* nxt = h_b;
    for (int l = 0; l < 3; ++l) {
        int Dout = douts[l];
        int NH = Dout / 128;
        for (int h = 0; h < NH; ++h) {
            bf16* Yh = Y + (size_t)h * M_PAD * 640;
            gemm_y_k<<<49 * 5 * 8, 256, 0, stream>>>(
                cur, Wt[l] + (size_t)h * 640 * 256, Yh, 640);
            gather_k<<<(N_NODES + 3) / 4, 256, 0, stream>>>(
                Yh, pk, noff, Cb + h * 128, Dout);
        }
        gemm_root_k<<<dim3(393, Dout / 128), 256, 0, stream>>>(
            cur, Rt[l], rootB[l], perm, meta, Cb, C, nxt, Dout, (l < 2) ? 1 : 0);
        bf16* tmp = cur; cur = nxt; nxt = tmp;
    }
    logsoftmax_k<<<(N_NODES + 3) / 4, 256, 0, stream>>>(C, out, N_NODES);
}

// Round 12
// 525.482 us; speedup vs baseline: 1.4774x; 1.2637x over previous
//
#include <hip/hip_runtime.h>
#include <hip/hip_bf16.h>
#include <hip/hip_fp8.h>
#include <stdint.h>

// Problem constants (fixed by reference setup)
#define N_NODES 50000
#define M_PAD   50048          // 391 * 128
#define N_EDGES 1600000
#define R_REL   5
#define NBUCK   391            // buckets of 128 dst nodes
#define NB1     256            // blocks in bucket hist/scatter
#define EPB     6250           // N_EDGES / NB1 (exact)
#define BH_N    (NBUCK * NB1)  // 100096
#define GS_BLOCKS 98           // ceil(BH_N / 1024)
#define STAGE_CAP 6144         // LDS staging cap per bucket (mean 4092)
#define HIST_BLOCKS 196        // ceil(N_NODES / 256)

typedef __bf16 bf16;
typedef __bf16 bf16x2 __attribute__((ext_vector_type(2)));
typedef __bf16 bf16x4 __attribute__((ext_vector_type(4)));
typedef __bf16 bf16x8 __attribute__((ext_vector_type(8)));
typedef float  f32x2  __attribute__((ext_vector_type(2)));
typedef float  f32x4  __attribute__((ext_vector_type(4)));

#define GLOAD_LDS16(g, l)                                                          \
    __builtin_amdgcn_global_load_lds(                                              \
        (const __attribute__((address_space(1))) void*)(g),                        \
        (__attribute__((address_space(3))) void*)(l), 16, 0, 0)

__device__ __forceinline__ uint8_t f32_to_fp8(float f) {
    return __hip_fp8_e4m3(f).__x;
}
__device__ __forceinline__ float fp8_to_f32(uint32_t b) {
    __hip_fp8_e4m3 v; v.__x = (uint8_t)b; return (float)v;
}

__device__ __forceinline__ void fp8_accum4(uint32_t bits, float ww, float* s) {
#if __has_builtin(__builtin_amdgcn_cvt_pk_f32_fp8)
    f32x2 lo = __builtin_amdgcn_cvt_pk_f32_fp8((int)bits, false);
    f32x2 hi = __builtin_amdgcn_cvt_pk_f32_fp8((int)bits, true);
    s[0] += ww * lo[0]; s[1] += ww * lo[1];
    s[2] += ww * hi[0]; s[3] += ww * hi[1];
#else
    s[0] += ww * fp8_to_f32(bits & 0xFF);
    s[1] += ww * fp8_to_f32((bits >> 8) & 0xFF);
    s[2] += ww * fp8_to_f32((bits >> 16) & 0xFF);
    s[3] += ww * fp8_to_f32(bits >> 24);
#endif
}

// ---------------------------------------------------------------------------
// h0[n,:] = xlist[node_type[n]][local_idx[n], :]  (f32 -> bf16), 4 rows/block
__global__ __launch_bounds__(256) void group_input_k(
    const float* __restrict__ x0, const float* __restrict__ x1,
    const float* __restrict__ emb2, const int* __restrict__ ntype,
    const int* __restrict__ lidx, bf16* __restrict__ h)
{
    int row = blockIdx.x * 4 + (threadIdx.x >> 6);
    int lane = threadIdx.x & 63;
    if (row >= N_NODES) return;
    int t = ntype[row];
    int li = lidx[row];
    const float* src = (t == 0) ? x0 : (t == 1) ? x1 : emb2;
    float4 v = *reinterpret_cast<const float4*>(&src[(size_t)li * 256 + lane * 4]);
    bf16x4 o;
    o[0] = (bf16)v.x; o[1] = (bf16)v.y; o[2] = (bf16)v.z; o[3] = (bf16)v.w;
    *reinterpret_cast<bf16x4*>(&h[(size_t)row * 256 + lane * 4]) = o;
}

// ---------------------------------------------------------------------------
// CSR build phase 1: per-block LDS histogram over 391 dst-buckets.
__global__ __launch_bounds__(256) void bucket_hist_k(
    const int* __restrict__ ei, int* __restrict__ bh)
{
    __shared__ int lds[NBUCK];
    int t = threadIdx.x;
    for (int i = t; i < NBUCK; i += 256) lds[i] = 0;
    __syncthreads();
    int base = blockIdx.x * EPB;
    for (int i = t; i < EPB; i += 256) {
        int dst = ei[N_EDGES + base + i];
        atomicAdd(&lds[dst >> 7], 1);
    }
    __syncthreads();
    for (int i = t; i < NBUCK; i += 256) bh[i * NB1 + blockIdx.x] = lds[i];
}

// Generic two-level exclusive scan over n ints (1024/block).
__global__ __launch_bounds__(256) void gscan1_k(
    const int* __restrict__ in, int* __restrict__ outv,
    int* __restrict__ blksum, int n)
{
    __shared__ int lds[256];
    int base = blockIdx.x * 1024;
    int t = threadIdx.x;
    int vals[4]; int s = 0;
#pragma unroll
    for (int i = 0; i < 4; ++i) {
        int idx = base + t * 4 + i;
        vals[i] = (idx < n) ? in[idx] : 0;
        s += vals[i];
    }
    lds[t] = s;
    __syncthreads();
    for (int off = 1; off < 256; off <<= 1) {
        int v = (t >= off) ? lds[t - off] : 0;
        __syncthreads();
        lds[t] += v;
        __syncthreads();
    }
    int incl = lds[t];
    int ex = incl - s;
    if (t == 255) blksum[blockIdx.x] = incl;
    int run = ex;
#pragma unroll
    for (int i = 0; i < 4; ++i) {
        int idx = base + t * 4 + i;
        if (idx < n) outv[idx] = run;
        run += vals[i];
    }
}

__global__ __launch_bounds__(256) void gscan2_k(int* __restrict__ blksum, int nblk)
{
    __shared__ int lds[256];
    int t = threadIdx.x;
    int v = (t < nblk) ? blksum[t] : 0;
    lds[t] = v;
    __syncthreads();
    for (int off = 1; off < 256; off <<= 1) {
        int u = (t >= off) ? lds[t - off] : 0;
        __syncthreads();
        lds[t] += u;
        __syncthreads();
    }
    if (t < nblk) blksum[t] = lds[t] - v;
}

__global__ __launch_bounds__(256) void gfold_k(
    int* __restrict__ outv, const int* __restrict__ blksum, int n)
{
    int base = blockIdx.x * 1024 + threadIdx.x * 4;
    int b = blksum[blockIdx.x];
#pragma unroll
    for (int i = 0; i < 4; ++i) {
        int idx = base + i;
        if (idx < n) outv[idx] += b;
    }
}

// CSR build phase 2: scatter edges to bucket-contiguous ebuf via LDS cursors.
// ebuf[pos] = (src*R + r) in bits [0,18) | dst&127 in bits [25,32)
__global__ __launch_bounds__(256) void bucket_scatter_k(
    const int* __restrict__ ei, const int* __restrict__ et,
    const int* __restrict__ bhs, uint32_t* __restrict__ ebuf)
{
    __shared__ int cur[NBUCK];
    int t = threadIdx.x;
    for (int i = t; i < NBUCK; i += 256) cur[i] = bhs[i * NB1 + blockIdx.x];
    __syncthreads();
    int base = blockIdx.x * EPB;
    for (int i = t; i < EPB; i += 256) {
        int e = base + i;
        int src = ei[e];
        int dst = ei[N_EDGES + e];
        int r = et[e];
        int pos = atomicAdd(&cur[dst >> 7], 1);
        ebuf[pos] = (uint32_t)(src * R_REL + r) | ((uint32_t)(dst & 127) << 25);
    }
}

// CSR build phase 3: one block per bucket. LDS hist over 640 local segs,
// LDS scan, LDS-atomic ranks -> final pk (sr | cnt<<18) + per-node offsets.
__global__ __launch_bounds__(256) void bucket_rank_k(
    const uint32_t* __restrict__ ebuf, const int* __restrict__ bhs,
    uint32_t* __restrict__ pk, int* __restrict__ noff)
{
    __shared__ uint32_t se[STAGE_CAP];
    __shared__ int hist[640];
    __shared__ int cursor[640];
    __shared__ int sb[256];
    int t = threadIdx.x;
    int b = blockIdx.x;
    int start = bhs[b * NB1];
    int end = (b < NBUCK - 1) ? bhs[(b + 1) * NB1] : N_EDGES;
    int size = end - start;
    for (int i = t; i < 640; i += 256) hist[i] = 0;
    __syncthreads();
    for (int i = t; i < size; i += 256) {
        uint32_t v = ebuf[start + i];
        if (i < STAGE_CAP) se[i] = v;
        uint32_t sr = v & 0x3FFFFu;
        int r = (int)(sr % 5u);
        int seg = (int)(v >> 25) * R_REL + r;
        atomicAdd(&hist[seg], 1);
    }
    __syncthreads();
    // exclusive scan of hist[640] -> cursor = start + excl (3 bins/thread)
    int b0 = t * 3;
    int loc[3]; int s0 = 0;
#pragma unroll
    for (int j = 0; j < 3; ++j) {
        int idx = b0 + j;
        int v = (idx < 640) ? hist[idx] : 0;
        loc[j] = s0; s0 += v;
    }
    sb[t] = s0;
    __syncthreads();
    for (int off = 1; off < 256; off <<= 1) {
        int u = (t >= off) ? sb[t - off] : 0;
        __syncthreads();
        sb[t] += u;
        __syncthreads();
    }
    int pre = sb[t] - s0;
#pragma unroll
    for (int j = 0; j < 3; ++j) {
        int idx = b0 + j;
        if (idx < 640) cursor[idx] = start + pre + loc[j];
    }
    __syncthreads();
    if (t < 128) noff[b * 128 + t] = cursor[t * 5];
    if (b == NBUCK - 1 && t == 128) noff[M_PAD] = N_EDGES;
    __syncthreads();
    for (int i = t; i < size; i += 256) {
        uint32_t v = (i < STAGE_CAP) ? se[i] : ebuf[start + i];
        uint32_t sr = v & 0x3FFFFu;
        int r = (int)(sr % 5u);
        int seg = (int)(v >> 25) * R_REL + r;
        int pos = atomicAdd(&cursor[seg], 1);
        pk[pos] = sr | ((uint32_t)hist[seg] << 18);
    }
}

// ---------------------------------------------------------------------------
// Type partition: perm lists node ids sorted by type (stable by block).
__global__ __launch_bounds__(256) void typed_hist_k(
    const int* __restrict__ ntype, int* __restrict__ tcnt)
{
    __shared__ int c[3];
    if (threadIdx.x < 3) c[threadIdx.x] = 0;
    __syncthreads();
    int n = blockIdx.x * 256 + threadIdx.x;
    if (n < N_NODES) atomicAdd(&c[ntype[n]], 1);
    __syncthreads();
    if (threadIdx.x < 3) tcnt[threadIdx.x * HIST_BLOCKS + blockIdx.x] = c[threadIdx.x];
}

// scan over 3*196=588 values ordered (type, block); emit toff + meta
__global__ __launch_bounds__(1024) void typed_scan_k(
    const int* __restrict__ tcnt, int* __restrict__ toff, int* __restrict__ meta)
{
    __shared__ int lds[1024];
    int t = threadIdx.x;
    int v = (t < 3 * HIST_BLOCKS) ? tcnt[t] : 0;
    lds[t] = v;
    __syncthreads();
    for (int off = 1; off < 1024; off <<= 1) {
        int u = (t >= off) ? lds[t - off] : 0;
        __syncthreads();
        lds[t] += u;
        __syncthreads();
    }
    if (t < 3 * HIST_BLOCKS) toff[t] = lds[t] - v;
    if (t == 0) {
        int ts1 = lds[1 * HIST_BLOCKS - 1];
        int ts2 = lds[2 * HIST_BLOCKS - 1];
        int ts3 = lds[3 * HIST_BLOCKS - 1];
        meta[0] = 0; meta[1] = ts1; meta[2] = ts2; meta[3] = ts3;
        int c0 = ts1, c1 = ts2 - ts1, c2 = ts3 - ts2;
        meta[8] = c0; meta[9] = c1; meta[10] = c2;
        int b0 = (c0 + 127) >> 7, b1 = (c1 + 127) >> 7, b2 = (c2 + 127) >> 7;
        meta[4] = 0; meta[5] = b0; meta[6] = b0 + b1; meta[7] = b0 + b1 + b2;
    }
}

__global__ __launch_bounds__(256) void typed_scatter_k(
    const int* __restrict__ ntype, const int* __restrict__ toff,
    int* __restrict__ perm)
{
    __shared__ int cur[3];
    if (threadIdx.x < 3) cur[threadIdx.x] = 0;
    __syncthreads();
    int n = blockIdx.x * 256 + threadIdx.x;
    if (n < N_NODES) {
        int t = ntype[n];
        int rank = atomicAdd(&cur[t], 1);
        perm[toff[t * HIST_BLOCKS + blockIdx.x] + rank] = n;
    }
}

// ---------------------------------------------------------------------------
// Weight cast: Wt = bf16(relW) (already [R*Dout][256] row-major), Rt = bf16(rootW).
__global__ __launch_bounds__(256) void cast_w_k(
    const float* __restrict__ relW, const float* __restrict__ rootW,
    bf16* __restrict__ Wt, bf16* __restrict__ Rt, int relN, int rootN)
{
    int i = blockIdx.x * 256 + threadIdx.x;
    if (i < relN)  Wt[i] = (bf16)relW[i];
    if (i < rootN) Rt[i] = (bf16)rootW[i];
}

// ---------------------------------------------------------------------------
// Y GEMM fp8-out: Y[m, j] = fp8(sum_d h[m, d] * W[j, d])  (K=256)
// XCD-aware 1-D grid: bid = (ml*NT + nt)*8 + xcd, m = xcd*49 + ml.
__global__ __launch_bounds__(256) void gemm_y_f8_k(
    const bf16* __restrict__ A, const bf16* __restrict__ B,
    uint8_t* __restrict__ Y, int ldc, int NT)
{
    __shared__ bf16 As[128][64];
    __shared__ bf16 Bs[128][64];
    int bid = blockIdx.x;
    int xcd = bid & 7;
    int r2 = bid >> 3;
    int ml = r2 / NT, nt = r2 - ml * NT;
    int m = xcd * 49 + ml;
    if (m >= M_PAD / 128) return;
    int m0 = m * 128, n0 = nt * 128;
    int tid = threadIdx.x;
    int lane = tid & 63, wave = tid >> 6;
    int wm = wave >> 1, wn = wave & 1;

    f32x4 acc[4][4] = {};

    for (int kt = 0; kt < 4; ++kt) {
#pragma unroll
        for (int cc = 0; cc < 4; ++cc) {
            int linear = cc * 256 + tid;
            int row = linear >> 3, sl = linear & 7;
            const bf16* gA = &A[(size_t)(m0 + row) * 256 + kt * 64 + sl * 8];
            const bf16* gB = &B[(size_t)(n0 + row) * 256 + kt * 64 + sl * 8];
            char* sA = (char*)&As[0][0] + (size_t)(cc * 256 + wave * 64) * 16;
            char* sB = (char*)&Bs[0][0] + (size_t)(cc * 256 + wave * 64) * 16;
            GLOAD_LDS16(gA, sA);
            GLOAD_LDS16(gB, sB);
        }
        __syncthreads();
#pragma unroll
        for (int kk = 0; kk < 2; ++kk) {
            bf16x8 af[4], bfr[4];
            int k0 = kk * 32 + (lane >> 4) * 8;
#pragma unroll
            for (int i = 0; i < 4; ++i) {
                af[i]  = *reinterpret_cast<const bf16x8*>(&As[wm * 64 + i * 16 + (lane & 15)][k0]);
                bfr[i] = *reinterpret_cast<const bf16x8*>(&Bs[wn * 64 + i * 16 + (lane & 15)][k0]);
            }
#pragma unroll
            for (int i = 0; i < 4; ++i)
#pragma unroll
                for (int j = 0; j < 4; ++j)
                    acc[i][j] = __builtin_amdgcn_mfma_f32_16x16x32_bf16(af[i], bfr[j], acc[i][j], 0, 0, 0);
        }
        __syncthreads();
    }

#pragma unroll
    for (int i = 0; i < 4; ++i)
#pragma unroll
        for (int j = 0; j < 4; ++j)
#pragma unroll
            for (int r = 0; r < 4; ++r) {
                int row = m0 + wm * 64 + i * 16 + (lane >> 4) * 4 + r;
                int col = n0 + wn * 64 + j * 16 + (lane & 15);
                Y[(size_t)row * ldc + col] = f32_to_fp8(acc[i][j][r]);
            }
}

// Y GEMM bf16-out (layer 3): same structure, bf16 store.
__global__ __launch_bounds__(256) void gemm_y_bf_k(
    const bf16* __restrict__ A, const bf16* __restrict__ B,
    bf16* __restrict__ Y, int ldc, int NT)
{
    __shared__ bf16 As[128][64];
    __shared__ bf16 Bs[128][64];
    int bid = blockIdx.x;
    int xcd = bid & 7;
    int r2 = bid >> 3;
    int ml = r2 / NT, nt = r2 - ml * NT;
    int m = xcd * 49 + ml;
    if (m >= M_PAD / 128) return;
    int m0 = m * 128, n0 = nt * 128;
    int tid = threadIdx.x;
    int lane = tid & 63, wave = tid >> 6;
    int wm = wave >> 1, wn = wave & 1;

    f32x4 acc[4][4] = {};

    for (int kt = 0; kt < 4; ++kt) {
#pragma unroll
        for (int cc = 0; cc < 4; ++cc) {
            int linear = cc * 256 + tid;
            int row = linear >> 3, sl = linear & 7;
            const bf16* gA = &A[(size_t)(m0 + row) * 256 + kt * 64 + sl * 8];
            const bf16* gB = &B[(size_t)(n0 + row) * 256 + kt * 64 + sl * 8];
            char* sA = (char*)&As[0][0] + (size_t)(cc * 256 + wave * 64) * 16;
            char* sB = (char*)&Bs[0][0] + (size_t)(cc * 256 + wave * 64) * 16;
            GLOAD_LDS16(gA, sA);
            GLOAD_LDS16(gB, sB);
        }
        __syncthreads();
#pragma unroll
        for (int kk = 0; kk < 2; ++kk) {
            bf16x8 af[4], bfr[4];
            int k0 = kk * 32 + (lane >> 4) * 8;
#pragma unroll
            for (int i = 0; i < 4; ++i) {
                af[i]  = *reinterpret_cast<const bf16x8*>(&As[wm * 64 + i * 16 + (lane & 15)][k0]);
                bfr[i] = *reinterpret_cast<const bf16x8*>(&Bs[wn * 64 + i * 16 + (lane & 15)][k0]);
            }
#pragma unroll
            for (int i = 0; i < 4; ++i)
#pragma unroll
                for (int j = 0; j < 4; ++j)
                    acc[i][j] = __builtin_amdgcn_mfma_f32_16x16x32_bf16(af[i], bfr[j], acc[i][j], 0, 0, 0);
        }
        __syncthreads();
    }

#pragma unroll
    for (int i = 0; i < 4; ++i)
#pragma unroll
        for (int j = 0; j < 4; ++j)
#pragma unroll
            for (int r = 0; r < 4; ++r) {
                int row = m0 + wm * 64 + i * 16 + (lane >> 4) * 4 + r;
                int col = n0 + wn * 64 + j * 16 + (lane & 15);
                Y[(size_t)row * ldc + col] = (bf16)acc[i][j][r];
            }
}

// ---------------------------------------------------------------------------
// fp8 gather, Dout=256 full width: Cb[n,:] = sum_e (1/cnt_e) * dq(Y[idx_e,:])
__global__ __launch_bounds__(256) void gather_f8_k(
    const uint8_t* __restrict__ Y, const uint32_t* __restrict__ pk,
    const int* __restrict__ noff, bf16* __restrict__ Cb)
{
    int wave = threadIdx.x >> 6, lane = threadIdx.x & 63;
    int n = blockIdx.x * 4 + wave;
    if (n >= N_NODES) return;
    int off0 = noff[n];
    int c = noff[n + 1] - off0;

    float s[4] = {};
    int e = 0;
    for (; e + 16 <= c; e += 16) {
        uint32_t w[16]; uint32_t v[16];
#pragma unroll
        for (int j = 0; j < 16; ++j) w[j] = pk[off0 + e + j];
#pragma unroll
        for (int j = 0; j < 16; ++j)
            v[j] = *reinterpret_cast<const uint32_t*>(&Y[(size_t)(w[j] & 0x3FFFF) * 256 + lane * 4]);
#pragma unroll
        for (int j = 0; j < 16; ++j) {
            float ww = __builtin_amdgcn_rcpf((float)(w[j] >> 18));
            fp8_accum4(v[j], ww, s);
        }
    }
    if (e + 8 <= c) {
        uint32_t w[8]; uint32_t v[8];
#pragma unroll
        for (int j = 0; j < 8; ++j) w[j] = pk[off0 + e + j];
#pragma unroll
        for (int j = 0; j < 8; ++j)
            v[j] = *reinterpret_cast<const uint32_t*>(&Y[(size_t)(w[j] & 0x3FFFF) * 256 + lane * 4]);
#pragma unroll
        for (int j = 0; j < 8; ++j) {
            float ww = __builtin_amdgcn_rcpf((float)(w[j] >> 18));
            fp8_accum4(v[j], ww, s);
        }
        e += 8;
    }
    if (e + 4 <= c) {
        uint32_t w[4]; uint32_t v[4];
#pragma unroll
        for (int j = 0; j < 4; ++j) w[j] = pk[off0 + e + j];
#pragma unroll
        for (int j = 0; j < 4; ++j)
            v[j] = *reinterpret_cast<const uint32_t*>(&Y[(size_t)(w[j] & 0x3FFFF) * 256 + lane * 4]);
#pragma unroll
        for (int j = 0; j < 4; ++j) {
            float ww = __builtin_amdgcn_rcpf((float)(w[j] >> 18));
            fp8_accum4(v[j], ww, s);
        }
        e += 4;
    }
    for (; e < c; ++e) {
        uint32_t w = pk[off0 + e];
        uint32_t v = *reinterpret_cast<const uint32_t*>(&Y[(size_t)(w & 0x3FFFF) * 256 + lane * 4]);
        float ww = __builtin_amdgcn_rcpf((float)(w >> 18));
        fp8_accum4(v, ww, s);
    }

    bf16x4 o;
#pragma unroll
    for (int q = 0; q < 4; ++q) o[q] = (bf16)s[q];
    *reinterpret_cast<bf16x4*>(&Cb[(size_t)n * 256 + lane * 4]) = o;
}

// bf16 gather, Dout=128 full width (layer 3).
__global__ __launch_bounds__(256) void gather_bf_k(
    const bf16* __restrict__ Y, const uint32_t* __restrict__ pk,
    const int* __restrict__ noff, bf16* __restrict__ Cb)
{
    int wave = threadIdx.x >> 6, lane = threadIdx.x & 63;
    int n = blockIdx.x * 4 + wave;
    if (n >= N_NODES) return;
    int off0 = noff[n];
    int c = noff[n + 1] - off0;

    float s0 = 0.f, s1 = 0.f;
    int e = 0;
    for (; e + 16 <= c; e += 16) {
        uint32_t w[16]; bf16x2 v[16];
#pragma unroll
        for (int j = 0; j < 16; ++j) w[j] = pk[off0 + e + j];
#pragma unroll
        for (int j = 0; j < 16; ++j)
            v[j] = *reinterpret_cast<const bf16x2*>(&Y[(size_t)(w[j] & 0x3FFFF) * 128 + lane * 2]);
#pragma unroll
        for (int j = 0; j < 16; ++j) {
            float ww = __builtin_amdgcn_rcpf((float)(w[j] >> 18));
            s0 += ww * (float)v[j][0];
            s1 += ww * (float)v[j][1];
        }
    }
    if (e + 8 <= c) {
        uint32_t w[8]; bf16x2 v[8];
#pragma unroll
        for (int j = 0; j < 8; ++j) w[j] = pk[off0 + e + j];
#pragma unroll
        for (int j = 0; j < 8; ++j)
            v[j] = *reinterpret_cast<const bf16x2*>(&Y[(size_t)(w[j] & 0x3FFFF) * 128 + lane * 2]);
#pragma unroll
        for (int j = 0; j < 8; ++j) {
            float ww = __builtin_amdgcn_rcpf((float)(w[j] >> 18));
            s0 += ww * (float)v[j][0];
            s1 += ww * (float)v[j][1];
        }
        e += 8;
    }
    if (e + 4 <= c) {
        uint32_t w[4]; bf16x2 v[4];
#pragma unroll
        for (int j = 0; j < 4; ++j) w[j] = pk[off0 + e + j];
#pragma unroll
        for (int j = 0; j < 4; ++j)
            v[j] = *reinterpret_cast<const bf16x2*>(&Y[(size_t)(w[j] & 0x3FFFF) * 128 + lane * 2]);
#pragma unroll
        for (int j = 0; j < 4; ++j) {
            float ww = __builtin_amdgcn_rcpf((float)(w[j] >> 18));
            s0 += ww * (float)v[j][0];
            s1 += ww * (float)v[j][1];
        }
        e += 4;
    }
    for (; e < c; ++e) {
        uint32_t w = pk[off0 + e];
        bf16x2 v = *reinterpret_cast<const bf16x2*>(&Y[(size_t)(w & 0x3FFFF) * 128 + lane * 2]);
        float ww = __builtin_amdgcn_rcpf((float)(w >> 18));
        s0 += ww * (float)v[0];
        s1 += ww * (float)v[1];
    }

    bf16x2 o; o[0] = (bf16)s0; o[1] = (bf16)s1;
    *reinterpret_cast<bf16x2*>(&Cb[(size_t)n * 128 + lane * 2]) = o;
}

// ---------------------------------------------------------------------------
// Root GEMM over type-sorted 128-row chunks: out = Cb[ri] + h[ri]@Rt[t]^T + b[t]
// relu_mode: ReLU + bf16 emit to hout; else fp32 emit to C (last layer).
__global__ __launch_bounds__(256) void gemm_root_k(
    const bf16* __restrict__ h, const bf16* __restrict__ Rt,
    const float* __restrict__ rootB, const int* __restrict__ perm,
    const int* __restrict__ meta, const bf16* __restrict__ Cb,
    float* __restrict__ C, bf16* __restrict__ hout, int Dout, int relu_mode)
{
    __shared__ bf16 As[128][64];
    __shared__ bf16 Bs[128][64];
    __shared__ int ridx[128];
    int tid = threadIdx.x;
    int bx = blockIdx.x;
    int b1 = meta[5], b2 = meta[6], b3 = meta[7];
    if (bx >= b3) return;
    int t = (bx >= b2) ? 2 : (bx >= b1 ? 1 : 0);
    int chunk = bx - (t == 2 ? b2 : (t == 1 ? b1 : 0));
    int tstart = meta[t];
    int tc = meta[8 + t];
    int rbase = chunk * 128;
    if (tid < 128) {
        int lr = rbase + tid;
        ridx[tid] = (lr < tc) ? perm[tstart + lr] : 0;
    }
    __syncthreads();

    int lane = tid & 63, wave = tid >> 6;
    int wm = wave >> 1, wn = wave & 1;
    int n0 = blockIdx.y * 128;
    const bf16* B = Rt + (size_t)t * Dout * 256;

    f32x4 acc[4][4] = {};

    for (int kt = 0; kt < 4; ++kt) {   // K = 256
#pragma unroll
        for (int cc = 0; cc < 4; ++cc) {
            int linear = cc * 256 + tid;
            int row = linear >> 3, sl = linear & 7;
            const bf16* gA = &h[(size_t)ridx[row] * 256 + kt * 64 + sl * 8];
            const bf16* gB = &B[(size_t)(n0 + row) * 256 + kt * 64 + sl * 8];
            char* sA = (char*)&As[0][0] + (size_t)(cc * 256 + wave * 64) * 16;
            char* sB = (char*)&Bs[0][0] + (size_t)(cc * 256 + wave * 64) * 16;
            GLOAD_LDS16(gA, sA);
            GLOAD_LDS16(gB, sB);
        }
        __syncthreads();
#pragma unroll
        for (int kk = 0; kk < 2; ++kk) {
            bf16x8 af[4], bfr[4];
            int k0 = kk * 32 + (lane >> 4) * 8;
#pragma unroll
            for (int i = 0; i < 4; ++i) {
                af[i]  = *reinterpret_cast<const bf16x8*>(&As[wm * 64 + i * 16 + (lane & 15)][k0]);
                bfr[i] = *reinterpret_cast<const bf16x8*>(&Bs[wn * 64 + i * 16 + (lane & 15)][k0]);
            }
#pragma unroll
            for (int i = 0; i < 4; ++i)
#pragma unroll
                for (int j = 0; j < 4; ++j)
                    acc[i][j] = __builtin_amdgcn_mfma_f32_16x16x32_bf16(af[i], bfr[j], acc[i][j], 0, 0, 0);
        }
        __syncthreads();
    }

#pragma unroll
    for (int i = 0; i < 4; ++i)
#pragma unroll
        for (int j = 0; j < 4; ++j)
#pragma unroll
            for (int r = 0; r < 4; ++r) {
                int rl = wm * 64 + i * 16 + (lane >> 4) * 4 + r;
                int col = n0 + wn * 64 + j * 16 + (lane & 15);
                if (rbase + rl < tc) {
                    int ri = ridx[rl];
                    float v = (float)Cb[(size_t)ri * Dout + col] + acc[i][j][r]
                              + rootB[t * Dout + col];
                    if (relu_mode)
                        hout[(size_t)ri * Dout + col] = (bf16)fmaxf(v, 0.f);
                    else
                        C[(size_t)ri * Dout + col] = v;
                }
            }
}

// ---------------------------------------------------------------------------
// Row-wise log_softmax over 128 logits; one wave per row.
__global__ __launch_bounds__(256) void logsoftmax_k(
    const float* __restrict__ C, float* __restrict__ out, int M)
{
    int row = blockIdx.x * 4 + (threadIdx.x >> 6);
    int lane = threadIdx.x & 63;
    if (row >= M) return;
    float v0 = C[(size_t)row * 128 + lane];
    float v1 = C[(size_t)row * 128 + 64 + lane];
    float m = fmaxf(v0, v1);
    for (int off = 32; off; off >>= 1) m = fmaxf(m, __shfl_xor(m, off));
    float s = expf(v0 - m) + expf(v1 - m);
    for (int off = 32; off; off >>= 1) s += __shfl_xor(s, off);
    float lse = m + logf(s);
    out[(size_t)row * 128 + lane] = v0 - lse;
    out[(size_t)row * 128 + 64 + lane] = v1 - lse;
}

// ---------------------------------------------------------------------------
extern "C" void kernel_launch(void* const* d_in, const int* in_sizes, int n_in,
                              void* d_out, int out_size, void* d_ws, size_t ws_size,
                              hipStream_t stream)
{
    const float* x0   = (const float*)d_in[0];
    const float* x1   = (const float*)d_in[1];
    const float* emb2 = (const float*)d_in[2];
    const int*   ei   = (const int*)d_in[3];
    const int*   et   = (const int*)d_in[4];
    const int*   ntyp = (const int*)d_in[5];
    const int*   lidx = (const int*)d_in[6];
    const float* relW[3]  = {(const float*)d_in[7],  (const float*)d_in[10], (const float*)d_in[13]};
    const float* rootW[3] = {(const float*)d_in[8],  (const float*)d_in[11], (const float*)d_in[14]};
    const float* rootB[3] = {(const float*)d_in[9],  (const float*)d_in[12], (const float*)d_in[15]};
    float* out = (float*)d_out;

    char* p = (char*)d_ws;
    auto carve = [&](size_t bytes) {
        char* q = p;
        p += (bytes + 255) & ~(size_t)255;
        return (void*)q;
    };
    bf16* h_a   = (bf16*)carve((size_t)M_PAD * 256 * 2);
    bf16* h_b   = (bf16*)carve((size_t)M_PAD * 256 * 2);
    // Y slab: 64 MB, used as fp8 [M][1280] in layers 1-2, bf16 [M][640] in layer 3
    uint8_t* Yq = (uint8_t*)carve((size_t)M_PAD * 1280);
    bf16* Yb    = (bf16*)Yq;
    bf16* Cb    = (bf16*)carve((size_t)M_PAD * 256 * 2);
    float* C    = (float*)carve((size_t)M_PAD * 128 * 4);
    bf16* WtA   = (bf16*)carve((size_t)(2 * R_REL * 256 * 256 + R_REL * 128 * 256) * 2);
    bf16* RtA   = (bf16*)carve((size_t)(2 * 3 * 256 * 256 + 3 * 128 * 256) * 2);
    int* bh     = (int*)carve((size_t)BH_N * 4);
    int* bhs    = (int*)carve((size_t)BH_N * 4);
    int* gblk   = (int*)carve((size_t)256 * 4);
    uint32_t* ebuf = (uint32_t*)carve((size_t)N_EDGES * 4);
    uint32_t* pk   = (uint32_t*)carve((size_t)N_EDGES * 4);
    int* noff   = (int*)carve((size_t)(M_PAD + 1) * 4);
    int* tcnt   = (int*)carve((size_t)3 * HIST_BLOCKS * 4);
    int* toff   = (int*)carve((size_t)3 * HIST_BLOCKS * 4);
    int* meta   = (int*)carve((size_t)16 * 4);
    int* perm   = (int*)carve((size_t)N_NODES * 4);

    bf16* Wt[3] = {WtA, WtA + (size_t)R_REL * 256 * 256, WtA + (size_t)2 * R_REL * 256 * 256};
    bf16* Rt[3] = {RtA, RtA + (size_t)3 * 256 * 256, RtA + (size_t)2 * 3 * 256 * 256};

    group_input_k<<<(N_NODES + 3) / 4, 256, 0, stream>>>(x0, x1, emb2, ntyp, lidx, h_a);
    // CSR build: bucket hist -> scan -> bucket scatter -> in-bucket rank
    bucket_hist_k<<<NB1, 256, 0, stream>>>(ei, bh);
    gscan1_k<<<GS_BLOCKS, 256, 0, stream>>>(bh, bhs, gblk, BH_N);
    gscan2_k<<<1, 256, 0, stream>>>(gblk, GS_BLOCKS);
    gfold_k<<<GS_BLOCKS, 256, 0, stream>>>(bhs, gblk, BH_N);
    bucket_scatter_k<<<NB1, 256, 0, stream>>>(ei, et, bhs, ebuf);
    bucket_rank_k<<<NBUCK, 256, 0, stream>>>(ebuf, bhs, pk, noff);
    typed_hist_k<<<HIST_BLOCKS, 256, 0, stream>>>(ntyp, tcnt);
    typed_scan_k<<<1, 1024, 0, stream>>>(tcnt, toff, meta);
    typed_scatter_k<<<HIST_BLOCKS, 256, 0, stream>>>(ntyp, toff, perm);
    // weight prep for all layers up-front (independent of activations)
    const int douts[3] = {256, 256, 128};
    for (int l = 0; l < 3; ++l)
        cast_w_k<<<(R_REL * douts[l] * 256 + 255) / 256, 256, 0, stream>>>(
            relW[l], rootW[l], Wt[l], Rt[l], R_REL * douts[l] * 256, 3 * douts[l] * 256);

    bf16* cur = h_a;
    bf16* nxt = h_b;
    for (int l = 0; l < 3; ++l) {
        if (l < 2) {
            // fp8 path: full-width Y [M][1280] fp8, one gather per layer
            gemm_y_f8_k<<<49 * 10 * 8, 256, 0, stream>>>(cur, Wt[l], Yq, 1280, 10);
            gather_f8_k<<<(N_NODES + 3) / 4, 256, 0, stream>>>(Yq, pk, noff, Cb);
            gemm_root_k<<<dim3(393, 2), 256, 0, stream>>>(
                cur, Rt[l], rootB[l], perm, meta, Cb, C, nxt, 256, 1);
        } else {
            // bf16 path (feeds logits): Y [M][640] bf16, Dout=128
            gemm_y_bf_k<<<49 * 5 * 8, 256, 0, stream>>>(cur, Wt[l], Yb, 640, 5);
            gather_bf_k<<<(N_NODES + 3) / 4, 256, 0, stream>>>(Yb, pk, noff, Cb);
            gemm_root_k<<<dim3(393, 1), 256, 0, stream>>>(
                cur, Rt[l], rootB[l], perm, meta, Cb, C, nxt, 128, 0);
        }
        bf16* tmp = cur; cur = nxt; nxt = tmp;
    }
    logsoftmax_k<<<(N_NODES + 3) / 4, 256, 0, stream>>>(C, out, N_NODES);
}

// Round 13
// 520.915 us; speedup vs baseline: 1.4904x; 1.0088x over previous
//
#include <hip/hip_runtime.h>
#include <hip/hip_bf16.h>
#include <hip/hip_fp8.h>
#include <stdint.h>

// Problem constants (fixed by reference setup)
#define N_NODES 50000
#define M_PAD   50048          // 391 * 128
#define N_EDGES 1600000
#define R_REL   5
#define NBUCK   391            // buckets of 128 dst nodes
#define NB1     256            // blocks in bucket hist/scatter
#define EPB     6250           // N_EDGES / NB1 (exact)
#define BH_N    (NBUCK * NB1)  // 100096
#define GS_BLOCKS 98           // ceil(BH_N / 1024)
#define STAGE_CAP 6144         // LDS staging cap per bucket (mean 4092)
#define HIST_BLOCKS 196        // ceil(N_NODES / 256)
#define GI_BLOCKS 12500        // N_NODES / 4

typedef __bf16 bf16;
typedef __bf16 bf16x2 __attribute__((ext_vector_type(2)));
typedef __bf16 bf16x4 __attribute__((ext_vector_type(4)));
typedef __bf16 bf16x8 __attribute__((ext_vector_type(8)));
typedef float  f32x2  __attribute__((ext_vector_type(2)));
typedef float  f32x4  __attribute__((ext_vector_type(4)));

#define GLOAD_LDS16(g, l)                                                          \
    __builtin_amdgcn_global_load_lds(                                              \
        (const __attribute__((address_space(1))) void*)(g),                        \
        (__attribute__((address_space(3))) void*)(l), 16, 0, 0)

__device__ __forceinline__ uint8_t f32_to_fp8(float f) {
    return __hip_fp8_e4m3(f).__x;
}
__device__ __forceinline__ float fp8_to_f32(uint32_t b) {
    __hip_fp8_e4m3 v; v.__x = (uint8_t)b; return (float)v;
}

// Pack 4 f32 -> 4 fp8 bytes (hardware cvt_pk when available)
__device__ __forceinline__ uint32_t fp8_pack4(float a0, float a1, float a2, float a3) {
#if __has_builtin(__builtin_amdgcn_cvt_pk_fp8_f32)
    int q = __builtin_amdgcn_cvt_pk_fp8_f32(a0, a1, 0, false);
    q = __builtin_amdgcn_cvt_pk_fp8_f32(a2, a3, q, true);
    return (uint32_t)q;
#else
    return (uint32_t)f32_to_fp8(a0) | ((uint32_t)f32_to_fp8(a1) << 8) |
           ((uint32_t)f32_to_fp8(a2) << 16) | ((uint32_t)f32_to_fp8(a3) << 24);
#endif
}

__device__ __forceinline__ void fp8_accum4(uint32_t bits, float ww, float* s) {
#if __has_builtin(__builtin_amdgcn_cvt_pk_f32_fp8)
    f32x2 lo = __builtin_amdgcn_cvt_pk_f32_fp8((int)bits, false);
    f32x2 hi = __builtin_amdgcn_cvt_pk_f32_fp8((int)bits, true);
    s[0] += ww * lo[0]; s[1] += ww * lo[1];
    s[2] += ww * hi[0]; s[3] += ww * hi[1];
#else
    s[0] += ww * fp8_to_f32(bits & 0xFF);
    s[1] += ww * fp8_to_f32((bits >> 8) & 0xFF);
    s[2] += ww * fp8_to_f32((bits >> 16) & 0xFF);
    s[3] += ww * fp8_to_f32(bits >> 24);
#endif
}

// ---------------------------------------------------------------------------
// Merged setup phase A: group_input | bucket_hist | typed_hist | cast_w x3
// (all independent; partitioned by blockIdx range)
__global__ __launch_bounds__(256) void setup1_k(
    const float* __restrict__ x0, const float* __restrict__ x1,
    const float* __restrict__ emb2, const int* __restrict__ ntype,
    const int* __restrict__ lidx, bf16* __restrict__ h,
    const int* __restrict__ ei, int* __restrict__ bh,
    int* __restrict__ tcnt,
    const float* __restrict__ relW0, const float* __restrict__ rootW0,
    const float* __restrict__ relW1, const float* __restrict__ rootW1,
    const float* __restrict__ relW2, const float* __restrict__ rootW2,
    bf16* __restrict__ Wt0, bf16* __restrict__ Rt0,
    bf16* __restrict__ Wt1, bf16* __restrict__ Rt1,
    bf16* __restrict__ Wt2, bf16* __restrict__ Rt2)
{
    __shared__ int smem[NBUCK];
    int bid = blockIdx.x;
    int t = threadIdx.x;
    if (bid < GI_BLOCKS) {
        // group_input: 4 rows per block
        int row = bid * 4 + (t >> 6);
        int lane = t & 63;
        int ty = ntype[row];
        int li = lidx[row];
        const float* src = (ty == 0) ? x0 : (ty == 1) ? x1 : emb2;
        float4 v = *reinterpret_cast<const float4*>(&src[(size_t)li * 256 + lane * 4]);
        bf16x4 o;
        o[0] = (bf16)v.x; o[1] = (bf16)v.y; o[2] = (bf16)v.z; o[3] = (bf16)v.w;
        *reinterpret_cast<bf16x4*>(&h[(size_t)row * 256 + lane * 4]) = o;
        return;
    }
    bid -= GI_BLOCKS;
    if (bid < NB1) {
        // bucket_hist
        for (int i = t; i < NBUCK; i += 256) smem[i] = 0;
        __syncthreads();
        int base = bid * EPB;
        for (int i = t; i < EPB; i += 256) {
            int dst = ei[N_EDGES + base + i];
            atomicAdd(&smem[dst >> 7], 1);
        }
        __syncthreads();
        for (int i = t; i < NBUCK; i += 256) bh[i * NB1 + bid] = smem[i];
        return;
    }
    bid -= NB1;
    if (bid < HIST_BLOCKS) {
        // typed_hist
        if (t < 3) smem[t] = 0;
        __syncthreads();
        int n = bid * 256 + t;
        if (n < N_NODES) atomicAdd(&smem[ntype[n]], 1);
        __syncthreads();
        if (t < 3) tcnt[t * HIST_BLOCKS + bid] = smem[t];
        return;
    }
    bid -= HIST_BLOCKS;
    // cast_w: l0 1280 blocks, l1 1280, l2 640
    const float* relW; const float* rootW; bf16* Wt; bf16* Rt; int Dout;
    if (bid < 1280)      { relW = relW0; rootW = rootW0; Wt = Wt0; Rt = Rt0; Dout = 256; }
    else if (bid < 2560) { relW = relW1; rootW = rootW1; Wt = Wt1; Rt = Rt1; Dout = 256; bid -= 1280; }
    else                 { relW = relW2; rootW = rootW2; Wt = Wt2; Rt = Rt2; Dout = 128; bid -= 2560; }
    int i = bid * 256 + t;
    int relN = R_REL * Dout * 256;
    if (i < relN)  Wt[i] = (bf16)relW[i];
    int rootN = 3 * Dout * 256;
    if (i < rootN) Rt[i] = (bf16)rootW[i];
}

// Generic two-level exclusive scan over n ints (1024/block).
__global__ __launch_bounds__(256) void gscan1_k(
    const int* __restrict__ in, int* __restrict__ outv,
    int* __restrict__ blksum, int n)
{
    __shared__ int lds[256];
    int base = blockIdx.x * 1024;
    int t = threadIdx.x;
    int vals[4]; int s = 0;
#pragma unroll
    for (int i = 0; i < 4; ++i) {
        int idx = base + t * 4 + i;
        vals[i] = (idx < n) ? in[idx] : 0;
        s += vals[i];
    }
    lds[t] = s;
    __syncthreads();
    for (int off = 1; off < 256; off <<= 1) {
        int v = (t >= off) ? lds[t - off] : 0;
        __syncthreads();
        lds[t] += v;
        __syncthreads();
    }
    int incl = lds[t];
    int ex = incl - s;
    if (t == 255) blksum[blockIdx.x] = incl;
    int run = ex;
#pragma unroll
    for (int i = 0; i < 4; ++i) {
        int idx = base + t * 4 + i;
        if (idx < n) outv[idx] = run;
        run += vals[i];
    }
}

// Merged phase B: block 0 = exclusive scan of gblk[GS_BLOCKS];
// block 1 = typed scan (3*HIST_BLOCKS values) + meta emit.
__global__ __launch_bounds__(1024) void scan2m_k(
    int* __restrict__ gblk,
    const int* __restrict__ tcnt, int* __restrict__ toff, int* __restrict__ meta)
{
    __shared__ int lds[1024];
    int t = threadIdx.x;
    if (blockIdx.x == 0) {
        int v = (t < GS_BLOCKS) ? gblk[t] : 0;
        lds[t] = v;
        __syncthreads();
        for (int off = 1; off < 1024; off <<= 1) {
            int u = (t >= off) ? lds[t - off] : 0;
            __syncthreads();
            lds[t] += u;
            __syncthreads();
        }
        if (t < GS_BLOCKS) gblk[t] = lds[t] - v;
        return;
    }
    int v = (t < 3 * HIST_BLOCKS) ? tcnt[t] : 0;
    lds[t] = v;
    __syncthreads();
    for (int off = 1; off < 1024; off <<= 1) {
        int u = (t >= off) ? lds[t - off] : 0;
        __syncthreads();
        lds[t] += u;
        __syncthreads();
    }
    if (t < 3 * HIST_BLOCKS) toff[t] = lds[t] - v;
    if (t == 0) {
        int ts1 = lds[1 * HIST_BLOCKS - 1];
        int ts2 = lds[2 * HIST_BLOCKS - 1];
        int ts3 = lds[3 * HIST_BLOCKS - 1];
        meta[0] = 0; meta[1] = ts1; meta[2] = ts2; meta[3] = ts3;
        int c0 = ts1, c1 = ts2 - ts1, c2 = ts3 - ts2;
        meta[8] = c0; meta[9] = c1; meta[10] = c2;
        int b0 = (c0 + 127) >> 7, b1 = (c1 + 127) >> 7, b2 = (c2 + 127) >> 7;
        meta[4] = 0; meta[5] = b0; meta[6] = b0 + b1; meta[7] = b0 + b1 + b2;
    }
}

// Merged phase C: gfold (GS_BLOCKS blocks) | typed_scatter (HIST_BLOCKS blocks)
__global__ __launch_bounds__(256) void setup3_k(
    int* __restrict__ bhs, const int* __restrict__ gblk,
    const int* __restrict__ ntype, const int* __restrict__ toff,
    int* __restrict__ perm)
{
    __shared__ int cur[3];
    int bid = blockIdx.x;
    int t = threadIdx.x;
    if (bid < GS_BLOCKS) {
        int base = bid * 1024 + t * 4;
        int b = gblk[bid];
#pragma unroll
        for (int i = 0; i < 4; ++i) {
            int idx = base + i;
            if (idx < BH_N) bhs[idx] += b;
        }
        return;
    }
    bid -= GS_BLOCKS;
    if (t < 3) cur[t] = 0;
    __syncthreads();
    int n = bid * 256 + t;
    if (n < N_NODES) {
        int ty = ntype[n];
        int rank = atomicAdd(&cur[ty], 1);
        perm[toff[ty * HIST_BLOCKS + bid] + rank] = n;
    }
}

// CSR build phase 2: scatter edges to bucket-contiguous ebuf via LDS cursors.
// ebuf[pos] = (src*R + r) in bits [0,18) | dst&127 in bits [25,32)
__global__ __launch_bounds__(256) void bucket_scatter_k(
    const int* __restrict__ ei, const int* __restrict__ et,
    const int* __restrict__ bhs, uint32_t* __restrict__ ebuf)
{
    __shared__ int cur[NBUCK];
    int t = threadIdx.x;
    for (int i = t; i < NBUCK; i += 256) cur[i] = bhs[i * NB1 + blockIdx.x];
    __syncthreads();
    int base = blockIdx.x * EPB;
    for (int i = t; i < EPB; i += 256) {
        int e = base + i;
        int src = ei[e];
        int dst = ei[N_EDGES + e];
        int r = et[e];
        int pos = atomicAdd(&cur[dst >> 7], 1);
        ebuf[pos] = (uint32_t)(src * R_REL + r) | ((uint32_t)(dst & 127) << 25);
    }
}

// CSR build phase 3: one block per bucket. LDS hist over 640 local segs,
// LDS scan, LDS-atomic ranks -> final pk (sr | cnt<<18) + per-node offsets.
__global__ __launch_bounds__(256) void bucket_rank_k(
    const uint32_t* __restrict__ ebuf, const int* __restrict__ bhs,
    uint32_t* __restrict__ pk, int* __restrict__ noff)
{
    __shared__ uint32_t se[STAGE_CAP];
    __shared__ int hist[640];
    __shared__ int cursor[640];
    __shared__ int sb[256];
    int t = threadIdx.x;
    int b = blockIdx.x;
    int start = bhs[b * NB1];
    int end = (b < NBUCK - 1) ? bhs[(b + 1) * NB1] : N_EDGES;
    int size = end - start;
    for (int i = t; i < 640; i += 256) hist[i] = 0;
    __syncthreads();
    for (int i = t; i < size; i += 256) {
        uint32_t v = ebuf[start + i];
        if (i < STAGE_CAP) se[i] = v;
        uint32_t sr = v & 0x3FFFFu;
        int r = (int)(sr % 5u);
        int seg = (int)(v >> 25) * R_REL + r;
        atomicAdd(&hist[seg], 1);
    }
    __syncthreads();
    // exclusive scan of hist[640] -> cursor = start + excl (3 bins/thread)
    int b0 = t * 3;
    int loc[3]; int s0 = 0;
#pragma unroll
    for (int j = 0; j < 3; ++j) {
        int idx = b0 + j;
        int v = (idx < 640) ? hist[idx] : 0;
        loc[j] = s0; s0 += v;
    }
    sb[t] = s0;
    __syncthreads();
    for (int off = 1; off < 256; off <<= 1) {
        int u = (t >= off) ? sb[t - off] : 0;
        __syncthreads();
        sb[t] += u;
        __syncthreads();
    }
    int pre = sb[t] - s0;
#pragma unroll
    for (int j = 0; j < 3; ++j) {
        int idx = b0 + j;
        if (idx < 640) cursor[idx] = start + pre + loc[j];
    }
    __syncthreads();
    if (t < 128) noff[b * 128 + t] = cursor[t * 5];
    if (b == NBUCK - 1 && t == 128) noff[M_PAD] = N_EDGES;
    __syncthreads();
    for (int i = t; i < size; i += 256) {
        uint32_t v = (i < STAGE_CAP) ? se[i] : ebuf[start + i];
        uint32_t sr = v & 0x3FFFFu;
        int r = (int)(sr % 5u);
        int seg = (int)(v >> 25) * R_REL + r;
        int pos = atomicAdd(&cursor[seg], 1);
        pk[pos] = sr | ((uint32_t)hist[seg] << 18);
    }
}

// ---------------------------------------------------------------------------
// Y GEMM fp8-out: Y[m, j] = fp8(sum_d h[m, d] * W[j, d])  (K=256)
// XCD-aware 1-D grid: bid = (ml*NT + nt)*8 + xcd, m = xcd*49 + ml.
__global__ __launch_bounds__(256) void gemm_y_f8_k(
    const bf16* __restrict__ A, const bf16* __restrict__ B,
    uint8_t* __restrict__ Y, int ldc, int NT)
{
    __shared__ bf16 As[128][64];
    __shared__ bf16 Bs[128][64];
    int bid = blockIdx.x;
    int xcd = bid & 7;
    int r2 = bid >> 3;
    int ml = r2 / NT, nt = r2 - ml * NT;
    int m = xcd * 49 + ml;
    if (m >= M_PAD / 128) return;
    int m0 = m * 128, n0 = nt * 128;
    int tid = threadIdx.x;
    int lane = tid & 63, wave = tid >> 6;
    int wm = wave >> 1, wn = wave & 1;

    f32x4 acc[4][4] = {};

    for (int kt = 0; kt < 4; ++kt) {
#pragma unroll
        for (int cc = 0; cc < 4; ++cc) {
            int linear = cc * 256 + tid;
            int row = linear >> 3, sl = linear & 7;
            const bf16* gA = &A[(size_t)(m0 + row) * 256 + kt * 64 + sl * 8];
            const bf16* gB = &B[(size_t)(n0 + row) * 256 + kt * 64 + sl * 8];
            char* sA = (char*)&As[0][0] + (size_t)(cc * 256 + wave * 64) * 16;
            char* sB = (char*)&Bs[0][0] + (size_t)(cc * 256 + wave * 64) * 16;
            GLOAD_LDS16(gA, sA);
            GLOAD_LDS16(gB, sB);
        }
        __syncthreads();
#pragma unroll
        for (int kk = 0; kk < 2; ++kk) {
            bf16x8 af[4], bfr[4];
            int k0 = kk * 32 + (lane >> 4) * 8;
#pragma unroll
            for (int i = 0; i < 4; ++i) {
                af[i]  = *reinterpret_cast<const bf16x8*>(&As[wm * 64 + i * 16 + (lane & 15)][k0]);
                bfr[i] = *reinterpret_cast<const bf16x8*>(&Bs[wn * 64 + i * 16 + (lane & 15)][k0]);
            }
#pragma unroll
            for (int i = 0; i < 4; ++i)
#pragma unroll
                for (int j = 0; j < 4; ++j)
                    acc[i][j] = __builtin_amdgcn_mfma_f32_16x16x32_bf16(af[i], bfr[j], acc[i][j], 0, 0, 0);
        }
        __syncthreads();
    }

#pragma unroll
    for (int i = 0; i < 4; ++i)
#pragma unroll
        for (int j = 0; j < 4; ++j) {
            uint32_t q = fp8_pack4(acc[i][j][0], acc[i][j][1], acc[i][j][2], acc[i][j][3]);
            int row0 = m0 + wm * 64 + i * 16 + (lane >> 4) * 4;
            int col = n0 + wn * 64 + j * 16 + (lane & 15);
            Y[(size_t)(row0 + 0) * ldc + col] = (uint8_t)q;
            Y[(size_t)(row0 + 1) * ldc + col] = (uint8_t)(q >> 8);
            Y[(size_t)(row0 + 2) * ldc + col] = (uint8_t)(q >> 16);
            Y[(size_t)(row0 + 3) * ldc + col] = (uint8_t)(q >> 24);
        }
}

// Y GEMM bf16-out (layer 3): same structure, bf16 store.
__global__ __launch_bounds__(256) void gemm_y_bf_k(
    const bf16* __restrict__ A, const bf16* __restrict__ B,
    bf16* __restrict__ Y, int ldc, int NT)
{
    __shared__ bf16 As[128][64];
    __shared__ bf16 Bs[128][64];
    int bid = blockIdx.x;
    int xcd = bid & 7;
    int r2 = bid >> 3;
    int ml = r2 / NT, nt = r2 - ml * NT;
    int m = xcd * 49 + ml;
    if (m >= M_PAD / 128) return;
    int m0 = m * 128, n0 = nt * 128;
    int tid = threadIdx.x;
    int lane = tid & 63, wave = tid >> 6;
    int wm = wave >> 1, wn = wave & 1;

    f32x4 acc[4][4] = {};

    for (int kt = 0; kt < 4; ++kt) {
#pragma unroll
        for (int cc = 0; cc < 4; ++cc) {
            int linear = cc * 256 + tid;
            int row = linear >> 3, sl = linear & 7;
            const bf16* gA = &A[(size_t)(m0 + row) * 256 + kt * 64 + sl * 8];
            const bf16* gB = &B[(size_t)(n0 + row) * 256 + kt * 64 + sl * 8];
            char* sA = (char*)&As[0][0] + (size_t)(cc * 256 + wave * 64) * 16;
            char* sB = (char*)&Bs[0][0] + (size_t)(cc * 256 + wave * 64) * 16;
            GLOAD_LDS16(gA, sA);
            GLOAD_LDS16(gB, sB);
        }
        __syncthreads();
#pragma unroll
        for (int kk = 0; kk < 2; ++kk) {
            bf16x8 af[4], bfr[4];
            int k0 = kk * 32 + (lane >> 4) * 8;
#pragma unroll
            for (int i = 0; i < 4; ++i) {
                af[i]  = *reinterpret_cast<const bf16x8*>(&As[wm * 64 + i * 16 + (lane & 15)][k0]);
                bfr[i] = *reinterpret_cast<const bf16x8*>(&Bs[wn * 64 + i * 16 + (lane & 15)][k0]);
            }
#pragma unroll
            for (int i = 0; i < 4; ++i)
#pragma unroll
                for (int j = 0; j < 4; ++j)
                    acc[i][j] = __builtin_amdgcn_mfma_f32_16x16x32_bf16(af[i], bfr[j], acc[i][j], 0, 0, 0);
        }
        __syncthreads();
    }

#pragma unroll
    for (int i = 0; i < 4; ++i)
#pragma unroll
        for (int j = 0; j < 4; ++j)
#pragma unroll
            for (int r = 0; r < 4; ++r) {
                int row = m0 + wm * 64 + i * 16 + (lane >> 4) * 4 + r;
                int col = n0 + wn * 64 + j * 16 + (lane & 15);
                Y[(size_t)row * ldc + col] = (bf16)acc[i][j][r];
            }
}

// ---------------------------------------------------------------------------
// fp8 gather, Dout=256 full width: Cb[n,:] = sum_e (1/cnt_e) * dq(Y[idx_e,:])
__global__ __launch_bounds__(256) void gather_f8_k(
    const uint8_t* __restrict__ Y, const uint32_t* __restrict__ pk,
    const int* __restrict__ noff, bf16* __restrict__ Cb)
{
    int wave = threadIdx.x >> 6, lane = threadIdx.x & 63;
    int n = blockIdx.x * 4 + wave;
    if (n >= N_NODES) return;
    int off0 = noff[n];
    int c = noff[n + 1] - off0;

    float s[4] = {};
    int e = 0;
    for (; e + 16 <= c; e += 16) {
        uint32_t w[16]; uint32_t v[16];
#pragma unroll
        for (int j = 0; j < 16; ++j) w[j] = pk[off0 + e + j];
#pragma unroll
        for (int j = 0; j < 16; ++j)
            v[j] = *reinterpret_cast<const uint32_t*>(&Y[(size_t)(w[j] & 0x3FFFF) * 256 + lane * 4]);
#pragma unroll
        for (int j = 0; j < 16; ++j) {
            float ww = __builtin_amdgcn_rcpf((float)(w[j] >> 18));
            fp8_accum4(v[j], ww, s);
        }
    }
    if (e + 8 <= c) {
        uint32_t w[8]; uint32_t v[8];
#pragma unroll
        for (int j = 0; j < 8; ++j) w[j] = pk[off0 + e + j];
#pragma unroll
        for (int j = 0; j < 8; ++j)
            v[j] = *reinterpret_cast<const uint32_t*>(&Y[(size_t)(w[j] & 0x3FFFF) * 256 + lane * 4]);
#pragma unroll
        for (int j = 0; j < 8; ++j) {
            float ww = __builtin_amdgcn_rcpf((float)(w[j] >> 18));
            fp8_accum4(v[j], ww, s);
        }
        e += 8;
    }
    if (e + 4 <= c) {
        uint32_t w[4]; uint32_t v[4];
#pragma unroll
        for (int j = 0; j < 4; ++j) w[j] = pk[off0 + e + j];
#pragma unroll
        for (int j = 0; j < 4; ++j)
            v[j] = *reinterpret_cast<const uint32_t*>(&Y[(size_t)(w[j] & 0x3FFFF) * 256 + lane * 4]);
#pragma unroll
        for (int j = 0; j < 4; ++j) {
            float ww = __builtin_amdgcn_rcpf((float)(w[j] >> 18));
            fp8_accum4(v[j], ww, s);
        }
        e += 4;
    }
    for (; e < c; ++e) {
        uint32_t w = pk[off0 + e];
        uint32_t v = *reinterpret_cast<const uint32_t*>(&Y[(size_t)(w & 0x3FFFF) * 256 + lane * 4]);
        float ww = __builtin_amdgcn_rcpf((float)(w >> 18));
        fp8_accum4(v, ww, s);
    }

    bf16x4 o;
#pragma unroll
    for (int q = 0; q < 4; ++q) o[q] = (bf16)s[q];
    *reinterpret_cast<bf16x4*>(&Cb[(size_t)n * 256 + lane * 4]) = o;
}

// bf16 gather, Dout=128 full width (layer 3).
__global__ __launch_bounds__(256) void gather_bf_k(
    const bf16* __restrict__ Y, const uint32_t* __restrict__ pk,
    const int* __restrict__ noff, bf16* __restrict__ Cb)
{
    int wave = threadIdx.x >> 6, lane = threadIdx.x & 63;
    int n = blockIdx.x * 4 + wave;
    if (n >= N_NODES) return;
    int off0 = noff[n];
    int c = noff[n + 1] - off0;

    float s0 = 0.f, s1 = 0.f;
    int e = 0;
    for (; e + 16 <= c; e += 16) {
        uint32_t w[16]; bf16x2 v[16];
#pragma unroll
        for (int j = 0; j < 16; ++j) w[j] = pk[off0 + e + j];
#pragma unroll
        for (int j = 0; j < 16; ++j)
            v[j] = *reinterpret_cast<const bf16x2*>(&Y[(size_t)(w[j] & 0x3FFFF) * 128 + lane * 2]);
#pragma unroll
        for (int j = 0; j < 16; ++j) {
            float ww = __builtin_amdgcn_rcpf((float)(w[j] >> 18));
            s0 += ww * (float)v[j][0];
            s1 += ww * (float)v[j][1];
        }
    }
    if (e + 8 <= c) {
        uint32_t w[8]; bf16x2 v[8];
#pragma unroll
        for (int j = 0; j < 8; ++j) w[j] = pk[off0 + e + j];
#pragma unroll
        for (int j = 0; j < 8; ++j)
            v[j] = *reinterpret_cast<const bf16x2*>(&Y[(size_t)(w[j] & 0x3FFFF) * 128 + lane * 2]);
#pragma unroll
        for (int j = 0; j < 8; ++j) {
            float ww = __builtin_amdgcn_rcpf((float)(w[j] >> 18));
            s0 += ww * (float)v[j][0];
            s1 += ww * (float)v[j][1];
        }
        e += 8;
    }
    if (e + 4 <= c) {
        uint32_t w[4]; bf16x2 v[4];
#pragma unroll
        for (int j = 0; j < 4; ++j) w[j] = pk[off0 + e + j];
#pragma unroll
        for (int j = 0; j < 4; ++j)
            v[j] = *reinterpret_cast<const bf16x2*>(&Y[(size_t)(w[j] & 0x3FFFF) * 128 + lane * 2]);
#pragma unroll
        for (int j = 0; j < 4; ++j) {
            float ww = __builtin_amdgcn_rcpf((float)(w[j] >> 18));
            s0 += ww * (float)v[j][0];
            s1 += ww * (float)v[j][1];
        }
        e += 4;
    }
    for (; e < c; ++e) {
        uint32_t w = pk[off0 + e];
        bf16x2 v = *reinterpret_cast<const bf16x2*>(&Y[(size_t)(w & 0x3FFFF) * 128 + lane * 2]);
        float ww = __builtin_amdgcn_rcpf((float)(w >> 18));
        s0 += ww * (float)v[0];
        s1 += ww * (float)v[1];
    }

    bf16x2 o; o[0] = (bf16)s0; o[1] = (bf16)s1;
    *reinterpret_cast<bf16x2*>(&Cb[(size_t)n * 128 + lane * 2]) = o;
}

// ---------------------------------------------------------------------------
// Root GEMM (layers 1-2): out = relu(Cb[ri] + h[ri]@Rt[t]^T + b[t]) -> bf16 hout
__global__ __launch_bounds__(256) void gemm_root_k(
    const bf16* __restrict__ h, const bf16* __restrict__ Rt,
    const float* __restrict__ rootB, const int* __restrict__ perm,
    const int* __restrict__ meta, const bf16* __restrict__ Cb,
    bf16* __restrict__ hout, int Dout)
{
    __shared__ bf16 As[128][64];
    __shared__ bf16 Bs[128][64];
    __shared__ int ridx[128];
    int tid = threadIdx.x;
    int bx = blockIdx.x;
    int b1 = meta[5], b2 = meta[6], b3 = meta[7];
    if (bx >= b3) return;
    int t = (bx >= b2) ? 2 : (bx >= b1 ? 1 : 0);
    int chunk = bx - (t == 2 ? b2 : (t == 1 ? b1 : 0));
    int tstart = meta[t];
    int tc = meta[8 + t];
    int rbase = chunk * 128;
    if (tid < 128) {
        int lr = rbase + tid;
        ridx[tid] = (lr < tc) ? perm[tstart + lr] : 0;
    }
    __syncthreads();

    int lane = tid & 63, wave = tid >> 6;
    int wm = wave >> 1, wn = wave & 1;
    int n0 = blockIdx.y * 128;
    const bf16* B = Rt + (size_t)t * Dout * 256;

    f32x4 acc[4][4] = {};

    for (int kt = 0; kt < 4; ++kt) {   // K = 256
#pragma unroll
        for (int cc = 0; cc < 4; ++cc) {
            int linear = cc * 256 + tid;
            int row = linear >> 3, sl = linear & 7;
            const bf16* gA = &h[(size_t)ridx[row] * 256 + kt * 64 + sl * 8];
            const bf16* gB = &B[(size_t)(n0 + row) * 256 + kt * 64 + sl * 8];
            char* sA = (char*)&As[0][0] + (size_t)(cc * 256 + wave * 64) * 16;
            char* sB = (char*)&Bs[0][0] + (size_t)(cc * 256 + wave * 64) * 16;
            GLOAD_LDS16(gA, sA);
            GLOAD_LDS16(gB, sB);
        }
        __syncthreads();
#pragma unroll
        for (int kk = 0; kk < 2; ++kk) {
            bf16x8 af[4], bfr[4];
            int k0 = kk * 32 + (lane >> 4) * 8;
#pragma unroll
            for (int i = 0; i < 4; ++i) {
                af[i]  = *reinterpret_cast<const bf16x8*>(&As[wm * 64 + i * 16 + (lane & 15)][k0]);
                bfr[i] = *reinterpret_cast<const bf16x8*>(&Bs[wn * 64 + i * 16 + (lane & 15)][k0]);
            }
#pragma unroll
            for (int i = 0; i < 4; ++i)
#pragma unroll
                for (int j = 0; j < 4; ++j)
                    acc[i][j] = __builtin_amdgcn_mfma_f32_16x16x32_bf16(af[i], bfr[j], acc[i][j], 0, 0, 0);
        }
        __syncthreads();
    }

#pragma unroll
    for (int i = 0; i < 4; ++i)
#pragma unroll
        for (int j = 0; j < 4; ++j)
#pragma unroll
            for (int r = 0; r < 4; ++r) {
                int rl = wm * 64 + i * 16 + (lane >> 4) * 4 + r;
                int col = n0 + wn * 64 + j * 16 + (lane & 15);
                if (rbase + rl < tc) {
                    int ri = ridx[rl];
                    float v = (float)Cb[(size_t)ri * Dout + col] + acc[i][j][r]
                              + rootB[t * Dout + col];
                    hout[(size_t)ri * Dout + col] = (bf16)fmaxf(v, 0.f);
                }
            }
}

// ---------------------------------------------------------------------------
// Final root GEMM (Dout=128) with fused log_softmax: writes out directly.
// Block covers 128 perm rows x full 128 logits; LDS tile + wave-per-row LSE.
__global__ __launch_bounds__(256) void gemm_root_ls_k(
    const bf16* __restrict__ h, const bf16* __restrict__ Rt,
    const float* __restrict__ rootB, const int* __restrict__ perm,
    const int* __restrict__ meta, const bf16* __restrict__ Cb,
    float* __restrict__ out)
{
    __shared__ bf16 As[128][64];
    __shared__ bf16 Bs[128][64];
    __shared__ int ridx[128];
    __shared__ float L[128][128];
    const int Dout = 128;
    int tid = threadIdx.x;
    int bx = blockIdx.x;
    int b1 = meta[5], b2 = meta[6], b3 = meta[7];
    if (bx >= b3) return;
    int t = (bx >= b2) ? 2 : (bx >= b1 ? 1 : 0);
    int chunk = bx - (t == 2 ? b2 : (t == 1 ? b1 : 0));
    int tstart = meta[t];
    int tc = meta[8 + t];
    int rbase = chunk * 128;
    if (tid < 128) {
        int lr = rbase + tid;
        ridx[tid] = (lr < tc) ? perm[tstart + lr] : 0;
    }
    __syncthreads();

    int lane = tid & 63, wave = tid >> 6;
    int wm = wave >> 1, wn = wave & 1;
    const bf16* B = Rt + (size_t)t * Dout * 256;

    f32x4 acc[4][4] = {};

    for (int kt = 0; kt < 4; ++kt) {   // K = 256
#pragma unroll
        for (int cc = 0; cc < 4; ++cc) {
            int linear = cc * 256 + tid;
            int row = linear >> 3, sl = linear & 7;
            const bf16* gA = &h[(size_t)ridx[row] * 256 + kt * 64 + sl * 8];
            const bf16* gB = &B[(size_t)(row) * 256 + kt * 64 + sl * 8];
            char* sA = (char*)&As[0][0] + (size_t)(cc * 256 + wave * 64) * 16;
            char* sB = (char*)&Bs[0][0] + (size_t)(cc * 256 + wave * 64) * 16;
            GLOAD_LDS16(gA, sA);
            GLOAD_LDS16(gB, sB);
        }
        __syncthreads();
#pragma unroll
        for (int kk = 0; kk < 2; ++kk) {
            bf16x8 af[4], bfr[4];
            int k0 = kk * 32 + (lane >> 4) * 8;
#pragma unroll
            for (int i = 0; i < 4; ++i) {
                af[i]  = *reinterpret_cast<const bf16x8*>(&As[wm * 64 + i * 16 + (lane & 15)][k0]);
                bfr[i] = *reinterpret_cast<const bf16x8*>(&Bs[wn * 64 + i * 16 + (lane & 15)][k0]);
            }
#pragma unroll
            for (int i = 0; i < 4; ++i)
#pragma unroll
                for (int j = 0; j < 4; ++j)
                    acc[i][j] = __builtin_amdgcn_mfma_f32_16x16x32_bf16(af[i], bfr[j], acc[i][j], 0, 0, 0);
        }
        __syncthreads();
    }

    // stage fp32 logits to LDS
#pragma unroll
    for (int i = 0; i < 4; ++i)
#pragma unroll
        for (int j = 0; j < 4; ++j)
#pragma unroll
            for (int r = 0; r < 4; ++r) {
                int rl = wm * 64 + i * 16 + (lane >> 4) * 4 + r;
                int col = wn * 64 + j * 16 + (lane & 15);
                int ri = ridx[rl];
                L[rl][col] = (float)Cb[(size_t)ri * Dout + col] + acc[i][j][r]
                             + rootB[t * Dout + col];
            }
    __syncthreads();

    // wave-per-row log_softmax: wave w handles rows w*32..w*32+31
    for (int rr = 0; rr < 32; ++rr) {
        int row = wave * 32 + rr;
        if (rbase + row >= tc) continue;
        float v0 = L[row][lane];
        float v1 = L[row][64 + lane];
        float m = fmaxf(v0, v1);
        for (int off = 32; off; off >>= 1) m = fmaxf(m, __shfl_xor(m, off));
        float s = expf(v0 - m) + expf(v1 - m);
        for (int off = 32; off; off >>= 1) s += __shfl_xor(s, off);
        float lse = m + logf(s);
        int ri = ridx[row];
        out[(size_t)ri * 128 + lane] = v0 - lse;
        out[(size_t)ri * 128 + 64 + lane] = v1 - lse;
    }
}

// ---------------------------------------------------------------------------
extern "C" void kernel_launch(void* const* d_in, const int* in_sizes, int n_in,
                              void* d_out, int out_size, void* d_ws, size_t ws_size,
                              hipStream_t stream)
{
    const float* x0   = (const float*)d_in[0];
    const float* x1   = (const float*)d_in[1];
    const float* emb2 = (const float*)d_in[2];
    const int*   ei   = (const int*)d_in[3];
    const int*   et   = (const int*)d_in[4];
    const int*   ntyp = (const int*)d_in[5];
    const int*   lidx = (const int*)d_in[6];
    const float* relW[3]  = {(const float*)d_in[7],  (const float*)d_in[10], (const float*)d_in[13]};
    const float* rootW[3] = {(const float*)d_in[8],  (const float*)d_in[11], (const float*)d_in[14]};
    const float* rootB[3] = {(const float*)d_in[9],  (const float*)d_in[12], (const float*)d_in[15]};
    float* out = (float*)d_out;

    char* p = (char*)d_ws;
    auto carve = [&](size_t bytes) {
        char* q = p;
        p += (bytes + 255) & ~(size_t)255;
        return (void*)q;
    };
    bf16* h_a   = (bf16*)carve((size_t)M_PAD * 256 * 2);
    bf16* h_b   = (bf16*)carve((size_t)M_PAD * 256 * 2);
    // Y slab: 64 MB, used as fp8 [M][1280] in layers 1-2, bf16 [M][640] in layer 3
    uint8_t* Yq = (uint8_t*)carve((size_t)M_PAD * 1280);
    bf16* Yb    = (bf16*)Yq;
    bf16* Cb    = (bf16*)carve((size_t)M_PAD * 256 * 2);
    bf16* WtA   = (bf16*)carve((size_t)(2 * R_REL * 256 * 256 + R_REL * 128 * 256) * 2);
    bf16* RtA   = (bf16*)carve((size_t)(2 * 3 * 256 * 256 + 3 * 128 * 256) * 2);
    int* bh     = (int*)carve((size_t)BH_N * 4);
    int* gblk   = (int*)carve((size_t)256 * 4);
    uint32_t* ebuf = (uint32_t*)carve((size_t)N_EDGES * 4);
    uint32_t* pk   = (uint32_t*)carve((size_t)N_EDGES * 4);
    int* noff   = (int*)carve((size_t)(M_PAD + 1) * 4);
    int* tcnt   = (int*)carve((size_t)3 * HIST_BLOCKS * 4);
    int* toff   = (int*)carve((size_t)3 * HIST_BLOCKS * 4);
    int* meta   = (int*)carve((size_t)16 * 4);
    int* perm   = (int*)carve((size_t)N_NODES * 4);

    bf16* Wt[3] = {WtA, WtA + (size_t)R_REL * 256 * 256, WtA + (size_t)2 * R_REL * 256 * 256};
    bf16* Rt[3] = {RtA, RtA + (size_t)3 * 256 * 256, RtA + (size_t)2 * 3 * 256 * 256};

    // Phase A: group_input | bucket_hist | typed_hist | cast_w x3
    setup1_k<<<GI_BLOCKS + NB1 + HIST_BLOCKS + 3200, 256, 0, stream>>>(
        x0, x1, emb2, ntyp, lidx, h_a, ei, bh, tcnt,
        relW[0], rootW[0], relW[1], rootW[1], relW[2], rootW[2],
        Wt[0], Rt[0], Wt[1], Rt[1], Wt[2], Rt[2]);
    // Phase B: scan bucket-hist (in-place into bh) + block sums
    gscan1_k<<<GS_BLOCKS, 256, 0, stream>>>(bh, bh, gblk, BH_N);
    scan2m_k<<<2, 1024, 0, stream>>>(gblk, tcnt, toff, meta);
    setup3_k<<<GS_BLOCKS + HIST_BLOCKS, 256, 0, stream>>>(bh, gblk, ntyp, toff, perm);
    bucket_scatter_k<<<NB1, 256, 0, stream>>>(ei, et, bh, ebuf);
    bucket_rank_k<<<NBUCK, 256, 0, stream>>>(ebuf, bh, pk, noff);

    bf16* cur = h_a;
    bf16* nxt = h_b;
    for (int l = 0; l < 2; ++l) {
        // fp8 path: full-width Y [M][1280] fp8, one gather per layer
        gemm_y_f8_k<<<49 * 10 * 8, 256, 0, stream>>>(cur, Wt[l], Yq, 1280, 10);
        gather_f8_k<<<GI_BLOCKS, 256, 0, stream>>>(Yq, pk, noff, Cb);
        gemm_root_k<<<dim3(393, 2), 256, 0, stream>>>(
            cur, Rt[l], rootB[l], perm, meta, Cb, nxt, 256);
        bf16* tmp = cur; cur = nxt; nxt = tmp;
    }
    // Layer 3 (bf16, feeds logits): Y [M][640] bf16, Dout=128, fused logsoftmax
    gemm_y_bf_k<<<49 * 5 * 8, 256, 0, stream>>>(cur, Wt[2], Yb, 640, 5);
    gather_bf_k<<<GI_BLOCKS, 256, 0, stream>>>(Yb, pk, noff, Cb);
    gemm_root_ls_k<<<393, 256, 0, stream>>>(cur, Rt[2], rootB[2], perm, meta, Cb, out);
}

// Round 14
// 511.145 us; speedup vs baseline: 1.5189x; 1.0191x over previous
//
#include <hip/hip_runtime.h>
#include <hip/hip_bf16.h>
#include <hip/hip_fp8.h>
#include <stdint.h>

// Problem constants (fixed by reference setup)
#define N_NODES 50000
#define M_PAD   50048          // 391 * 128
#define N_EDGES 1600000
#define R_REL   5
#define NBUCK   391            // buckets of 128 dst nodes
#define NB1     256            // blocks in bucket hist/scatter
#define EPB     6250           // N_EDGES / NB1 (exact)
#define BH_N    (NBUCK * NB1)  // 100096
#define GS_BLOCKS 98           // ceil(BH_N / 1024)
#define STAGE_CAP 6144         // LDS staging cap per bucket (mean 4092)
#define HIST_BLOCKS 196        // ceil(N_NODES / 256)
#define GI_BLOCKS 12500        // N_NODES / 4

typedef __bf16 bf16;
typedef __bf16 bf16x2 __attribute__((ext_vector_type(2)));
typedef __bf16 bf16x4 __attribute__((ext_vector_type(4)));
typedef __bf16 bf16x8 __attribute__((ext_vector_type(8)));
typedef float  f32x2  __attribute__((ext_vector_type(2)));
typedef float  f32x4  __attribute__((ext_vector_type(4)));

#define GLOAD_LDS16(g, l)                                                          \
    __builtin_amdgcn_global_load_lds(                                              \
        (const __attribute__((address_space(1))) void*)(g),                        \
        (__attribute__((address_space(3))) void*)(l), 16, 0, 0)

__device__ __forceinline__ uint8_t f32_to_fp8(float f) {
    return __hip_fp8_e4m3(f).__x;
}
__device__ __forceinline__ float fp8_to_f32(uint32_t b) {
    __hip_fp8_e4m3 v; v.__x = (uint8_t)b; return (float)v;
}

// Pack 4 f32 -> 4 fp8 bytes (hardware cvt_pk when available)
__device__ __forceinline__ uint32_t fp8_pack4(float a0, float a1, float a2, float a3) {
#if __has_builtin(__builtin_amdgcn_cvt_pk_fp8_f32)
    int q = __builtin_amdgcn_cvt_pk_fp8_f32(a0, a1, 0, false);
    q = __builtin_amdgcn_cvt_pk_fp8_f32(a2, a3, q, true);
    return (uint32_t)q;
#else
    return (uint32_t)f32_to_fp8(a0) | ((uint32_t)f32_to_fp8(a1) << 8) |
           ((uint32_t)f32_to_fp8(a2) << 16) | ((uint32_t)f32_to_fp8(a3) << 24);
#endif
}

__device__ __forceinline__ void fp8_accum4(uint32_t bits, float ww, float* s) {
#if __has_builtin(__builtin_amdgcn_cvt_pk_f32_fp8)
    f32x2 lo = __builtin_amdgcn_cvt_pk_f32_fp8((int)bits, false);
    f32x2 hi = __builtin_amdgcn_cvt_pk_f32_fp8((int)bits, true);
    s[0] += ww * lo[0]; s[1] += ww * lo[1];
    s[2] += ww * hi[0]; s[3] += ww * hi[1];
#else
    s[0] += ww * fp8_to_f32(bits & 0xFF);
    s[1] += ww * fp8_to_f32((bits >> 8) & 0xFF);
    s[2] += ww * fp8_to_f32((bits >> 16) & 0xFF);
    s[3] += ww * fp8_to_f32(bits >> 24);
#endif
}

// ---------------------------------------------------------------------------
// Merged setup phase A: group_input | bucket_hist | typed_hist | cast_w x3
__global__ __launch_bounds__(256) void setup1_k(
    const float* __restrict__ x0, const float* __restrict__ x1,
    const float* __restrict__ emb2, const int* __restrict__ ntype,
    const int* __restrict__ lidx, bf16* __restrict__ h,
    const int* __restrict__ ei, int* __restrict__ bh,
    int* __restrict__ tcnt,
    const float* __restrict__ relW0, const float* __restrict__ rootW0,
    const float* __restrict__ relW1, const float* __restrict__ rootW1,
    const float* __restrict__ relW2, const float* __restrict__ rootW2,
    bf16* __restrict__ Wt0, bf16* __restrict__ Rt0,
    bf16* __restrict__ Wt1, bf16* __restrict__ Rt1,
    bf16* __restrict__ Wt2, bf16* __restrict__ Rt2)
{
    __shared__ int smem[NBUCK];
    int bid = blockIdx.x;
    int t = threadIdx.x;
    if (bid < GI_BLOCKS) {
        int row = bid * 4 + (t >> 6);
        int lane = t & 63;
        int ty = ntype[row];
        int li = lidx[row];
        const float* src = (ty == 0) ? x0 : (ty == 1) ? x1 : emb2;
        float4 v = *reinterpret_cast<const float4*>(&src[(size_t)li * 256 + lane * 4]);
        bf16x4 o;
        o[0] = (bf16)v.x; o[1] = (bf16)v.y; o[2] = (bf16)v.z; o[3] = (bf16)v.w;
        *reinterpret_cast<bf16x4*>(&h[(size_t)row * 256 + lane * 4]) = o;
        return;
    }
    bid -= GI_BLOCKS;
    if (bid < NB1) {
        for (int i = t; i < NBUCK; i += 256) smem[i] = 0;
        __syncthreads();
        int base = bid * EPB;
        for (int i = t; i < EPB; i += 256) {
            int dst = ei[N_EDGES + base + i];
            atomicAdd(&smem[dst >> 7], 1);
        }
        __syncthreads();
        for (int i = t; i < NBUCK; i += 256) bh[i * NB1 + bid] = smem[i];
        return;
    }
    bid -= NB1;
    if (bid < HIST_BLOCKS) {
        if (t < 3) smem[t] = 0;
        __syncthreads();
        int n = bid * 256 + t;
        if (n < N_NODES) atomicAdd(&smem[ntype[n]], 1);
        __syncthreads();
        if (t < 3) tcnt[t * HIST_BLOCKS + bid] = smem[t];
        return;
    }
    bid -= HIST_BLOCKS;
    const float* relW; const float* rootW; bf16* Wt; bf16* Rt; int Dout;
    if (bid < 1280)      { relW = relW0; rootW = rootW0; Wt = Wt0; Rt = Rt0; Dout = 256; }
    else if (bid < 2560) { relW = relW1; rootW = rootW1; Wt = Wt1; Rt = Rt1; Dout = 256; bid -= 1280; }
    else                 { relW = relW2; rootW = rootW2; Wt = Wt2; Rt = Rt2; Dout = 128; bid -= 2560; }
    int i = bid * 256 + t;
    int relN = R_REL * Dout * 256;
    if (i < relN)  Wt[i] = (bf16)relW[i];
    int rootN = 3 * Dout * 256;
    if (i < rootN) Rt[i] = (bf16)rootW[i];
}

// Generic two-level exclusive scan over n ints (1024/block).
__global__ __launch_bounds__(256) void gscan1_k(
    const int* __restrict__ in, int* __restrict__ outv,
    int* __restrict__ blksum, int n)
{
    __shared__ int lds[256];
    int base = blockIdx.x * 1024;
    int t = threadIdx.x;
    int vals[4]; int s = 0;
#pragma unroll
    for (int i = 0; i < 4; ++i) {
        int idx = base + t * 4 + i;
        vals[i] = (idx < n) ? in[idx] : 0;
        s += vals[i];
    }
    lds[t] = s;
    __syncthreads();
    for (int off = 1; off < 256; off <<= 1) {
        int v = (t >= off) ? lds[t - off] : 0;
        __syncthreads();
        lds[t] += v;
        __syncthreads();
    }
    int incl = lds[t];
    int ex = incl - s;
    if (t == 255) blksum[blockIdx.x] = incl;
    int run = ex;
#pragma unroll
    for (int i = 0; i < 4; ++i) {
        int idx = base + t * 4 + i;
        if (idx < n) outv[idx] = run;
        run += vals[i];
    }
}

// Merged phase B: block 0 = exclusive scan of gblk; block 1 = typed scan + meta.
__global__ __launch_bounds__(1024) void scan2m_k(
    int* __restrict__ gblk,
    const int* __restrict__ tcnt, int* __restrict__ toff, int* __restrict__ meta)
{
    __shared__ int lds[1024];
    int t = threadIdx.x;
    if (blockIdx.x == 0) {
        int v = (t < GS_BLOCKS) ? gblk[t] : 0;
        lds[t] = v;
        __syncthreads();
        for (int off = 1; off < 1024; off <<= 1) {
            int u = (t >= off) ? lds[t - off] : 0;
            __syncthreads();
            lds[t] += u;
            __syncthreads();
        }
        if (t < GS_BLOCKS) gblk[t] = lds[t] - v;
        return;
    }
    int v = (t < 3 * HIST_BLOCKS) ? tcnt[t] : 0;
    lds[t] = v;
    __syncthreads();
    for (int off = 1; off < 1024; off <<= 1) {
        int u = (t >= off) ? lds[t - off] : 0;
        __syncthreads();
        lds[t] += u;
        __syncthreads();
    }
    if (t < 3 * HIST_BLOCKS) toff[t] = lds[t] - v;
    if (t == 0) {
        int ts1 = lds[1 * HIST_BLOCKS - 1];
        int ts2 = lds[2 * HIST_BLOCKS - 1];
        int ts3 = lds[3 * HIST_BLOCKS - 1];
        meta[0] = 0; meta[1] = ts1; meta[2] = ts2; meta[3] = ts3;
        int c0 = ts1, c1 = ts2 - ts1, c2 = ts3 - ts2;
        meta[8] = c0; meta[9] = c1; meta[10] = c2;
        int b0 = (c0 + 127) >> 7, b1 = (c1 + 127) >> 7, b2 = (c2 + 127) >> 7;
        meta[4] = 0; meta[5] = b0; meta[6] = b0 + b1; meta[7] = b0 + b1 + b2;
    }
}

// Merged phase C: gfold | typed_scatter
__global__ __launch_bounds__(256) void setup3_k(
    int* __restrict__ bhs, const int* __restrict__ gblk,
    const int* __restrict__ ntype, const int* __restrict__ toff,
    int* __restrict__ perm)
{
    __shared__ int cur[3];
    int bid = blockIdx.x;
    int t = threadIdx.x;
    if (bid < GS_BLOCKS) {
        int base = bid * 1024 + t * 4;
        int b = gblk[bid];
#pragma unroll
        for (int i = 0; i < 4; ++i) {
            int idx = base + i;
            if (idx < BH_N) bhs[idx] += b;
        }
        return;
    }
    bid -= GS_BLOCKS;
    if (t < 3) cur[t] = 0;
    __syncthreads();
    int n = bid * 256 + t;
    if (n < N_NODES) {
        int ty = ntype[n];
        int rank = atomicAdd(&cur[ty], 1);
        perm[toff[ty * HIST_BLOCKS + bid] + rank] = n;
    }
}

// CSR build phase 2: scatter edges to bucket-contiguous ebuf via LDS cursors.
__global__ __launch_bounds__(256) void bucket_scatter_k(
    const int* __restrict__ ei, const int* __restrict__ et,
    const int* __restrict__ bhs, uint32_t* __restrict__ ebuf)
{
    __shared__ int cur[NBUCK];
    int t = threadIdx.x;
    for (int i = t; i < NBUCK; i += 256) cur[i] = bhs[i * NB1 + blockIdx.x];
    __syncthreads();
    int base = blockIdx.x * EPB;
    for (int i = t; i < EPB; i += 256) {
        int e = base + i;
        int src = ei[e];
        int dst = ei[N_EDGES + e];
        int r = et[e];
        int pos = atomicAdd(&cur[dst >> 7], 1);
        ebuf[pos] = (uint32_t)(src * R_REL + r) | ((uint32_t)(dst & 127) << 25);
    }
}

// CSR build phase 3: one block per bucket; LDS hist/scan/rank -> pk + noff.
__global__ __launch_bounds__(256) void bucket_rank_k(
    const uint32_t* __restrict__ ebuf, const int* __restrict__ bhs,
    uint32_t* __restrict__ pk, int* __restrict__ noff)
{
    __shared__ uint32_t se[STAGE_CAP];
    __shared__ int hist[640];
    __shared__ int cursor[640];
    __shared__ int sb[256];
    int t = threadIdx.x;
    int b = blockIdx.x;
    int start = bhs[b * NB1];
    int end = (b < NBUCK - 1) ? bhs[(b + 1) * NB1] : N_EDGES;
    int size = end - start;
    for (int i = t; i < 640; i += 256) hist[i] = 0;
    __syncthreads();
    for (int i = t; i < size; i += 256) {
        uint32_t v = ebuf[start + i];
        if (i < STAGE_CAP) se[i] = v;
        uint32_t sr = v & 0x3FFFFu;
        int r = (int)(sr % 5u);
        int seg = (int)(v >> 25) * R_REL + r;
        atomicAdd(&hist[seg], 1);
    }
    __syncthreads();
    int b0 = t * 3;
    int loc[3]; int s0 = 0;
#pragma unroll
    for (int j = 0; j < 3; ++j) {
        int idx = b0 + j;
        int v = (idx < 640) ? hist[idx] : 0;
        loc[j] = s0; s0 += v;
    }
    sb[t] = s0;
    __syncthreads();
    for (int off = 1; off < 256; off <<= 1) {
        int u = (t >= off) ? sb[t - off] : 0;
        __syncthreads();
        sb[t] += u;
        __syncthreads();
    }
    int pre = sb[t] - s0;
#pragma unroll
    for (int j = 0; j < 3; ++j) {
        int idx = b0 + j;
        if (idx < 640) cursor[idx] = start + pre + loc[j];
    }
    __syncthreads();
    if (t < 128) noff[b * 128 + t] = cursor[t * 5];
    if (b == NBUCK - 1 && t == 128) noff[M_PAD] = N_EDGES;
    __syncthreads();
    for (int i = t; i < size; i += 256) {
        uint32_t v = (i < STAGE_CAP) ? se[i] : ebuf[start + i];
        uint32_t sr = v & 0x3FFFFu;
        int r = (int)(sr % 5u);
        int seg = (int)(v >> 25) * R_REL + r;
        int pos = atomicAdd(&cursor[seg], 1);
        pk[pos] = sr | ((uint32_t)hist[seg] << 18);
    }
}

// ---------------------------------------------------------------------------
// Y GEMM fp8-out: Y[m, j] = fp8(sum_d h[m, d] * W[j, d])  (K=256)
__global__ __launch_bounds__(256) void gemm_y_f8_k(
    const bf16* __restrict__ A, const bf16* __restrict__ B,
    uint8_t* __restrict__ Y, int ldc, int NT)
{
    __shared__ bf16 As[128][64];
    __shared__ bf16 Bs[128][64];
    int bid = blockIdx.x;
    int xcd = bid & 7;
    int r2 = bid >> 3;
    int ml = r2 / NT, nt = r2 - ml * NT;
    int m = xcd * 49 + ml;
    if (m >= M_PAD / 128) return;
    int m0 = m * 128, n0 = nt * 128;
    int tid = threadIdx.x;
    int lane = tid & 63, wave = tid >> 6;
    int wm = wave >> 1, wn = wave & 1;

    f32x4 acc[4][4] = {};

    for (int kt = 0; kt < 4; ++kt) {
#pragma unroll
        for (int cc = 0; cc < 4; ++cc) {
            int linear = cc * 256 + tid;
            int row = linear >> 3, sl = linear & 7;
            const bf16* gA = &A[(size_t)(m0 + row) * 256 + kt * 64 + sl * 8];
            const bf16* gB = &B[(size_t)(n0 + row) * 256 + kt * 64 + sl * 8];
            char* sA = (char*)&As[0][0] + (size_t)(cc * 256 + wave * 64) * 16;
            char* sB = (char*)&Bs[0][0] + (size_t)(cc * 256 + wave * 64) * 16;
            GLOAD_LDS16(gA, sA);
            GLOAD_LDS16(gB, sB);
        }
        __syncthreads();
#pragma unroll
        for (int kk = 0; kk < 2; ++kk) {
            bf16x8 af[4], bfr[4];
            int k0 = kk * 32 + (lane >> 4) * 8;
#pragma unroll
            for (int i = 0; i < 4; ++i) {
                af[i]  = *reinterpret_cast<const bf16x8*>(&As[wm * 64 + i * 16 + (lane & 15)][k0]);
                bfr[i] = *reinterpret_cast<const bf16x8*>(&Bs[wn * 64 + i * 16 + (lane & 15)][k0]);
            }
#pragma unroll
            for (int i = 0; i < 4; ++i)
#pragma unroll
                for (int j = 0; j < 4; ++j)
                    acc[i][j] = __builtin_amdgcn_mfma_f32_16x16x32_bf16(af[i], bfr[j], acc[i][j], 0, 0, 0);
        }
        __syncthreads();
    }

#pragma unroll
    for (int i = 0; i < 4; ++i)
#pragma unroll
        for (int j = 0; j < 4; ++j) {
            uint32_t q = fp8_pack4(acc[i][j][0], acc[i][j][1], acc[i][j][2], acc[i][j][3]);
            int row0 = m0 + wm * 64 + i * 16 + (lane >> 4) * 4;
            int col = n0 + wn * 64 + j * 16 + (lane & 15);
            Y[(size_t)(row0 + 0) * ldc + col] = (uint8_t)q;
            Y[(size_t)(row0 + 1) * ldc + col] = (uint8_t)(q >> 8);
            Y[(size_t)(row0 + 2) * ldc + col] = (uint8_t)(q >> 16);
            Y[(size_t)(row0 + 3) * ldc + col] = (uint8_t)(q >> 24);
        }
}

// Y GEMM bf16-out (layer 3): same structure, bf16 store.
__global__ __launch_bounds__(256) void gemm_y_bf_k(
    const bf16* __restrict__ A, const bf16* __restrict__ B,
    bf16* __restrict__ Y, int ldc, int NT)
{
    __shared__ bf16 As[128][64];
    __shared__ bf16 Bs[128][64];
    int bid = blockIdx.x;
    int xcd = bid & 7;
    int r2 = bid >> 3;
    int ml = r2 / NT, nt = r2 - ml * NT;
    int m = xcd * 49 + ml;
    if (m >= M_PAD / 128) return;
    int m0 = m * 128, n0 = nt * 128;
    int tid = threadIdx.x;
    int lane = tid & 63, wave = tid >> 6;
    int wm = wave >> 1, wn = wave & 1;

    f32x4 acc[4][4] = {};

    for (int kt = 0; kt < 4; ++kt) {
#pragma unroll
        for (int cc = 0; cc < 4; ++cc) {
            int linear = cc * 256 + tid;
            int row = linear >> 3, sl = linear & 7;
            const bf16* gA = &A[(size_t)(m0 + row) * 256 + kt * 64 + sl * 8];
            const bf16* gB = &B[(size_t)(n0 + row) * 256 + kt * 64 + sl * 8];
            char* sA = (char*)&As[0][0] + (size_t)(cc * 256 + wave * 64) * 16;
            char* sB = (char*)&Bs[0][0] + (size_t)(cc * 256 + wave * 64) * 16;
            GLOAD_LDS16(gA, sA);
            GLOAD_LDS16(gB, sB);
        }
        __syncthreads();
#pragma unroll
        for (int kk = 0; kk < 2; ++kk) {
            bf16x8 af[4], bfr[4];
            int k0 = kk * 32 + (lane >> 4) * 8;
#pragma unroll
            for (int i = 0; i < 4; ++i) {
                af[i]  = *reinterpret_cast<const bf16x8*>(&As[wm * 64 + i * 16 + (lane & 15)][k0]);
                bfr[i] = *reinterpret_cast<const bf16x8*>(&Bs[wn * 64 + i * 16 + (lane & 15)][k0]);
            }
#pragma unroll
            for (int i = 0; i < 4; ++i)
#pragma unroll
                for (int j = 0; j < 4; ++j)
                    acc[i][j] = __builtin_amdgcn_mfma_f32_16x16x32_bf16(af[i], bfr[j], acc[i][j], 0, 0, 0);
        }
        __syncthreads();
    }

#pragma unroll
    for (int i = 0; i < 4; ++i)
#pragma unroll
        for (int j = 0; j < 4; ++j)
#pragma unroll
            for (int r = 0; r < 4; ++r) {
                int row = m0 + wm * 64 + i * 16 + (lane >> 4) * 4 + r;
                int col = n0 + wn * 64 + j * 16 + (lane & 15);
                Y[(size_t)row * ldc + col] = (bf16)acc[i][j][r];
            }
}

// ---------------------------------------------------------------------------
// fp8 gather, Dout=256 full width: Cb[n,:] = sum_e (1/cnt_e) * dq(Y[idx_e,:])
__global__ __launch_bounds__(256) void gather_f8_k(
    const uint8_t* __restrict__ Y, const uint32_t* __restrict__ pk,
    const int* __restrict__ noff, bf16* __restrict__ Cb)
{
    int wave = threadIdx.x >> 6, lane = threadIdx.x & 63;
    int n = blockIdx.x * 4 + wave;
    if (n >= N_NODES) return;
    int off0 = noff[n];
    int c = noff[n + 1] - off0;

    float s[4] = {};
    int e = 0;
    for (; e + 16 <= c; e += 16) {
        uint32_t w[16]; uint32_t v[16];
#pragma unroll
        for (int j = 0; j < 16; ++j) w[j] = pk[off0 + e + j];
#pragma unroll
        for (int j = 0; j < 16; ++j)
            v[j] = *reinterpret_cast<const uint32_t*>(&Y[(size_t)(w[j] & 0x3FFFF) * 256 + lane * 4]);
#pragma unroll
        for (int j = 0; j < 16; ++j) {
            float ww = __builtin_amdgcn_rcpf((float)(w[j] >> 18));
            fp8_accum4(v[j], ww, s);
        }
    }
    if (e + 8 <= c) {
        uint32_t w[8]; uint32_t v[8];
#pragma unroll
        for (int j = 0; j < 8; ++j) w[j] = pk[off0 + e + j];
#pragma unroll
        for (int j = 0; j < 8; ++j)
            v[j] = *reinterpret_cast<const uint32_t*>(&Y[(size_t)(w[j] & 0x3FFFF) * 256 + lane * 4]);
#pragma unroll
        for (int j = 0; j < 8; ++j) {
            float ww = __builtin_amdgcn_rcpf((float)(w[j] >> 18));
            fp8_accum4(v[j], ww, s);
        }
        e += 8;
    }
    if (e + 4 <= c) {
        uint32_t w[4]; uint32_t v[4];
#pragma unroll
        for (int j = 0; j < 4; ++j) w[j] = pk[off0 + e + j];
#pragma unroll
        for (int j = 0; j < 4; ++j)
            v[j] = *reinterpret_cast<const uint32_t*>(&Y[(size_t)(w[j] & 0x3FFFF) * 256 + lane * 4]);
#pragma unroll
        for (int j = 0; j < 4; ++j) {
            float ww = __builtin_amdgcn_rcpf((float)(w[j] >> 18));
            fp8_accum4(v[j], ww, s);
        }
        e += 4;
    }
    for (; e < c; ++e) {
        uint32_t w = pk[off0 + e];
        uint32_t v = *reinterpret_cast<const uint32_t*>(&Y[(size_t)(w & 0x3FFFF) * 256 + lane * 4]);
        float ww = __builtin_amdgcn_rcpf((float)(w >> 18));
        fp8_accum4(v, ww, s);
    }

    bf16x4 o;
#pragma unroll
    for (int q = 0; q < 4; ++q) o[q] = (bf16)s[q];
    *reinterpret_cast<bf16x4*>(&Cb[(size_t)n * 256 + lane * 4]) = o;
}

// bf16 gather, Dout=128 full width (layer 3).
__global__ __launch_bounds__(256) void gather_bf_k(
    const bf16* __restrict__ Y, const uint32_t* __restrict__ pk,
    const int* __restrict__ noff, bf16* __restrict__ Cb)
{
    int wave = threadIdx.x >> 6, lane = threadIdx.x & 63;
    int n = blockIdx.x * 4 + wave;
    if (n >= N_NODES) return;
    int off0 = noff[n];
    int c = noff[n + 1] - off0;

    float s0 = 0.f, s1 = 0.f;
    int e = 0;
    for (; e + 16 <= c; e += 16) {
        uint32_t w[16]; bf16x2 v[16];
#pragma unroll
        for (int j = 0; j < 16; ++j) w[j] = pk[off0 + e + j];
#pragma unroll
        for (int j = 0; j < 16; ++j)
            v[j] = *reinterpret_cast<const bf16x2*>(&Y[(size_t)(w[j] & 0x3FFFF) * 128 + lane * 2]);
#pragma unroll
        for (int j = 0; j < 16; ++j) {
            float ww = __builtin_amdgcn_rcpf((float)(w[j] >> 18));
            s0 += ww * (float)v[j][0];
            s1 += ww * (float)v[j][1];
        }
    }
    if (e + 8 <= c) {
        uint32_t w[8]; bf16x2 v[8];
#pragma unroll
        for (int j = 0; j < 8; ++j) w[j] = pk[off0 + e + j];
#pragma unroll
        for (int j = 0; j < 8; ++j)
            v[j] = *reinterpret_cast<const bf16x2*>(&Y[(size_t)(w[j] & 0x3FFFF) * 128 + lane * 2]);
#pragma unroll
        for (int j = 0; j < 8; ++j) {
            float ww = __builtin_amdgcn_rcpf((float)(w[j] >> 18));
            s0 += ww * (float)v[j][0];
            s1 += ww * (float)v[j][1];
        }
        e += 8;
    }
    if (e + 4 <= c) {
        uint32_t w[4]; bf16x2 v[4];
#pragma unroll
        for (int j = 0; j < 4; ++j) w[j] = pk[off0 + e + j];
#pragma unroll
        for (int j = 0; j < 4; ++j)
            v[j] = *reinterpret_cast<const bf16x2*>(&Y[(size_t)(w[j] & 0x3FFFF) * 128 + lane * 2]);
#pragma unroll
        for (int j = 0; j < 4; ++j) {
            float ww = __builtin_amdgcn_rcpf((float)(w[j] >> 18));
            s0 += ww * (float)v[j][0];
            s1 += ww * (float)v[j][1];
        }
        e += 4;
    }
    for (; e < c; ++e) {
        uint32_t w = pk[off0 + e];
        bf16x2 v = *reinterpret_cast<const bf16x2*>(&Y[(size_t)(w & 0x3FFFF) * 128 + lane * 2]);
        float ww = __builtin_amdgcn_rcpf((float)(w >> 18));
        s0 += ww * (float)v[0];
        s1 += ww * (float)v[1];
    }

    bf16x2 o; o[0] = (bf16)s0; o[1] = (bf16)s1;
    *reinterpret_cast<bf16x2*>(&Cb[(size_t)n * 128 + lane * 2]) = o;
}

// ---------------------------------------------------------------------------
// Root GEMM over type-sorted 128-row chunks: out = Cb[ri] + h[ri]@Rt[t]^T + b[t]
// relu_mode: ReLU + bf16 emit to hout; else fp32 emit to C (last layer).
__global__ __launch_bounds__(256) void gemm_root_k(
    const bf16* __restrict__ h, const bf16* __restrict__ Rt,
    const float* __restrict__ rootB, const int* __restrict__ perm,
    const int* __restrict__ meta, const bf16* __restrict__ Cb,
    float* __restrict__ C, bf16* __restrict__ hout, int Dout, int relu_mode)
{
    __shared__ bf16 As[128][64];
    __shared__ bf16 Bs[128][64];
    __shared__ int ridx[128];
    int tid = threadIdx.x;
    int bx = blockIdx.x;
    int b1 = meta[5], b2 = meta[6], b3 = meta[7];
    if (bx >= b3) return;
    int t = (bx >= b2) ? 2 : (bx >= b1 ? 1 : 0);
    int chunk = bx - (t == 2 ? b2 : (t == 1 ? b1 : 0));
    int tstart = meta[t];
    int tc = meta[8 + t];
    int rbase = chunk * 128;
    if (tid < 128) {
        int lr = rbase + tid;
        ridx[tid] = (lr < tc) ? perm[tstart + lr] : 0;
    }
    __syncthreads();

    int lane = tid & 63, wave = tid >> 6;
    int wm = wave >> 1, wn = wave & 1;
    int n0 = blockIdx.y * 128;
    const bf16* B = Rt + (size_t)t * Dout * 256;

    f32x4 acc[4][4] = {};

    for (int kt = 0; kt < 4; ++kt) {   // K = 256
#pragma unroll
        for (int cc = 0; cc < 4; ++cc) {
            int linear = cc * 256 + tid;
            int row = linear >> 3, sl = linear & 7;
            const bf16* gA = &h[(size_t)ridx[row] * 256 + kt * 64 + sl * 8];
            const bf16* gB = &B[(size_t)(n0 + row) * 256 + kt * 64 + sl * 8];
            char* sA = (char*)&As[0][0] + (size_t)(cc * 256 + wave * 64) * 16;
            char* sB = (char*)&Bs[0][0] + (size_t)(cc * 256 + wave * 64) * 16;
            GLOAD_LDS16(gA, sA);
            GLOAD_LDS16(gB, sB);
        }
        __syncthreads();
#pragma unroll
        for (int kk = 0; kk < 2; ++kk) {
            bf16x8 af[4], bfr[4];
            int k0 = kk * 32 + (lane >> 4) * 8;
#pragma unroll
            for (int i = 0; i < 4; ++i) {
                af[i]  = *reinterpret_cast<const bf16x8*>(&As[wm * 64 + i * 16 + (lane & 15)][k0]);
                bfr[i] = *reinterpret_cast<const bf16x8*>(&Bs[wn * 64 + i * 16 + (lane & 15)][k0]);
            }
#pragma unroll
            for (int i = 0; i < 4; ++i)
#pragma unroll
                for (int j = 0; j < 4; ++j)
                    acc[i][j] = __builtin_amdgcn_mfma_f32_16x16x32_bf16(af[i], bfr[j], acc[i][j], 0, 0, 0);
        }
        __syncthreads();
    }

#pragma unroll
    for (int i = 0; i < 4; ++i)
#pragma unroll
        for (int j = 0; j < 4; ++j)
#pragma unroll
            for (int r = 0; r < 4; ++r) {
                int rl = wm * 64 + i * 16 + (lane >> 4) * 4 + r;
                int col = n0 + wn * 64 + j * 16 + (lane & 15);
                if (rbase + rl < tc) {
                    int ri = ridx[rl];
                    float v = (float)Cb[(size_t)ri * Dout + col] + acc[i][j][r]
                              + rootB[t * Dout + col];
                    if (relu_mode)
                        hout[(size_t)ri * Dout + col] = (bf16)fmaxf(v, 0.f);
                    else
                        C[(size_t)ri * Dout + col] = v;
                }
            }
}

// ---------------------------------------------------------------------------
// Row-wise log_softmax over 128 logits; one wave per row.
__global__ __launch_bounds__(256) void logsoftmax_k(
    const float* __restrict__ C, float* __restrict__ out, int M)
{
    int row = blockIdx.x * 4 + (threadIdx.x >> 6);
    int lane = threadIdx.x & 63;
    if (row >= M) return;
    float v0 = C[(size_t)row * 128 + lane];
    float v1 = C[(size_t)row * 128 + 64 + lane];
    float m = fmaxf(v0, v1);
    for (int off = 32; off; off >>= 1) m = fmaxf(m, __shfl_xor(m, off));
    float s = expf(v0 - m) + expf(v1 - m);
    for (int off = 32; off; off >>= 1) s += __shfl_xor(s, off);
    float lse = m + logf(s);
    out[(size_t)row * 128 + lane] = v0 - lse;
    out[(size_t)row * 128 + 64 + lane] = v1 - lse;
}

// ---------------------------------------------------------------------------
extern "C" void kernel_launch(void* const* d_in, const int* in_sizes, int n_in,
                              void* d_out, int out_size, void* d_ws, size_t ws_size,
                              hipStream_t stream)
{
    const float* x0   = (const float*)d_in[0];
    const float* x1   = (const float*)d_in[1];
    const float* emb2 = (const float*)d_in[2];
    const int*   ei   = (const int*)d_in[3];
    const int*   et   = (const int*)d_in[4];
    const int*   ntyp = (const int*)d_in[5];
    const int*   lidx = (const int*)d_in[6];
    const float* relW[3]  = {(const float*)d_in[7],  (const float*)d_in[10], (const float*)d_in[13]};
    const float* rootW[3] = {(const float*)d_in[8],  (const float*)d_in[11], (const float*)d_in[14]};
    const float* rootB[3] = {(const float*)d_in[9],  (const float*)d_in[12], (const float*)d_in[15]};
    float* out = (float*)d_out;

    char* p = (char*)d_ws;
    auto carve = [&](size_t bytes) {
        char* q = p;
        p += (bytes + 255) & ~(size_t)255;
        return (void*)q;
    };
    bf16* h_a   = (bf16*)carve((size_t)M_PAD * 256 * 2);
    bf16* h_b   = (bf16*)carve((size_t)M_PAD * 256 * 2);
    // Y slab: 64 MB, used as fp8 [M][1280] in layers 1-2, bf16 [M][640] in layer 3
    uint8_t* Yq = (uint8_t*)carve((size_t)M_PAD * 1280);
    bf16* Yb    = (bf16*)Yq;
    bf16* Cb    = (bf16*)carve((size_t)M_PAD * 256 * 2);
    float* C    = (float*)carve((size_t)M_PAD * 128 * 4);
    bf16* WtA   = (bf16*)carve((size_t)(2 * R_REL * 256 * 256 + R_REL * 128 * 256) * 2);
    bf16* RtA   = (bf16*)carve((size_t)(2 * 3 * 256 * 256 + 3 * 128 * 256) * 2);
    int* bh     = (int*)carve((size_t)BH_N * 4);
    int* gblk   = (int*)carve((size_t)256 * 4);
    uint32_t* ebuf = (uint32_t*)carve((size_t)N_EDGES * 4);
    uint32_t* pk   = (uint32_t*)carve((size_t)N_EDGES * 4);
    int* noff   = (int*)carve((size_t)(M_PAD + 1) * 4);
    int* tcnt   = (int*)carve((size_t)3 * HIST_BLOCKS * 4);
    int* toff   = (int*)carve((size_t)3 * HIST_BLOCKS * 4);
    int* meta   = (int*)carve((size_t)16 * 4);
    int* perm   = (int*)carve((size_t)N_NODES * 4);

    bf16* Wt[3] = {WtA, WtA + (size_t)R_REL * 256 * 256, WtA + (size_t)2 * R_REL * 256 * 256};
    bf16* Rt[3] = {RtA, RtA + (size_t)3 * 256 * 256, RtA + (size_t)2 * 3 * 256 * 256};

    // Phase A: group_input | bucket_hist | typed_hist | cast_w x3
    setup1_k<<<GI_BLOCKS + NB1 + HIST_BLOCKS + 3200, 256, 0, stream>>>(
        x0, x1, emb2, ntyp, lidx, h_a, ei, bh, tcnt,
        relW[0], rootW[0], relW[1], rootW[1], relW[2], rootW[2],
        Wt[0], Rt[0], Wt[1], Rt[1], Wt[2], Rt[2]);
    // Phase B: scan bucket-hist (in-place into bh) + block sums
    gscan1_k<<<GS_BLOCKS, 256, 0, stream>>>(bh, bh, gblk, BH_N);
    scan2m_k<<<2, 1024, 0, stream>>>(gblk, tcnt, toff, meta);
    setup3_k<<<GS_BLOCKS + HIST_BLOCKS, 256, 0, stream>>>(bh, gblk, ntyp, toff, perm);
    bucket_scatter_k<<<NB1, 256, 0, stream>>>(ei, et, bh, ebuf);
    bucket_rank_k<<<NBUCK, 256, 0, stream>>>(ebuf, bh, pk, noff);

    bf16* cur = h_a;
    bf16* nxt = h_b;
    for (int l = 0; l < 2; ++l) {
        // fp8 path: full-width Y [M][1280] fp8, one gather per layer
        gemm_y_f8_k<<<49 * 10 * 8, 256, 0, stream>>>(cur, Wt[l], Yq, 1280, 10);
        gather_f8_k<<<GI_BLOCKS, 256, 0, stream>>>(Yq, pk, noff, Cb);
        gemm_root_k<<<dim3(393, 2), 256, 0, stream>>>(
            cur, Rt[l], rootB[l], perm, meta, Cb, nullptr, nxt, 256, 1);
        bf16* tmp = cur; cur = nxt; nxt = tmp;
    }
    // Layer 3 (bf16, feeds logits): Y [M][640] bf16, Dout=128
    gemm_y_bf_k<<<49 * 5 * 8, 256, 0, stream>>>(cur, Wt[2], Yb, 640, 5);
    gather_bf_k<<<GI_BLOCKS, 256, 0, stream>>>(Yb, pk, noff, Cb);
    gemm_root_k<<<dim3(393, 1), 256, 0, stream>>>(
        cur, Rt[2], rootB[2], perm, meta, Cb, C, nullptr, 128, 0);
    logsoftmax_k<<<GI_BLOCKS, 256, 0, stream>>>(C, out, N_NODES);
}

// Round 15
// 510.529 us; speedup vs baseline: 1.5207x; 1.0012x over previous
//
#include <hip/hip_runtime.h>
#include <hip/hip_bf16.h>
#include <hip/hip_fp8.h>
#include <stdint.h>

// Problem constants (fixed by reference setup)
#define N_NODES 50000
#define M_PAD   50048          // 391 * 128
#define N_EDGES 1600000
#define R_REL   5
#define NBUCK   391            // buckets of 128 dst nodes
#define NB1     256            // blocks in bucket hist/scatter
#define EPB     6250           // N_EDGES / NB1 (exact)
#define BH_N    (NBUCK * NB1)  // 100096
#define GS_BLOCKS 98           // ceil(BH_N / 1024)
#define STAGE_CAP 6144         // LDS staging cap per bucket (mean 4092)
#define HIST_BLOCKS 196        // ceil(N_NODES / 256)
#define GI_BLOCKS 12500        // N_NODES / 4

typedef __bf16 bf16;
typedef __bf16 bf16x2 __attribute__((ext_vector_type(2)));
typedef __bf16 bf16x4 __attribute__((ext_vector_type(4)));
typedef __bf16 bf16x8 __attribute__((ext_vector_type(8)));
typedef float  f32x2  __attribute__((ext_vector_type(2)));
typedef float  f32x4  __attribute__((ext_vector_type(4)));

#define GLOAD_LDS16(g, l)                                                          \
    __builtin_amdgcn_global_load_lds(                                              \
        (const __attribute__((address_space(1))) void*)(g),                        \
        (__attribute__((address_space(3))) void*)(l), 16, 0, 0)

__device__ __forceinline__ uint8_t f32_to_fp8(float f) {
    return __hip_fp8_e4m3(f).__x;
}
__device__ __forceinline__ float fp8_to_f32(uint32_t b) {
    __hip_fp8_e4m3 v; v.__x = (uint8_t)b; return (float)v;
}

// Pack 4 f32 -> 4 fp8 bytes (hardware cvt_pk when available)
__device__ __forceinline__ uint32_t fp8_pack4(float a0, float a1, float a2, float a3) {
#if __has_builtin(__builtin_amdgcn_cvt_pk_fp8_f32)
    int q = __builtin_amdgcn_cvt_pk_fp8_f32(a0, a1, 0, false);
    q = __builtin_amdgcn_cvt_pk_fp8_f32(a2, a3, q, true);
    return (uint32_t)q;
#else
    return (uint32_t)f32_to_fp8(a0) | ((uint32_t)f32_to_fp8(a1) << 8) |
           ((uint32_t)f32_to_fp8(a2) << 16) | ((uint32_t)f32_to_fp8(a3) << 24);
#endif
}

__device__ __forceinline__ void fp8_accum4(uint32_t bits, float ww, float* s) {
#if __has_builtin(__builtin_amdgcn_cvt_pk_f32_fp8)
    f32x2 lo = __builtin_amdgcn_cvt_pk_f32_fp8((int)bits, false);
    f32x2 hi = __builtin_amdgcn_cvt_pk_f32_fp8((int)bits, true);
    s[0] += ww * lo[0]; s[1] += ww * lo[1];
    s[2] += ww * hi[0]; s[3] += ww * hi[1];
#else
    s[0] += ww * fp8_to_f32(bits & 0xFF);
    s[1] += ww * fp8_to_f32((bits >> 8) & 0xFF);
    s[2] += ww * fp8_to_f32((bits >> 16) & 0xFF);
    s[3] += ww * fp8_to_f32(bits >> 24);
#endif
}

// ---------------------------------------------------------------------------
// Merged setup phase A: group_input | bucket_hist | typed_hist | cast_w x3
__global__ __launch_bounds__(256) void setup1_k(
    const float* __restrict__ x0, const float* __restrict__ x1,
    const float* __restrict__ emb2, const int* __restrict__ ntype,
    const int* __restrict__ lidx, bf16* __restrict__ h,
    const int* __restrict__ ei, int* __restrict__ bh,
    int* __restrict__ tcnt,
    const float* __restrict__ relW0, const float* __restrict__ rootW0,
    const float* __restrict__ relW1, const float* __restrict__ rootW1,
    const float* __restrict__ relW2, const float* __restrict__ rootW2,
    bf16* __restrict__ Wt0, bf16* __restrict__ Rt0,
    bf16* __restrict__ Wt1, bf16* __restrict__ Rt1,
    bf16* __restrict__ Wt2, bf16* __restrict__ Rt2)
{
    __shared__ int smem[NBUCK];
    int bid = blockIdx.x;
    int t = threadIdx.x;
    if (bid < GI_BLOCKS) {
        int row = bid * 4 + (t >> 6);
        int lane = t & 63;
        int ty = ntype[row];
        int li = lidx[row];
        const float* src = (ty == 0) ? x0 : (ty == 1) ? x1 : emb2;
        float4 v = *reinterpret_cast<const float4*>(&src[(size_t)li * 256 + lane * 4]);
        bf16x4 o;
        o[0] = (bf16)v.x; o[1] = (bf16)v.y; o[2] = (bf16)v.z; o[3] = (bf16)v.w;
        *reinterpret_cast<bf16x4*>(&h[(size_t)row * 256 + lane * 4]) = o;
        return;
    }
    bid -= GI_BLOCKS;
    if (bid < NB1) {
        for (int i = t; i < NBUCK; i += 256) smem[i] = 0;
        __syncthreads();
        int base = bid * EPB;
        for (int i = t; i < EPB; i += 256) {
            int dst = ei[N_EDGES + base + i];
            atomicAdd(&smem[dst >> 7], 1);
        }
        __syncthreads();
        for (int i = t; i < NBUCK; i += 256) bh[i * NB1 + bid] = smem[i];
        return;
    }
    bid -= NB1;
    if (bid < HIST_BLOCKS) {
        if (t < 3) smem[t] = 0;
        __syncthreads();
        int n = bid * 256 + t;
        if (n < N_NODES) atomicAdd(&smem[ntype[n]], 1);
        __syncthreads();
        if (t < 3) tcnt[t * HIST_BLOCKS + bid] = smem[t];
        return;
    }
    bid -= HIST_BLOCKS;
    const float* relW; const float* rootW; bf16* Wt; bf16* Rt; int Dout;
    if (bid < 1280)      { relW = relW0; rootW = rootW0; Wt = Wt0; Rt = Rt0; Dout = 256; }
    else if (bid < 2560) { relW = relW1; rootW = rootW1; Wt = Wt1; Rt = Rt1; Dout = 256; bid -= 1280; }
    else                 { relW = relW2; rootW = rootW2; Wt = Wt2; Rt = Rt2; Dout = 128; bid -= 2560; }
    int i = bid * 256 + t;
    int relN = R_REL * Dout * 256;
    if (i < relN)  Wt[i] = (bf16)relW[i];
    int rootN = 3 * Dout * 256;
    if (i < rootN) Rt[i] = (bf16)rootW[i];
}

// Generic two-level exclusive scan over n ints (1024/block).
__global__ __launch_bounds__(256) void gscan1_k(
    const int* __restrict__ in, int* __restrict__ outv,
    int* __restrict__ blksum, int n)
{
    __shared__ int lds[256];
    int base = blockIdx.x * 1024;
    int t = threadIdx.x;
    int vals[4]; int s = 0;
#pragma unroll
    for (int i = 0; i < 4; ++i) {
        int idx = base + t * 4 + i;
        vals[i] = (idx < n) ? in[idx] : 0;
        s += vals[i];
    }
    lds[t] = s;
    __syncthreads();
    for (int off = 1; off < 256; off <<= 1) {
        int v = (t >= off) ? lds[t - off] : 0;
        __syncthreads();
        lds[t] += v;
        __syncthreads();
    }
    int incl = lds[t];
    int ex = incl - s;
    if (t == 255) blksum[blockIdx.x] = incl;
    int run = ex;
#pragma unroll
    for (int i = 0; i < 4; ++i) {
        int idx = base + t * 4 + i;
        if (idx < n) outv[idx] = run;
        run += vals[i];
    }
}

// Merged phase B: block 0 = exclusive scan of gblk; block 1 = typed scan + meta.
__global__ __launch_bounds__(1024) void scan2m_k(
    int* __restrict__ gblk,
    const int* __restrict__ tcnt, int* __restrict__ toff, int* __restrict__ meta)
{
    __shared__ int lds[1024];
    int t = threadIdx.x;
    if (blockIdx.x == 0) {
        int v = (t < GS_BLOCKS) ? gblk[t] : 0;
        lds[t] = v;
        __syncthreads();
        for (int off = 1; off < 1024; off <<= 1) {
            int u = (t >= off) ? lds[t - off] : 0;
            __syncthreads();
            lds[t] += u;
            __syncthreads();
        }
        if (t < GS_BLOCKS) gblk[t] = lds[t] - v;
        return;
    }
    int v = (t < 3 * HIST_BLOCKS) ? tcnt[t] : 0;
    lds[t] = v;
    __syncthreads();
    for (int off = 1; off < 1024; off <<= 1) {
        int u = (t >= off) ? lds[t - off] : 0;
        __syncthreads();
        lds[t] += u;
        __syncthreads();
    }
    if (t < 3 * HIST_BLOCKS) toff[t] = lds[t] - v;
    if (t == 0) {
        int ts1 = lds[1 * HIST_BLOCKS - 1];
        int ts2 = lds[2 * HIST_BLOCKS - 1];
        int ts3 = lds[3 * HIST_BLOCKS - 1];
        meta[0] = 0; meta[1] = ts1; meta[2] = ts2; meta[3] = ts3;
        int c0 = ts1, c1 = ts2 - ts1, c2 = ts3 - ts2;
        meta[8] = c0; meta[9] = c1; meta[10] = c2;
        int b0 = (c0 + 127) >> 7, b1 = (c1 + 127) >> 7, b2 = (c2 + 127) >> 7;
        meta[4] = 0; meta[5] = b0; meta[6] = b0 + b1; meta[7] = b0 + b1 + b2;
    }
}

// Merged phase C: gfold | typed_scatter
__global__ __launch_bounds__(256) void setup3_k(
    int* __restrict__ bhs, const int* __restrict__ gblk,
    const int* __restrict__ ntype, const int* __restrict__ toff,
    int* __restrict__ perm)
{
    __shared__ int cur[3];
    int bid = blockIdx.x;
    int t = threadIdx.x;
    if (bid < GS_BLOCKS) {
        int base = bid * 1024 + t * 4;
        int b = gblk[bid];
#pragma unroll
        for (int i = 0; i < 4; ++i) {
            int idx = base + i;
            if (idx < BH_N) bhs[idx] += b;
        }
        return;
    }
    bid -= GS_BLOCKS;
    if (t < 3) cur[t] = 0;
    __syncthreads();
    int n = bid * 256 + t;
    if (n < N_NODES) {
        int ty = ntype[n];
        int rank = atomicAdd(&cur[ty], 1);
        perm[toff[ty * HIST_BLOCKS + bid] + rank] = n;
    }
}

// CSR build phase 2: scatter edges to bucket-contiguous ebuf via LDS cursors.
__global__ __launch_bounds__(256) void bucket_scatter_k(
    const int* __restrict__ ei, const int* __restrict__ et,
    const int* __restrict__ bhs, uint32_t* __restrict__ ebuf)
{
    __shared__ int cur[NBUCK];
    int t = threadIdx.x;
    for (int i = t; i < NBUCK; i += 256) cur[i] = bhs[i * NB1 + blockIdx.x];
    __syncthreads();
    int base = blockIdx.x * EPB;
    for (int i = t; i < EPB; i += 256) {
        int e = base + i;
        int src = ei[e];
        int dst = ei[N_EDGES + e];
        int r = et[e];
        int pos = atomicAdd(&cur[dst >> 7], 1);
        ebuf[pos] = (uint32_t)(src * R_REL + r) | ((uint32_t)(dst & 127) << 25);
    }
}

// CSR build phase 3: one block per bucket; LDS hist/scan/rank -> pk + noff.
__global__ __launch_bounds__(256) void bucket_rank_k(
    const uint32_t* __restrict__ ebuf, const int* __restrict__ bhs,
    uint32_t* __restrict__ pk, int* __restrict__ noff)
{
    __shared__ uint32_t se[STAGE_CAP];
    __shared__ int hist[640];
    __shared__ int cursor[640];
    __shared__ int sb[256];
    int t = threadIdx.x;
    int b = blockIdx.x;
    int start = bhs[b * NB1];
    int end = (b < NBUCK - 1) ? bhs[(b + 1) * NB1] : N_EDGES;
    int size = end - start;
    for (int i = t; i < 640; i += 256) hist[i] = 0;
    __syncthreads();
    for (int i = t; i < size; i += 256) {
        uint32_t v = ebuf[start + i];
        if (i < STAGE_CAP) se[i] = v;
        uint32_t sr = v & 0x3FFFFu;
        int r = (int)(sr % 5u);
        int seg = (int)(v >> 25) * R_REL + r;
        atomicAdd(&hist[seg], 1);
    }
    __syncthreads();
    int b0 = t * 3;
    int loc[3]; int s0 = 0;
#pragma unroll
    for (int j = 0; j < 3; ++j) {
        int idx = b0 + j;
        int v = (idx < 640) ? hist[idx] : 0;
        loc[j] = s0; s0 += v;
    }
    sb[t] = s0;
    __syncthreads();
    for (int off = 1; off < 256; off <<= 1) {
        int u = (t >= off) ? sb[t - off] : 0;
        __syncthreads();
        sb[t] += u;
        __syncthreads();
    }
    int pre = sb[t] - s0;
#pragma unroll
    for (int j = 0; j < 3; ++j) {
        int idx = b0 + j;
        if (idx < 640) cursor[idx] = start + pre + loc[j];
    }
    __syncthreads();
    if (t < 128) noff[b * 128 + t] = cursor[t * 5];
    if (b == NBUCK - 1 && t == 128) noff[M_PAD] = N_EDGES;
    __syncthreads();
    for (int i = t; i < size; i += 256) {
        uint32_t v = (i < STAGE_CAP) ? se[i] : ebuf[start + i];
        uint32_t sr = v & 0x3FFFFu;
        int r = (int)(sr % 5u);
        int seg = (int)(v >> 25) * R_REL + r;
        int pos = atomicAdd(&cursor[seg], 1);
        pk[pos] = sr | ((uint32_t)hist[seg] << 18);
    }
}

// ---------------------------------------------------------------------------
// Y GEMM fp8-out: Y[m, j] = fp8(sum_d h[m, d] * W[j, d])  (K=256)
__global__ __launch_bounds__(256) void gemm_y_f8_k(
    const bf16* __restrict__ A, const bf16* __restrict__ B,
    uint8_t* __restrict__ Y, int ldc, int NT)
{
    __shared__ bf16 As[128][64];
    __shared__ bf16 Bs[128][64];
    int bid = blockIdx.x;
    int xcd = bid & 7;
    int r2 = bid >> 3;
    int ml = r2 / NT, nt = r2 - ml * NT;
    int m = xcd * 49 + ml;
    if (m >= M_PAD / 128) return;
    int m0 = m * 128, n0 = nt * 128;
    int tid = threadIdx.x;
    int lane = tid & 63, wave = tid >> 6;
    int wm = wave >> 1, wn = wave & 1;

    f32x4 acc[4][4] = {};

    for (int kt = 0; kt < 4; ++kt) {
#pragma unroll
        for (int cc = 0; cc < 4; ++cc) {
            int linear = cc * 256 + tid;
            int row = linear >> 3, sl = linear & 7;
            const bf16* gA = &A[(size_t)(m0 + row) * 256 + kt * 64 + sl * 8];
            const bf16* gB = &B[(size_t)(n0 + row) * 256 + kt * 64 + sl * 8];
            char* sA = (char*)&As[0][0] + (size_t)(cc * 256 + wave * 64) * 16;
            char* sB = (char*)&Bs[0][0] + (size_t)(cc * 256 + wave * 64) * 16;
            GLOAD_LDS16(gA, sA);
            GLOAD_LDS16(gB, sB);
        }
        __syncthreads();
#pragma unroll
        for (int kk = 0; kk < 2; ++kk) {
            bf16x8 af[4], bfr[4];
            int k0 = kk * 32 + (lane >> 4) * 8;
#pragma unroll
            for (int i = 0; i < 4; ++i) {
                af[i]  = *reinterpret_cast<const bf16x8*>(&As[wm * 64 + i * 16 + (lane & 15)][k0]);
                bfr[i] = *reinterpret_cast<const bf16x8*>(&Bs[wn * 64 + i * 16 + (lane & 15)][k0]);
            }
#pragma unroll
            for (int i = 0; i < 4; ++i)
#pragma unroll
                for (int j = 0; j < 4; ++j)
                    acc[i][j] = __builtin_amdgcn_mfma_f32_16x16x32_bf16(af[i], bfr[j], acc[i][j], 0, 0, 0);
        }
        __syncthreads();
    }

#pragma unroll
    for (int i = 0; i < 4; ++i)
#pragma unroll
        for (int j = 0; j < 4; ++j) {
            uint32_t q = fp8_pack4(acc[i][j][0], acc[i][j][1], acc[i][j][2], acc[i][j][3]);
            int row0 = m0 + wm * 64 + i * 16 + (lane >> 4) * 4;
            int col = n0 + wn * 64 + j * 16 + (lane & 15);
            Y[(size_t)(row0 + 0) * ldc + col] = (uint8_t)q;
            Y[(size_t)(row0 + 1) * ldc + col] = (uint8_t)(q >> 8);
            Y[(size_t)(row0 + 2) * ldc + col] = (uint8_t)(q >> 16);
            Y[(size_t)(row0 + 3) * ldc + col] = (uint8_t)(q >> 24);
        }
}

// Y GEMM bf16-out (layer 3): same structure, bf16 store.
__global__ __launch_bounds__(256) void gemm_y_bf_k(
    const bf16* __restrict__ A, const bf16* __restrict__ B,
    bf16* __restrict__ Y, int ldc, int NT)
{
    __shared__ bf16 As[128][64];
    __shared__ bf16 Bs[128][64];
    int bid = blockIdx.x;
    int xcd = bid & 7;
    int r2 = bid >> 3;
    int ml = r2 / NT, nt = r2 - ml * NT;
    int m = xcd * 49 + ml;
    if (m >= M_PAD / 128) return;
    int m0 = m * 128, n0 = nt * 128;
    int tid = threadIdx.x;
    int lane = tid & 63, wave = tid >> 6;
    int wm = wave >> 1, wn = wave & 1;

    f32x4 acc[4][4] = {};

    for (int kt = 0; kt < 4; ++kt) {
#pragma unroll
        for (int cc = 0; cc < 4; ++cc) {
            int linear = cc * 256 + tid;
            int row = linear >> 3, sl = linear & 7;
            const bf16* gA = &A[(size_t)(m0 + row) * 256 + kt * 64 + sl * 8];
            const bf16* gB = &B[(size_t)(n0 + row) * 256 + kt * 64 + sl * 8];
            char* sA = (char*)&As[0][0] + (size_t)(cc * 256 + wave * 64) * 16;
            char* sB = (char*)&Bs[0][0] + (size_t)(cc * 256 + wave * 64) * 16;
            GLOAD_LDS16(gA, sA);
            GLOAD_LDS16(gB, sB);
        }
        __syncthreads();
#pragma unroll
        for (int kk = 0; kk < 2; ++kk) {
            bf16x8 af[4], bfr[4];
            int k0 = kk * 32 + (lane >> 4) * 8;
#pragma unroll
            for (int i = 0; i < 4; ++i) {
                af[i]  = *reinterpret_cast<const bf16x8*>(&As[wm * 64 + i * 16 + (lane & 15)][k0]);
                bfr[i] = *reinterpret_cast<const bf16x8*>(&Bs[wn * 64 + i * 16 + (lane & 15)][k0]);
            }
#pragma unroll
            for (int i = 0; i < 4; ++i)
#pragma unroll
                for (int j = 0; j < 4; ++j)
                    acc[i][j] = __builtin_amdgcn_mfma_f32_16x16x32_bf16(af[i], bfr[j], acc[i][j], 0, 0, 0);
        }
        __syncthreads();
    }

#pragma unroll
    for (int i = 0; i < 4; ++i)
#pragma unroll
        for (int j = 0; j < 4; ++j)
#pragma unroll
            for (int r = 0; r < 4; ++r) {
                int row = m0 + wm * 64 + i * 16 + (lane >> 4) * 4 + r;
                int col = n0 + wn * 64 + j * 16 + (lane & 15);
                Y[(size_t)row * ldc + col] = (bf16)acc[i][j][r];
            }
}

// ---------------------------------------------------------------------------
// fp8 gather, Dout=256 full width: Cb[n,:] = sum_e (1/cnt_e) * dq(Y[idx_e,:])
// Coalesced pk load (lanes 0-15) + readlane broadcast -> scalar index path.
__global__ __launch_bounds__(256) void gather_f8_k(
    const uint8_t* __restrict__ Y, const uint32_t* __restrict__ pk,
    const int* __restrict__ noff, bf16* __restrict__ Cb)
{
    int wave = threadIdx.x >> 6, lane = threadIdx.x & 63;
    int n = blockIdx.x * 4 + wave;
    if (n >= N_NODES) return;
    int off0 = noff[n];
    int c = noff[n + 1] - off0;

    float s[4] = {};
    int e = 0;
    for (; e + 16 <= c; e += 16) {
        uint32_t pkv = pk[off0 + e + (lane & 15)];
        uint32_t v[16]; float cf[16];
#pragma unroll
        for (int j = 0; j < 16; ++j) {
            uint32_t w = (uint32_t)__builtin_amdgcn_readlane((int)pkv, j);
            v[j] = *reinterpret_cast<const uint32_t*>(
                &Y[(size_t)(w & 0x3FFFF) * 256 + lane * 4]);
            cf[j] = (float)(w >> 18);
        }
#pragma unroll
        for (int j = 0; j < 16; ++j)
            fp8_accum4(v[j], __builtin_amdgcn_rcpf(cf[j]), s);
    }
    if (e + 8 <= c) {
        uint32_t w[8]; uint32_t v[8];
#pragma unroll
        for (int j = 0; j < 8; ++j) w[j] = pk[off0 + e + j];
#pragma unroll
        for (int j = 0; j < 8; ++j)
            v[j] = *reinterpret_cast<const uint32_t*>(&Y[(size_t)(w[j] & 0x3FFFF) * 256 + lane * 4]);
#pragma unroll
        for (int j = 0; j < 8; ++j) {
            float ww = __builtin_amdgcn_rcpf((float)(w[j] >> 18));
            fp8_accum4(v[j], ww, s);
        }
        e += 8;
    }
    if (e + 4 <= c) {
        uint32_t w[4]; uint32_t v[4];
#pragma unroll
        for (int j = 0; j < 4; ++j) w[j] = pk[off0 + e + j];
#pragma unroll
        for (int j = 0; j < 4; ++j)
            v[j] = *reinterpret_cast<const uint32_t*>(&Y[(size_t)(w[j] & 0x3FFFF) * 256 + lane * 4]);
#pragma unroll
        for (int j = 0; j < 4; ++j) {
            float ww = __builtin_amdgcn_rcpf((float)(w[j] >> 18));
            fp8_accum4(v[j], ww, s);
        }
        e += 4;
    }
    for (; e < c; ++e) {
        uint32_t w = pk[off0 + e];
        uint32_t v = *reinterpret_cast<const uint32_t*>(&Y[(size_t)(w & 0x3FFFF) * 256 + lane * 4]);
        float ww = __builtin_amdgcn_rcpf((float)(w >> 18));
        fp8_accum4(v, ww, s);
    }

    bf16x4 o;
#pragma unroll
    for (int q = 0; q < 4; ++q) o[q] = (bf16)s[q];
    *reinterpret_cast<bf16x4*>(&Cb[(size_t)n * 256 + lane * 4]) = o;
}

// bf16 gather, Dout=128 full width (layer 3), same readlane batching.
__global__ __launch_bounds__(256) void gather_bf_k(
    const bf16* __restrict__ Y, const uint32_t* __restrict__ pk,
    const int* __restrict__ noff, bf16* __restrict__ Cb)
{
    int wave = threadIdx.x >> 6, lane = threadIdx.x & 63;
    int n = blockIdx.x * 4 + wave;
    if (n >= N_NODES) return;
    int off0 = noff[n];
    int c = noff[n + 1] - off0;

    float s0 = 0.f, s1 = 0.f;
    int e = 0;
    for (; e + 16 <= c; e += 16) {
        uint32_t pkv = pk[off0 + e + (lane & 15)];
        bf16x2 v[16]; float cf[16];
#pragma unroll
        for (int j = 0; j < 16; ++j) {
            uint32_t w = (uint32_t)__builtin_amdgcn_readlane((int)pkv, j);
            v[j] = *reinterpret_cast<const bf16x2*>(
                &Y[(size_t)(w & 0x3FFFF) * 128 + lane * 2]);
            cf[j] = (float)(w >> 18);
        }
#pragma unroll
        for (int j = 0; j < 16; ++j) {
            float ww = __builtin_amdgcn_rcpf(cf[j]);
            s0 += ww * (float)v[j][0];
            s1 += ww * (float)v[j][1];
        }
    }
    if (e + 8 <= c) {
        uint32_t w[8]; bf16x2 v[8];
#pragma unroll
        for (int j = 0; j < 8; ++j) w[j] = pk[off0 + e + j];
#pragma unroll
        for (int j = 0; j < 8; ++j)
            v[j] = *reinterpret_cast<const bf16x2*>(&Y[(size_t)(w[j] & 0x3FFFF) * 128 + lane * 2]);
#pragma unroll
        for (int j = 0; j < 8; ++j) {
            float ww = __builtin_amdgcn_rcpf((float)(w[j] >> 18));
            s0 += ww * (float)v[j][0];
            s1 += ww * (float)v[j][1];
        }
        e += 8;
    }
    if (e + 4 <= c) {
        uint32_t w[4]; bf16x2 v[4];
#pragma unroll
        for (int j = 0; j < 4; ++j) w[j] = pk[off0 + e + j];
#pragma unroll
        for (int j = 0; j < 4; ++j)
            v[j] = *reinterpret_cast<const bf16x2*>(&Y[(size_t)(w[j] & 0x3FFFF) * 128 + lane * 2]);
#pragma unroll
        for (int j = 0; j < 4; ++j) {
            float ww = __builtin_amdgcn_rcpf((float)(w[j] >> 18));
            s0 += ww * (float)v[j][0];
            s1 += ww * (float)v[j][1];
        }
        e += 4;
    }
    for (; e < c; ++e) {
        uint32_t w = pk[off0 + e];
        bf16x2 v = *reinterpret_cast<const bf16x2*>(&Y[(size_t)(w & 0x3FFFF) * 128 + lane * 2]);
        float ww = __builtin_amdgcn_rcpf((float)(w >> 18));
        s0 += ww * (float)v[0];
        s1 += ww * (float)v[1];
    }

    bf16x2 o; o[0] = (bf16)s0; o[1] = (bf16)s1;
    *reinterpret_cast<bf16x2*>(&Cb[(size_t)n * 128 + lane * 2]) = o;
}

// ---------------------------------------------------------------------------
// Root GEMM over type-sorted 128-row chunks: out = Cb[ri] + h[ri]@Rt[t]^T + b[t]
// relu_mode: ReLU + bf16 emit to hout; else fp32 emit to C (last layer).
__global__ __launch_bounds__(256) void gemm_root_k(
    const bf16* __restrict__ h, const bf16* __restrict__ Rt,
    const float* __restrict__ rootB, const int* __restrict__ perm,
    const int* __restrict__ meta, const bf16* __restrict__ Cb,
    float* __restrict__ C, bf16* __restrict__ hout, int Dout, int relu_mode)
{
    __shared__ bf16 As[128][64];
    __shared__ bf16 Bs[128][64];
    __shared__ int ridx[128];
    int tid = threadIdx.x;
    int bx = blockIdx.x;
    int b1 = meta[5], b2 = meta[6], b3 = meta[7];
    if (bx >= b3) return;
    int t = (bx >= b2) ? 2 : (bx >= b1 ? 1 : 0);
    int chunk = bx - (t == 2 ? b2 : (t == 1 ? b1 : 0));
    int tstart = meta[t];
    int tc = meta[8 + t];
    int rbase = chunk * 128;
    if (tid < 128) {
        int lr = rbase + tid;
        ridx[tid] = (lr < tc) ? perm[tstart + lr] : 0;
    }
    __syncthreads();

    int lane = tid & 63, wave = tid >> 6;
    int wm = wave >> 1, wn = wave & 1;
    int n0 = blockIdx.y * 128;
    const bf16* B = Rt + (size_t)t * Dout * 256;

    f32x4 acc[4][4] = {};

    for (int kt = 0; kt < 4; ++kt) {   // K = 256
#pragma unroll
        for (int cc = 0; cc < 4; ++cc) {
            int linear = cc * 256 + tid;
            int row = linear >> 3, sl = linear & 7;
            const bf16* gA = &h[(size_t)ridx[row] * 256 + kt * 64 + sl * 8];
            const bf16* gB = &B[(size_t)(n0 + row) * 256 + kt * 64 + sl * 8];
            char* sA = (char*)&As[0][0] + (size_t)(cc * 256 + wave * 64) * 16;
            char* sB = (char*)&Bs[0][0] + (size_t)(cc * 256 + wave * 64) * 16;
            GLOAD_LDS16(gA, sA);
            GLOAD_LDS16(gB, sB);
        }
        __syncthreads();
#pragma unroll
        for (int kk = 0; kk < 2; ++kk) {
            bf16x8 af[4], bfr[4];
            int k0 = kk * 32 + (lane >> 4) * 8;
#pragma unroll
            for (int i = 0; i < 4; ++i) {
                af[i]  = *reinterpret_cast<const bf16x8*>(&As[wm * 64 + i * 16 + (lane & 15)][k0]);
                bfr[i] = *reinterpret_cast<const bf16x8*>(&Bs[wn * 64 + i * 16 + (lane & 15)][k0]);
            }
#pragma unroll
            for (int i = 0; i < 4; ++i)
#pragma unroll
                for (int j = 0; j < 4; ++j)
                    acc[i][j] = __builtin_amdgcn_mfma_f32_16x16x32_bf16(af[i], bfr[j], acc[i][j], 0, 0, 0);
        }
        __syncthreads();
    }

#pragma unroll
    for (int i = 0; i < 4; ++i)
#pragma unroll
        for (int j = 0; j < 4; ++j)
#pragma unroll
            for (int r = 0; r < 4; ++r) {
                int rl = wm * 64 + i * 16 + (lane >> 4) * 4 + r;
                int col = n0 + wn * 64 + j * 16 + (lane & 15);
                if (rbase + rl < tc) {
                    int ri = ridx[rl];
                    float v = (float)Cb[(size_t)ri * Dout + col] + acc[i][j][r]
                              + rootB[t * Dout + col];
                    if (relu_mode)
                        hout[(size_t)ri * Dout + col] = (bf16)fmaxf(v, 0.f);
                    else
                        C[(size_t)ri * Dout + col] = v;
                }
            }
}

// ---------------------------------------------------------------------------
// Row-wise log_softmax over 128 logits; one wave per row.
__global__ __launch_bounds__(256) void logsoftmax_k(
    const float* __restrict__ C, float* __restrict__ out, int M)
{
    int row = blockIdx.x * 4 + (threadIdx.x >> 6);
    int lane = threadIdx.x & 63;
    if (row >= M) return;
    float v0 = C[(size_t)row * 128 + lane];
    float v1 = C[(size_t)row * 128 + 64 + lane];
    float m = fmaxf(v0, v1);
    for (int off = 32; off; off >>= 1) m = fmaxf(m, __shfl_xor(m, off));
    float s = expf(v0 - m) + expf(v1 - m);
    for (int off = 32; off; off >>= 1) s += __shfl_xor(s, off);
    float lse = m + logf(s);
    out[(size_t)row * 128 + lane] = v0 - lse;
    out[(size_t)row * 128 + 64 + lane] = v1 - lse;
}

// ---------------------------------------------------------------------------
extern "C" void kernel_launch(void* const* d_in, const int* in_sizes, int n_in,
                              void* d_out, int out_size, void* d_ws, size_t ws_size,
                              hipStream_t stream)
{
    const float* x0   = (const float*)d_in[0];
    const float* x1   = (const float*)d_in[1];
    const float* emb2 = (const float*)d_in[2];
    const int*   ei   = (const int*)d_in[3];
    const int*   et   = (const int*)d_in[4];
    const int*   ntyp = (const int*)d_in[5];
    const int*   lidx = (const int*)d_in[6];
    const float* relW[3]  = {(const float*)d_in[7],  (const float*)d_in[10], (const float*)d_in[13]};
    const float* rootW[3] = {(const float*)d_in[8],  (const float*)d_in[11], (const float*)d_in[14]};
    const float* rootB[3] = {(const float*)d_in[9],  (const float*)d_in[12], (const float*)d_in[15]};
    float* out = (float*)d_out;

    char* p = (char*)d_ws;
    auto carve = [&](size_t bytes) {
        char* q = p;
        p += (bytes + 255) & ~(size_t)255;
        return (void*)q;
    };
    bf16* h_a   = (bf16*)carve((size_t)M_PAD * 256 * 2);
    bf16* h_b   = (bf16*)carve((size_t)M_PAD * 256 * 2);
    // Y slab: 64 MB, used as fp8 [M][1280] in layers 1-2, bf16 [M][640] in layer 3
    uint8_t* Yq = (uint8_t*)carve((size_t)M_PAD * 1280);
    bf16* Yb    = (bf16*)Yq;
    bf16* Cb    = (bf16*)carve((size_t)M_PAD * 256 * 2);
    float* C    = (float*)carve((size_t)M_PAD * 128 * 4);
    bf16* WtA   = (bf16*)carve((size_t)(2 * R_REL * 256 * 256 + R_REL * 128 * 256) * 2);
    bf16* RtA   = (bf16*)carve((size_t)(2 * 3 * 256 * 256 + 3 * 128 * 256) * 2);
    int* bh     = (int*)carve((size_t)BH_N * 4);
    int* gblk   = (int*)carve((size_t)256 * 4);
    uint32_t* ebuf = (uint32_t*)carve((size_t)N_EDGES * 4);
    uint32_t* pk   = (uint32_t*)carve((size_t)(N_EDGES + 64) * 4);
    int* noff   = (int*)carve((size_t)(M_PAD + 1) * 4);
    int* tcnt   = (int*)carve((size_t)3 * HIST_BLOCKS * 4);
    int* toff   = (int*)carve((size_t)3 * HIST_BLOCKS * 4);
    int* meta   = (int*)carve((size_t)16 * 4);
    int* perm   = (int*)carve((size_t)N_NODES * 4);

    bf16* Wt[3] = {WtA, WtA + (size_t)R_REL * 256 * 256, WtA + (size_t)2 * R_REL * 256 * 256};
    bf16* Rt[3] = {RtA, RtA + (size_t)3 * 256 * 256, RtA + (size_t)2 * 3 * 256 * 256};

    // Phase A: group_input | bucket_hist | typed_hist | cast_w x3
    setup1_k<<<GI_BLOCKS + NB1 + HIST_BLOCKS + 3200, 256, 0, stream>>>(
        x0, x1, emb2, ntyp, lidx, h_a, ei, bh, tcnt,
        relW[0], rootW[0], relW[1], rootW[1], relW[2], rootW[2],
        Wt[0], Rt[0], Wt[1], Rt[1], Wt[2], Rt[2]);
    // Phase B: scan bucket-hist (in-place into bh) + block sums
    gscan1_k<<<GS_BLOCKS, 256, 0, stream>>>(bh, bh, gblk, BH_N);
    scan2m_k<<<2, 1024, 0, stream>>>(gblk, tcnt, toff, meta);
    setup3_k<<<GS_BLOCKS + HIST_BLOCKS, 256, 0, stream>>>(bh, gblk, ntyp, toff, perm);
    bucket_scatter_k<<<NB1, 256, 0, stream>>>(ei, et, bh, ebuf);
    bucket_rank_k<<<NBUCK, 256, 0, stream>>>(ebuf, bh, pk, noff);

    bf16* cur = h_a;
    bf16* nxt = h_b;
    for (int l = 0; l < 2; ++l) {
        // fp8 path: full-width Y [M][1280] fp8, one gather per layer
        gemm_y_f8_k<<<49 * 10 * 8, 256, 0, stream>>>(cur, Wt[l], Yq, 1280, 10);
        gather_f8_k<<<GI_BLOCKS, 256, 0, stream>>>(Yq, pk, noff, Cb);
        gemm_root_k<<<dim3(393, 2), 256, 0, stream>>>(
            cur, Rt[l], rootB[l], perm, meta, Cb, nullptr, nxt, 256, 1);
        bf16* tmp = cur; cur = nxt; nxt = tmp;
    }
    // Layer 3 (bf16, feeds logits): Y [M][640] bf16, Dout=128
    gemm_y_bf_k<<<49 * 5 * 8, 256, 0, stream>>>(cur, Wt[2], Yb, 640, 5);
    gather_bf_k<<<GI_BLOCKS, 256, 0, stream>>>(Yb, pk, noff, Cb);
    gemm_root_k<<<dim3(393, 1), 256, 0, stream>>>(
        cur, Rt[2], rootB[2], perm, meta, Cb, C, nullptr, 128, 0);
    logsoftmax_k<<<GI_BLOCKS, 256, 0, stream>>>(C, out, N_NODES);
}

// Round 16
// 508.954 us; speedup vs baseline: 1.5254x; 1.0031x over previous
//
#include <hip/hip_runtime.h>
#include <hip/hip_bf16.h>
#include <hip/hip_fp8.h>
#include <stdint.h>

// Problem constants (fixed by reference setup)
#define N_NODES 50000
#define M_PAD   50048          // 391 * 128
#define N_EDGES 1600000
#define R_REL   5
#define NBUCK   391            // buckets of 128 dst nodes
#define NB1     256            // blocks in bucket hist/scatter
#define EPB     6250           // N_EDGES / NB1 (exact)
#define BH_N    (NBUCK * NB1)  // 100096
#define GS_BLOCKS 98           // ceil(BH_N / 1024)
#define STAGE_CAP 6144         // LDS staging cap per bucket (mean 4092)
#define HIST_BLOCKS 196        // ceil(N_NODES / 256)
#define GI_BLOCKS 12500        // N_NODES / 4

typedef __bf16 bf16;
typedef __bf16 bf16x2 __attribute__((ext_vector_type(2)));
typedef __bf16 bf16x4 __attribute__((ext_vector_type(4)));
typedef __bf16 bf16x8 __attribute__((ext_vector_type(8)));
typedef float  f32x2  __attribute__((ext_vector_type(2)));
typedef float  f32x4  __attribute__((ext_vector_type(4)));

#define GLOAD_LDS16(g, l)                                                          \
    __builtin_amdgcn_global_load_lds(                                              \
        (const __attribute__((address_space(1))) void*)(g),                        \
        (__attribute__((address_space(3))) void*)(l), 16, 0, 0)

__device__ __forceinline__ uint8_t f32_to_fp8(float f) {
    return __hip_fp8_e4m3(f).__x;
}
__device__ __forceinline__ float fp8_to_f32(uint32_t b) {
    __hip_fp8_e4m3 v; v.__x = (uint8_t)b; return (float)v;
}

// Pack 4 f32 -> 4 fp8 bytes (hardware cvt_pk when available)
__device__ __forceinline__ uint32_t fp8_pack4(float a0, float a1, float a2, float a3) {
#if __has_builtin(__builtin_amdgcn_cvt_pk_fp8_f32)
    int q = __builtin_amdgcn_cvt_pk_fp8_f32(a0, a1, 0, false);
    q = __builtin_amdgcn_cvt_pk_fp8_f32(a2, a3, q, true);
    return (uint32_t)q;
#else
    return (uint32_t)f32_to_fp8(a0) | ((uint32_t)f32_to_fp8(a1) << 8) |
           ((uint32_t)f32_to_fp8(a2) << 16) | ((uint32_t)f32_to_fp8(a3) << 24);
#endif
}

__device__ __forceinline__ void fp8_accum4(uint32_t bits, float ww, float* s) {
#if __has_builtin(__builtin_amdgcn_cvt_pk_f32_fp8)
    f32x2 lo = __builtin_amdgcn_cvt_pk_f32_fp8((int)bits, false);
    f32x2 hi = __builtin_amdgcn_cvt_pk_f32_fp8((int)bits, true);
    s[0] += ww * lo[0]; s[1] += ww * lo[1];
    s[2] += ww * hi[0]; s[3] += ww * hi[1];
#else
    s[0] += ww * fp8_to_f32(bits & 0xFF);
    s[1] += ww * fp8_to_f32((bits >> 8) & 0xFF);
    s[2] += ww * fp8_to_f32((bits >> 16) & 0xFF);
    s[3] += ww * fp8_to_f32(bits >> 24);
#endif
}

// ---------------------------------------------------------------------------
// Merged setup phase A: group_input | bucket_hist | typed_hist | cast_w x3
__global__ __launch_bounds__(256) void setup1_k(
    const float* __restrict__ x0, const float* __restrict__ x1,
    const float* __restrict__ emb2, const int* __restrict__ ntype,
    const int* __restrict__ lidx, bf16* __restrict__ h,
    const int* __restrict__ ei, int* __restrict__ bh,
    int* __restrict__ tcnt,
    const float* __restrict__ relW0, const float* __restrict__ rootW0,
    const float* __restrict__ relW1, const float* __restrict__ rootW1,
    const float* __restrict__ relW2, const float* __restrict__ rootW2,
    bf16* __restrict__ Wt0, bf16* __restrict__ Rt0,
    bf16* __restrict__ Wt1, bf16* __restrict__ Rt1,
    bf16* __restrict__ Wt2, bf16* __restrict__ Rt2)
{
    __shared__ int smem[NBUCK];
    int bid = blockIdx.x;
    int t = threadIdx.x;
    if (bid < GI_BLOCKS) {
        int row = bid * 4 + (t >> 6);
        int lane = t & 63;
        int ty = ntype[row];
        int li = lidx[row];
        const float* src = (ty == 0) ? x0 : (ty == 1) ? x1 : emb2;
        float4 v = *reinterpret_cast<const float4*>(&src[(size_t)li * 256 + lane * 4]);
        bf16x4 o;
        o[0] = (bf16)v.x; o[1] = (bf16)v.y; o[2] = (bf16)v.z; o[3] = (bf16)v.w;
        *reinterpret_cast<bf16x4*>(&h[(size_t)row * 256 + lane * 4]) = o;
        return;
    }
    bid -= GI_BLOCKS;
    if (bid < NB1) {
        for (int i = t; i < NBUCK; i += 256) smem[i] = 0;
        __syncthreads();
        int base = bid * EPB;
        for (int i = t; i < EPB; i += 256) {
            int dst = ei[N_EDGES + base + i];
            atomicAdd(&smem[dst >> 7], 1);
        }
        __syncthreads();
        for (int i = t; i < NBUCK; i += 256) bh[i * NB1 + bid] = smem[i];
        return;
    }
    bid -= NB1;
    if (bid < HIST_BLOCKS) {
        if (t < 3) smem[t] = 0;
        __syncthreads();
        int n = bid * 256 + t;
        if (n < N_NODES) atomicAdd(&smem[ntype[n]], 1);
        __syncthreads();
        if (t < 3) tcnt[t * HIST_BLOCKS + bid] = smem[t];
        return;
    }
    bid -= HIST_BLOCKS;
    const float* relW; const float* rootW; bf16* Wt; bf16* Rt; int Dout;
    if (bid < 1280)      { relW = relW0; rootW = rootW0; Wt = Wt0; Rt = Rt0; Dout = 256; }
    else if (bid < 2560) { relW = relW1; rootW = rootW1; Wt = Wt1; Rt = Rt1; Dout = 256; bid -= 1280; }
    else                 { relW = relW2; rootW = rootW2; Wt = Wt2; Rt = Rt2; Dout = 128; bid -= 2560; }
    int i = bid * 256 + t;
    int relN = R_REL * Dout * 256;
    if (i < relN)  Wt[i] = (bf16)relW[i];
    int rootN = 3 * Dout * 256;
    if (i < rootN) Rt[i] = (bf16)rootW[i];
}

// Generic two-level exclusive scan over n ints (1024/block).
__global__ __launch_bounds__(256) void gscan1_k(
    const int* __restrict__ in, int* __restrict__ outv,
    int* __restrict__ blksum, int n)
{
    __shared__ int lds[256];
    int base = blockIdx.x * 1024;
    int t = threadIdx.x;
    int vals[4]; int s = 0;
#pragma unroll
    for (int i = 0; i < 4; ++i) {
        int idx = base + t * 4 + i;
        vals[i] = (idx < n) ? in[idx] : 0;
        s += vals[i];
    }
    lds[t] = s;
    __syncthreads();
    for (int off = 1; off < 256; off <<= 1) {
        int v = (t >= off) ? lds[t - off] : 0;
        __syncthreads();
        lds[t] += v;
        __syncthreads();
    }
    int incl = lds[t];
    int ex = incl - s;
    if (t == 255) blksum[blockIdx.x] = incl;
    int run = ex;
#pragma unroll
    for (int i = 0; i < 4; ++i) {
        int idx = base + t * 4 + i;
        if (idx < n) outv[idx] = run;
        run += vals[i];
    }
}

// Merged phase B: block 0 = exclusive scan of gblk; block 1 = typed scan + meta.
__global__ __launch_bounds__(1024) void scan2m_k(
    int* __restrict__ gblk,
    const int* __restrict__ tcnt, int* __restrict__ toff, int* __restrict__ meta)
{
    __shared__ int lds[1024];
    int t = threadIdx.x;
    if (blockIdx.x == 0) {
        int v = (t < GS_BLOCKS) ? gblk[t] : 0;
        lds[t] = v;
        __syncthreads();
        for (int off = 1; off < 1024; off <<= 1) {
            int u = (t >= off) ? lds[t - off] : 0;
            __syncthreads();
            lds[t] += u;
            __syncthreads();
        }
        if (t < GS_BLOCKS) gblk[t] = lds[t] - v;
        return;
    }
    int v = (t < 3 * HIST_BLOCKS) ? tcnt[t] : 0;
    lds[t] = v;
    __syncthreads();
    for (int off = 1; off < 1024; off <<= 1) {
        int u = (t >= off) ? lds[t - off] : 0;
        __syncthreads();
        lds[t] += u;
        __syncthreads();
    }
    if (t < 3 * HIST_BLOCKS) toff[t] = lds[t] - v;
    if (t == 0) {
        int ts1 = lds[1 * HIST_BLOCKS - 1];
        int ts2 = lds[2 * HIST_BLOCKS - 1];
        int ts3 = lds[3 * HIST_BLOCKS - 1];
        meta[0] = 0; meta[1] = ts1; meta[2] = ts2; meta[3] = ts3;
        int c0 = ts1, c1 = ts2 - ts1, c2 = ts3 - ts2;
        meta[8] = c0; meta[9] = c1; meta[10] = c2;
        int b0 = (c0 + 127) >> 7, b1 = (c1 + 127) >> 7, b2 = (c2 + 127) >> 7;
        meta[4] = 0; meta[5] = b0; meta[6] = b0 + b1; meta[7] = b0 + b1 + b2;
    }
}

// Merged phase C: gfold | typed_scatter
__global__ __launch_bounds__(256) void setup3_k(
    int* __restrict__ bhs, const int* __restrict__ gblk,
    const int* __restrict__ ntype, const int* __restrict__ toff,
    int* __restrict__ perm)
{
    __shared__ int cur[3];
    int bid = blockIdx.x;
    int t = threadIdx.x;
    if (bid < GS_BLOCKS) {
        int base = bid * 1024 + t * 4;
        int b = gblk[bid];
#pragma unroll
        for (int i = 0; i < 4; ++i) {
            int idx = base + i;
            if (idx < BH_N) bhs[idx] += b;
        }
        return;
    }
    bid -= GS_BLOCKS;
    if (t < 3) cur[t] = 0;
    __syncthreads();
    int n = bid * 256 + t;
    if (n < N_NODES) {
        int ty = ntype[n];
        int rank = atomicAdd(&cur[ty], 1);
        perm[toff[ty * HIST_BLOCKS + bid] + rank] = n;
    }
}

// CSR build phase 2: scatter edges to bucket-contiguous ebuf via LDS cursors.
__global__ __launch_bounds__(256) void bucket_scatter_k(
    const int* __restrict__ ei, const int* __restrict__ et,
    const int* __restrict__ bhs, uint32_t* __restrict__ ebuf)
{
    __shared__ int cur[NBUCK];
    int t = threadIdx.x;
    for (int i = t; i < NBUCK; i += 256) cur[i] = bhs[i * NB1 + blockIdx.x];
    __syncthreads();
    int base = blockIdx.x * EPB;
    for (int i = t; i < EPB; i += 256) {
        int e = base + i;
        int src = ei[e];
        int dst = ei[N_EDGES + e];
        int r = et[e];
        int pos = atomicAdd(&cur[dst >> 7], 1);
        ebuf[pos] = (uint32_t)(src * R_REL + r) | ((uint32_t)(dst & 127) << 25);
    }
}

// CSR build phase 3: one block per bucket; LDS hist/scan/rank -> pk + noff.
__global__ __launch_bounds__(256) void bucket_rank_k(
    const uint32_t* __restrict__ ebuf, const int* __restrict__ bhs,
    uint32_t* __restrict__ pk, int* __restrict__ noff)
{
    __shared__ uint32_t se[STAGE_CAP];
    __shared__ int hist[640];
    __shared__ int cursor[640];
    __shared__ int sb[256];
    int t = threadIdx.x;
    int b = blockIdx.x;
    int start = bhs[b * NB1];
    int end = (b < NBUCK - 1) ? bhs[(b + 1) * NB1] : N_EDGES;
    int size = end - start;
    for (int i = t; i < 640; i += 256) hist[i] = 0;
    __syncthreads();
    for (int i = t; i < size; i += 256) {
        uint32_t v = ebuf[start + i];
        if (i < STAGE_CAP) se[i] = v;
        uint32_t sr = v & 0x3FFFFu;
        int r = (int)(sr % 5u);
        int seg = (int)(v >> 25) * R_REL + r;
        atomicAdd(&hist[seg], 1);
    }
    __syncthreads();
    int b0 = t * 3;
    int loc[3]; int s0 = 0;
#pragma unroll
    for (int j = 0; j < 3; ++j) {
        int idx = b0 + j;
        int v = (idx < 640) ? hist[idx] : 0;
        loc[j] = s0; s0 += v;
    }
    sb[t] = s0;
    __syncthreads();
    for (int off = 1; off < 256; off <<= 1) {
        int u = (t >= off) ? sb[t - off] : 0;
        __syncthreads();
        sb[t] += u;
        __syncthreads();
    }
    int pre = sb[t] - s0;
#pragma unroll
    for (int j = 0; j < 3; ++j) {
        int idx = b0 + j;
        if (idx < 640) cursor[idx] = start + pre + loc[j];
    }
    __syncthreads();
    if (t < 128) noff[b * 128 + t] = cursor[t * 5];
    if (b == NBUCK - 1 && t == 128) noff[M_PAD] = N_EDGES;
    __syncthreads();
    for (int i = t; i < size; i += 256) {
        uint32_t v = (i < STAGE_CAP) ? se[i] : ebuf[start + i];
        uint32_t sr = v & 0x3FFFFu;
        int r = (int)(sr % 5u);
        int seg = (int)(v >> 25) * R_REL + r;
        int pos = atomicAdd(&cursor[seg], 1);
        pk[pos] = sr | ((uint32_t)hist[seg] << 18);
    }
}

// ---------------------------------------------------------------------------
// Y GEMM fp8-out: Y[m, j] = fp8(sum_d h[m, d] * W[j, d])  (K=256)
__global__ __launch_bounds__(256) void gemm_y_f8_k(
    const bf16* __restrict__ A, const bf16* __restrict__ B,
    uint8_t* __restrict__ Y, int ldc, int NT)
{
    __shared__ bf16 As[128][64];
    __shared__ bf16 Bs[128][64];
    int bid = blockIdx.x;
    int xcd = bid & 7;
    int r2 = bid >> 3;
    int ml = r2 / NT, nt = r2 - ml * NT;
    int m = xcd * 49 + ml;
    if (m >= M_PAD / 128) return;
    int m0 = m * 128, n0 = nt * 128;
    int tid = threadIdx.x;
    int lane = tid & 63, wave = tid >> 6;
    int wm = wave >> 1, wn = wave & 1;

    f32x4 acc[4][4] = {};

    for (int kt = 0; kt < 4; ++kt) {
#pragma unroll
        for (int cc = 0; cc < 4; ++cc) {
            int linear = cc * 256 + tid;
            int row = linear >> 3, sl = linear & 7;
            const bf16* gA = &A[(size_t)(m0 + row) * 256 + kt * 64 + sl * 8];
            const bf16* gB = &B[(size_t)(n0 + row) * 256 + kt * 64 + sl * 8];
            char* sA = (char*)&As[0][0] + (size_t)(cc * 256 + wave * 64) * 16;
            char* sB = (char*)&Bs[0][0] + (size_t)(cc * 256 + wave * 64) * 16;
            GLOAD_LDS16(gA, sA);
            GLOAD_LDS16(gB, sB);
        }
        __syncthreads();
#pragma unroll
        for (int kk = 0; kk < 2; ++kk) {
            bf16x8 af[4], bfr[4];
            int k0 = kk * 32 + (lane >> 4) * 8;
#pragma unroll
            for (int i = 0; i < 4; ++i) {
                af[i]  = *reinterpret_cast<const bf16x8*>(&As[wm * 64 + i * 16 + (lane & 15)][k0]);
                bfr[i] = *reinterpret_cast<const bf16x8*>(&Bs[wn * 64 + i * 16 + (lane & 15)][k0]);
            }
#pragma unroll
            for (int i = 0; i < 4; ++i)
#pragma unroll
                for (int j = 0; j < 4; ++j)
                    acc[i][j] = __builtin_amdgcn_mfma_f32_16x16x32_bf16(af[i], bfr[j], acc[i][j], 0, 0, 0);
        }
        __syncthreads();
    }

#pragma unroll
    for (int i = 0; i < 4; ++i)
#pragma unroll
        for (int j = 0; j < 4; ++j) {
            uint32_t q = fp8_pack4(acc[i][j][0], acc[i][j][1], acc[i][j][2], acc[i][j][3]);
            int row0 = m0 + wm * 64 + i * 16 + (lane >> 4) * 4;
            int col = n0 + wn * 64 + j * 16 + (lane & 15);
            Y[(size_t)(row0 + 0) * ldc + col] = (uint8_t)q;
            Y[(size_t)(row0 + 1) * ldc + col] = (uint8_t)(q >> 8);
            Y[(size_t)(row0 + 2) * ldc + col] = (uint8_t)(q >> 16);
            Y[(size_t)(row0 + 3) * ldc + col] = (uint8_t)(q >> 24);
        }
}

// Y GEMM bf16-out (layer 3): same structure, bf16 store.
__global__ __launch_bounds__(256) void gemm_y_bf_k(
    const bf16* __restrict__ A, const bf16* __restrict__ B,
    bf16* __restrict__ Y, int ldc, int NT)
{
    __shared__ bf16 As[128][64];
    __shared__ bf16 Bs[128][64];
    int bid = blockIdx.x;
    int xcd = bid & 7;
    int r2 = bid >> 3;
    int ml = r2 / NT, nt = r2 - ml * NT;
    int m = xcd * 49 + ml;
    if (m >= M_PAD / 128) return;
    int m0 = m * 128, n0 = nt * 128;
    int tid = threadIdx.x;
    int lane = tid & 63, wave = tid >> 6;
    int wm = wave >> 1, wn = wave & 1;

    f32x4 acc[4][4] = {};

    for (int kt = 0; kt < 4; ++kt) {
#pragma unroll
        for (int cc = 0; cc < 4; ++cc) {
            int linear = cc * 256 + tid;
            int row = linear >> 3, sl = linear & 7;
            const bf16* gA = &A[(size_t)(m0 + row) * 256 + kt * 64 + sl * 8];
            const bf16* gB = &B[(size_t)(n0 + row) * 256 + kt * 64 + sl * 8];
            char* sA = (char*)&As[0][0] + (size_t)(cc * 256 + wave * 64) * 16;
            char* sB = (char*)&Bs[0][0] + (size_t)(cc * 256 + wave * 64) * 16;
            GLOAD_LDS16(gA, sA);
            GLOAD_LDS16(gB, sB);
        }
        __syncthreads();
#pragma unroll
        for (int kk = 0; kk < 2; ++kk) {
            bf16x8 af[4], bfr[4];
            int k0 = kk * 32 + (lane >> 4) * 8;
#pragma unroll
            for (int i = 0; i < 4; ++i) {
                af[i]  = *reinterpret_cast<const bf16x8*>(&As[wm * 64 + i * 16 + (lane & 15)][k0]);
                bfr[i] = *reinterpret_cast<const bf16x8*>(&Bs[wn * 64 + i * 16 + (lane & 15)][k0]);
            }
#pragma unroll
            for (int i = 0; i < 4; ++i)
#pragma unroll
                for (int j = 0; j < 4; ++j)
                    acc[i][j] = __builtin_amdgcn_mfma_f32_16x16x32_bf16(af[i], bfr[j], acc[i][j], 0, 0, 0);
        }
        __syncthreads();
    }

#pragma unroll
    for (int i = 0; i < 4; ++i)
#pragma unroll
        for (int j = 0; j < 4; ++j)
#pragma unroll
            for (int r = 0; r < 4; ++r) {
                int row = m0 + wm * 64 + i * 16 + (lane >> 4) * 4 + r;
                int col = n0 + wn * 64 + j * 16 + (lane & 15);
                Y[(size_t)row * ldc + col] = (bf16)acc[i][j][r];
            }
}

// ---------------------------------------------------------------------------
// fp8 gather, Dout=256 full width: Cb[n,:] = sum_e (1/cnt_e) * dq(Y[idx_e,:])
// Coalesced pk load (lanes 0-15) + readlane broadcast -> scalar index path.
__global__ __launch_bounds__(256) void gather_f8_k(
    const uint8_t* __restrict__ Y, const uint32_t* __restrict__ pk,
    const int* __restrict__ noff, bf16* __restrict__ Cb)
{
    int wave = threadIdx.x >> 6, lane = threadIdx.x & 63;
    int n = blockIdx.x * 4 + wave;
    if (n >= N_NODES) return;
    int off0 = noff[n];
    int c = noff[n + 1] - off0;

    float s[4] = {};
    int e = 0;
    for (; e + 16 <= c; e += 16) {
        uint32_t pkv = pk[off0 + e + (lane & 15)];
        uint32_t v[16]; float cf[16];
#pragma unroll
        for (int j = 0; j < 16; ++j) {
            uint32_t w = (uint32_t)__builtin_amdgcn_readlane((int)pkv, j);
            v[j] = *reinterpret_cast<const uint32_t*>(
                &Y[(size_t)(w & 0x3FFFF) * 256 + lane * 4]);
            cf[j] = (float)(w >> 18);
        }
#pragma unroll
        for (int j = 0; j < 16; ++j)
            fp8_accum4(v[j], __builtin_amdgcn_rcpf(cf[j]), s);
    }
    if (e + 8 <= c) {
        uint32_t w[8]; uint32_t v[8];
#pragma unroll
        for (int j = 0; j < 8; ++j) w[j] = pk[off0 + e + j];
#pragma unroll
        for (int j = 0; j < 8; ++j)
            v[j] = *reinterpret_cast<const uint32_t*>(&Y[(size_t)(w[j] & 0x3FFFF) * 256 + lane * 4]);
#pragma unroll
        for (int j = 0; j < 8; ++j) {
            float ww = __builtin_amdgcn_rcpf((float)(w[j] >> 18));
            fp8_accum4(v[j], ww, s);
        }
        e += 8;
    }
    if (e + 4 <= c) {
        uint32_t w[4]; uint32_t v[4];
#pragma unroll
        for (int j = 0; j < 4; ++j) w[j] = pk[off0 + e + j];
#pragma unroll
        for (int j = 0; j < 4; ++j)
            v[j] = *reinterpret_cast<const uint32_t*>(&Y[(size_t)(w[j] & 0x3FFFF) * 256 + lane * 4]);
#pragma unroll
        for (int j = 0; j < 4; ++j) {
            float ww = __builtin_amdgcn_rcpf((float)(w[j] >> 18));
            fp8_accum4(v[j], ww, s);
        }
        e += 4;
    }
    for (; e < c; ++e) {
        uint32_t w = pk[off0 + e];
        uint32_t v = *reinterpret_cast<const uint32_t*>(&Y[(size_t)(w & 0x3FFFF) * 256 + lane * 4]);
        float ww = __builtin_amdgcn_rcpf((float)(w >> 18));
        fp8_accum4(v, ww, s);
    }

    bf16x4 o;
#pragma unroll
    for (int q = 0; q < 4; ++q) o[q] = (bf16)s[q];
    *reinterpret_cast<bf16x4*>(&Cb[(size_t)n * 256 + lane * 4]) = o;
}

// bf16 gather, Dout=128 full width (layer 3), same readlane batching.
__global__ __launch_bounds__(256) void gather_bf_k(
    const bf16* __restrict__ Y, const uint32_t* __restrict__ pk,
    const int* __restrict__ noff, bf16* __restrict__ Cb)
{
    int wave = threadIdx.x >> 6, lane = threadIdx.x & 63;
    int n = blockIdx.x * 4 + wave;
    if (n >= N_NODES) return;
    int off0 = noff[n];
    int c = noff[n + 1] - off0;

    float s0 = 0.f, s1 = 0.f;
    int e = 0;
    for (; e + 16 <= c; e += 16) {
        uint32_t pkv = pk[off0 + e + (lane & 15)];
        bf16x2 v[16]; float cf[16];
#pragma unroll
        for (int j = 0; j < 16; ++j) {
            uint32_t w = (uint32_t)__builtin_amdgcn_readlane((int)pkv, j);
            v[j] = *reinterpret_cast<const bf16x2*>(
                &Y[(size_t)(w & 0x3FFFF) * 128 + lane * 2]);
            cf[j] = (float)(w >> 18);
        }
#pragma unroll
        for (int j = 0; j < 16; ++j) {
            float ww = __builtin_amdgcn_rcpf(cf[j]);
            s0 += ww * (float)v[j][0];
            s1 += ww * (float)v[j][1];
        }
    }
    if (e + 8 <= c) {
        uint32_t w[8]; bf16x2 v[8];
#pragma unroll
        for (int j = 0; j < 8; ++j) w[j] = pk[off0 + e + j];
#pragma unroll
        for (int j = 0; j < 8; ++j)
            v[j] = *reinterpret_cast<const bf16x2*>(&Y[(size_t)(w[j] & 0x3FFFF) * 128 + lane * 2]);
#pragma unroll
        for (int j = 0; j < 8; ++j) {
            float ww = __builtin_amdgcn_rcpf((float)(w[j] >> 18));
            s0 += ww * (float)v[j][0];
            s1 += ww * (float)v[j][1];
        }
        e += 8;
    }
    if (e + 4 <= c) {
        uint32_t w[4]; bf16x2 v[4];
#pragma unroll
        for (int j = 0; j < 4; ++j) w[j] = pk[off0 + e + j];
#pragma unroll
        for (int j = 0; j < 4; ++j)
            v[j] = *reinterpret_cast<const bf16x2*>(&Y[(size_t)(w[j] & 0x3FFFF) * 128 + lane * 2]);
#pragma unroll
        for (int j = 0; j < 4; ++j) {
            float ww = __builtin_amdgcn_rcpf((float)(w[j] >> 18));
            s0 += ww * (float)v[j][0];
            s1 += ww * (float)v[j][1];
        }
        e += 4;
    }
    for (; e < c; ++e) {
        uint32_t w = pk[off0 + e];
        bf16x2 v = *reinterpret_cast<const bf16x2*>(&Y[(size_t)(w & 0x3FFFF) * 128 + lane * 2]);
        float ww = __builtin_amdgcn_rcpf((float)(w >> 18));
        s0 += ww * (float)v[0];
        s1 += ww * (float)v[1];
    }

    bf16x2 o; o[0] = (bf16)s0; o[1] = (bf16)s1;
    *reinterpret_cast<bf16x2*>(&Cb[(size_t)n * 128 + lane * 2]) = o;
}

// ---------------------------------------------------------------------------
// Root GEMM over type-sorted 128-row chunks: out = Cb[ri] + h[ri]@Rt[t]^T + b[t]
// relu_mode: ReLU + bf16 emit to hout; else fp32 emit to C (last layer).
__global__ __launch_bounds__(256) void gemm_root_k(
    const bf16* __restrict__ h, const bf16* __restrict__ Rt,
    const float* __restrict__ rootB, const int* __restrict__ perm,
    const int* __restrict__ meta, const bf16* __restrict__ Cb,
    float* __restrict__ C, bf16* __restrict__ hout, int Dout, int relu_mode)
{
    __shared__ bf16 As[128][64];
    __shared__ bf16 Bs[128][64];
    __shared__ int ridx[128];
    int tid = threadIdx.x;
    int bx = blockIdx.x;
    int b1 = meta[5], b2 = meta[6], b3 = meta[7];
    if (bx >= b3) return;
    int t = (bx >= b2) ? 2 : (bx >= b1 ? 1 : 0);
    int chunk = bx - (t == 2 ? b2 : (t == 1 ? b1 : 0));
    int tstart = meta[t];
    int tc = meta[8 + t];
    int rbase = chunk * 128;
    if (tid < 128) {
        int lr = rbase + tid;
        ridx[tid] = (lr < tc) ? perm[tstart + lr] : 0;
    }
    __syncthreads();

    int lane = tid & 63, wave = tid >> 6;
    int wm = wave >> 1, wn = wave & 1;
    int n0 = blockIdx.y * 128;
    const bf16* B = Rt + (size_t)t * Dout * 256;

    f32x4 acc[4][4] = {};

    for (int kt = 0; kt < 4; ++kt) {   // K = 256
#pragma unroll
        for (int cc = 0; cc < 4; ++cc) {
            int linear = cc * 256 + tid;
            int row = linear >> 3, sl = linear & 7;
            const bf16* gA = &h[(size_t)ridx[row] * 256 + kt * 64 + sl * 8];
            const bf16* gB = &B[(size_t)(n0 + row) * 256 + kt * 64 + sl * 8];
            char* sA = (char*)&As[0][0] + (size_t)(cc * 256 + wave * 64) * 16;
            char* sB = (char*)&Bs[0][0] + (size_t)(cc * 256 + wave * 64) * 16;
            GLOAD_LDS16(gA, sA);
            GLOAD_LDS16(gB, sB);
        }
        __syncthreads();
#pragma unroll
        for (int kk = 0; kk < 2; ++kk) {
            bf16x8 af[4], bfr[4];
            int k0 = kk * 32 + (lane >> 4) * 8;
#pragma unroll
            for (int i = 0; i < 4; ++i) {
                af[i]  = *reinterpret_cast<const bf16x8*>(&As[wm * 64 + i * 16 + (lane & 15)][k0]);
                bfr[i] = *reinterpret_cast<const bf16x8*>(&Bs[wn * 64 + i * 16 + (lane & 15)][k0]);
            }
#pragma unroll
            for (int i = 0; i < 4; ++i)
#pragma unroll
                for (int j = 0; j < 4; ++j)
                    acc[i][j] = __builtin_amdgcn_mfma_f32_16x16x32_bf16(af[i], bfr[j], acc[i][j], 0, 0, 0);
        }
        __syncthreads();
    }

#pragma unroll
    for (int i = 0; i < 4; ++i)
#pragma unroll
        for (int j = 0; j < 4; ++j)
#pragma unroll
            for (int r = 0; r < 4; ++r) {
                int rl = wm * 64 + i * 16 + (lane >> 4) * 4 + r;
                int col = n0 + wn * 64 + j * 16 + (lane & 15);
                if (rbase + rl < tc) {
                    int ri = ridx[rl];
                    float v = (float)Cb[(size_t)ri * Dout + col] + acc[i][j][r]
                              + rootB[t * Dout + col];
                    if (relu_mode)
                        hout[(size_t)ri * Dout + col] = (bf16)fmaxf(v, 0.f);
                    else
                        C[(size_t)ri * Dout + col] = v;
                }
            }
}

// ---------------------------------------------------------------------------
// Row-wise log_softmax over 128 logits; one wave per row.
__global__ __launch_bounds__(256) void logsoftmax_k(
    const float* __restrict__ C, float* __restrict__ out, int M)
{
    int row = blockIdx.x * 4 + (threadIdx.x >> 6);
    int lane = threadIdx.x & 63;
    if (row >= M) return;
    float v0 = C[(size_t)row * 128 + lane];
    float v1 = C[(size_t)row * 128 + 64 + lane];
    float m = fmaxf(v0, v1);
    for (int off = 32; off; off >>= 1) m = fmaxf(m, __shfl_xor(m, off));
    float s = expf(v0 - m) + expf(v1 - m);
    for (int off = 32; off; off >>= 1) s += __shfl_xor(s, off);
    float lse = m + logf(s);
    out[(size_t)row * 128 + lane] = v0 - lse;
    out[(size_t)row * 128 + 64 + lane] = v1 - lse;
}

// ---------------------------------------------------------------------------
extern "C" void kernel_launch(void* const* d_in, const int* in_sizes, int n_in,
                              void* d_out, int out_size, void* d_ws, size_t ws_size,
                              hipStream_t stream)
{
    const float* x0   = (const float*)d_in[0];
    const float* x1   = (const float*)d_in[1];
    const float* emb2 = (const float*)d_in[2];
    const int*   ei   = (const int*)d_in[3];
    const int*   et   = (const int*)d_in[4];
    const int*   ntyp = (const int*)d_in[5];
    const int*   lidx = (const int*)d_in[6];
    const float* relW[3]  = {(const float*)d_in[7],  (const float*)d_in[10], (const float*)d_in[13]};
    const float* rootW[3] = {(const float*)d_in[8],  (const float*)d_in[11], (const float*)d_in[14]};
    const float* rootB[3] = {(const float*)d_in[9],  (const float*)d_in[12], (const float*)d_in[15]};
    float* out = (float*)d_out;

    char* p = (char*)d_ws;
    auto carve = [&](size_t bytes) {
        char* q = p;
        p += (bytes + 255) & ~(size_t)255;
        return (void*)q;
    };
    bf16* h_a   = (bf16*)carve((size_t)M_PAD * 256 * 2);
    bf16* h_b   = (bf16*)carve((size_t)M_PAD * 256 * 2);
    // Y slab: 64 MB, used as fp8 [M][1280] in layers 1-2, bf16 [M][640] in layer 3
    uint8_t* Yq = (uint8_t*)carve((size_t)M_PAD * 1280);
    bf16* Yb    = (bf16*)Yq;
    bf16* Cb    = (bf16*)carve((size_t)M_PAD * 256 * 2);
    float* C    = (float*)carve((size_t)M_PAD * 128 * 4);
    bf16* WtA   = (bf16*)carve((size_t)(2 * R_REL * 256 * 256 + R_REL * 128 * 256) * 2);
    bf16* RtA   = (bf16*)carve((size_t)(2 * 3 * 256 * 256 + 3 * 128 * 256) * 2);
    int* bh     = (int*)carve((size_t)BH_N * 4);
    int* gblk   = (int*)carve((size_t)256 * 4);
    uint32_t* ebuf = (uint32_t*)carve((size_t)N_EDGES * 4);
    uint32_t* pk   = (uint32_t*)carve((size_t)(N_EDGES + 64) * 4);
    int* noff   = (int*)carve((size_t)(M_PAD + 1) * 4);
    int* tcnt   = (int*)carve((size_t)3 * HIST_BLOCKS * 4);
    int* toff   = (int*)carve((size_t)3 * HIST_BLOCKS * 4);
    int* meta   = (int*)carve((size_t)16 * 4);
    int* perm   = (int*)carve((size_t)N_NODES * 4);

    bf16* Wt[3] = {WtA, WtA + (size_t)R_REL * 256 * 256, WtA + (size_t)2 * R_REL * 256 * 256};
    bf16* Rt[3] = {RtA, RtA + (size_t)3 * 256 * 256, RtA + (size_t)2 * 3 * 256 * 256};

    // Phase A: group_input | bucket_hist | typed_hist | cast_w x3
    setup1_k<<<GI_BLOCKS + NB1 + HIST_BLOCKS + 3200, 256, 0, stream>>>(
        x0, x1, emb2, ntyp, lidx, h_a, ei, bh, tcnt,
        relW[0], rootW[0], relW[1], rootW[1], relW[2], rootW[2],
        Wt[0], Rt[0], Wt[1], Rt[1], Wt[2], Rt[2]);
    // Phase B: scan bucket-hist (in-place into bh) + block sums
    gscan1_k<<<GS_BLOCKS, 256, 0, stream>>>(bh, bh, gblk, BH_N);
    scan2m_k<<<2, 1024, 0, stream>>>(gblk, tcnt, toff, meta);
    setup3_k<<<GS_BLOCKS + HIST_BLOCKS, 256, 0, stream>>>(bh, gblk, ntyp, toff, perm);
    bucket_scatter_k<<<NB1, 256, 0, stream>>>(ei, et, bh, ebuf);
    bucket_rank_k<<<NBUCK, 256, 0, stream>>>(ebuf, bh, pk, noff);

    bf16* cur = h_a;
    bf16* nxt = h_b;
    for (int l = 0; l < 2; ++l) {
        // fp8 path: full-width Y [M][1280] fp8, one gather per layer
        gemm_y_f8_k<<<49 * 10 * 8, 256, 0, stream>>>(cur, Wt[l], Yq, 1280, 10);
        gather_f8_k<<<GI_BLOCKS, 256, 0, stream>>>(Yq, pk, noff, Cb);
        gemm_root_k<<<dim3(393, 2), 256, 0, stream>>>(
            cur, Rt[l], rootB[l], perm, meta, Cb, nullptr, nxt, 256, 1);
        bf16* tmp = cur; cur = nxt; nxt = tmp;
    }
    // Layer 3 (bf16, feeds logits): Y [M][640] bf16, Dout=128
    gemm_y_bf_k<<<49 * 5 * 8, 256, 0, stream>>>(cur, Wt[2], Yb, 640, 5);
    gather_bf_k<<<GI_BLOCKS, 256, 0, stream>>>(Yb, pk, noff, Cb);
    gemm_root_k<<<dim3(393, 1), 256, 0, stream>>>(
        cur, Rt[2], rootB[2], perm, meta, Cb, C, nullptr, 128, 0);
    logsoftmax_k<<<GI_BLOCKS, 256, 0, stream>>>(C, out, N_NODES);
}